// Round 2
// baseline (1416.451 us; speedup 1.0000x reference)
//
#include <hip/hip_runtime.h>
#include <hip/hip_bf16.h>
#include <math.h>

#define S 2048
#define HID 1024
#define NH 8
#define HD 128
#define INTER 4096
#define EPSV 1e-6f
#define THETA 10000.0f

typedef __hip_bfloat16 bf16;
typedef unsigned short u16;
typedef __attribute__((ext_vector_type(8))) short bf16x8;  // 8 bf16 = 4 VGPRs
typedef __attribute__((ext_vector_type(4))) float f32x4;

__device__ inline float bu2f(u16 u) {
    unsigned int x = ((unsigned int)u) << 16;
    return __uint_as_float(x);
}
__device__ inline u16 f2bu(float f) {
    bf16 h = __float2bfloat16(f);
    return *reinterpret_cast<u16*>(&h);
}
// Dual-dtype input load (raw harness inputs): isbf ? bf16 : f32
__device__ inline float ldin(const void* p, size_t i, bool isbf) {
    return isbf ? bu2f(((const u16*)p)[i]) : ((const float*)p)[i];
}
__device__ inline float gelu_tanh(float x) {
    float x3 = x * x * x;
    return 0.5f * x * (1.f + tanhf(0.7978845608028654f * (x + 0.044715f * x3)));
}
// Direct global->LDS 16B/lane async copy. LDS dest must be wave-uniform;
// lane i's 16B lands at ldsbase + i*16. Global source IS per-lane.
__device__ inline void gload16(const u16* g, u16* l) {
    __builtin_amdgcn_global_load_lds(
        (const __attribute__((address_space(1))) void*)g,
        (__attribute__((address_space(3))) void*)l, 16, 0, 0);
}

// ---------------- dtype probe (round-1 notes) ----------------
__global__ __launch_bounds__(256) void probe_kernel(const unsigned short* __restrict__ x,
                                                    int* __restrict__ flag) {
    __shared__ int red[256];
    int tid = threadIdx.x;
    int cnt = 0;
    for (int i = tid; i < 2048; i += 256) {
        unsigned short u = x[2 * i];
        int e = (u >> 7) & 0xFF;
        cnt += (e >= 110 && e <= 135) ? 1 : 0;
    }
    red[tid] = cnt;
    __syncthreads();
    for (int off = 128; off > 0; off >>= 1) {
        if (tid < off) red[tid] += red[tid + off];
        __syncthreads();
    }
    if (tid == 0) *flag = (red[0] > 1024) ? 1 : 0;
}

// ---------------- weight transpose+convert: W (KxN, input dtype) -> WT (NxK, bf16) ----------------
__global__ __launch_bounds__(256) void transpose_w(const void* __restrict__ W,
                                                   u16* __restrict__ WT,
                                                   const int* __restrict__ flag,
                                                   int K, int N) {
    bool isbf = (*flag != 0);
    __shared__ float t[32][33];
    int n0 = blockIdx.x * 32, k0 = blockIdx.y * 32;
    int c = threadIdx.x & 31, r = threadIdx.x >> 5;
#pragma unroll
    for (int p = 0; p < 4; p++)
        t[r + 8 * p][c] = ldin(W, (size_t)(k0 + r + 8 * p) * N + n0 + c, isbf);
    __syncthreads();
#pragma unroll
    for (int p = 0; p < 4; p++) {
        int row = r + 8 * p;
        WT[(size_t)(n0 + row) * K + k0 + c] = f2bu(t[c][row]);
    }
}

// ---------------- V transpose: V[key][dh] (stride sv, bf16) -> VT[dh][key] (2048 keys) ----------------
__global__ __launch_bounds__(256) void transpose_v(const u16* __restrict__ V, int sv,
                                                   u16* __restrict__ VT) {
    __shared__ u16 t[32][33];
    int k0 = blockIdx.x * 32;  // key tile
    int d0 = blockIdx.y * 32;  // dh tile
    int c = threadIdx.x & 31, r = threadIdx.x >> 5;
#pragma unroll
    for (int p = 0; p < 4; p++)
        t[r + 8 * p][c] = V[(size_t)(k0 + r + 8 * p) * sv + d0 + c];
    __syncthreads();
#pragma unroll
    for (int p = 0; p < 4; p++)
        VT[(size_t)(d0 + r + 8 * p) * S + k0 + c] = t[c][r + 8 * p];
}

// ---------------- RMSNorm -> bf16 ----------------
__global__ __launch_bounds__(256) void rmsnorm_kernel(const void* __restrict__ x,
                                                      const void* __restrict__ w,
                                                      u16* __restrict__ y,
                                                      const int* __restrict__ flag,
                                                      int dual) {
    bool isbf = (*flag != 0);
    bool xbf = dual && isbf;
    int row = blockIdx.x;
    size_t base = (size_t)row * HID;
    __shared__ float red[256];
    float xv[4];
    float s = 0.f;
#pragma unroll
    for (int i = 0; i < 4; i++) {
        float v = ldin(x, base + threadIdx.x + 256 * i, xbf);
        xv[i] = v;
        s += v * v;
    }
    red[threadIdx.x] = s;
    __syncthreads();
    for (int off = 128; off > 0; off >>= 1) {
        if (threadIdx.x < off) red[threadIdx.x] += red[threadIdx.x + off];
        __syncthreads();
    }
    float scale = rsqrtf(red[0] / (float)HID + EPSV);
#pragma unroll
    for (int i = 0; i < 4; i++) {
        int c = threadIdx.x + 256 * i;
        y[base + c] = f2bu(xv[i] * scale * (1.f + ldin(w, c, isbf)));
    }
}

// ================= MFMA GEMM (v2: global_load_lds staging, XOR-swizzled LDS) =================
// LDS tiles are LINEAR [row][64B] (BK=32 bf16 per row). global_load_lds writes lane-linear,
// so the XOR swizzle (chunk ^= (row>>1)&3, 16B chunks within the 64B row) is applied on the
// per-lane GLOBAL SOURCE address at load time and again on the frag-read address (involution).
// Spreads the 16-row b128 column reads over 8 bank groups (2 lanes/bank = free).
template <int BM, int BN, int WRN, int WCN, int EPI>
__global__ __launch_bounds__(256) void gemm_mfma(const u16* __restrict__ A,
                                                 const u16* __restrict__ BT,
                                                 float* __restrict__ Cf,
                                                 u16* __restrict__ Cb,
                                                 const void* __restrict__ res,
                                                 const int* __restrict__ flag,
                                                 int M, int N, int K) {
    constexpr int BK = 32;
    constexpr int WM = BM / WRN, WN = BN / WCN, TI = WM / 16, TJ = WN / 16;
    __shared__ u16 As[BM * 32];
    __shared__ u16 Bs[BN * 32];
    int tid = threadIdx.x, lane = tid & 63, wv = tid >> 6;
    int wr = wv / WCN, wc = wv % WCN;
    int m = lane & 15, quad = lane >> 4;
    int m0 = blockIdx.y * BM, n0 = blockIdx.x * BN;
    f32x4 acc[TI][TJ] = {};
    for (int k0 = 0; k0 < K; k0 += BK) {
        __syncthreads();  // prev compute done reading LDS
#pragma unroll
        for (int c2 = 0; c2 < BM / 64; c2++) {
            int row0 = (wv * (BM / 64) + c2) * 16;
            int row = row0 + (lane >> 2);
            int ch = lane & 3;
            gload16(&A[(size_t)(m0 + row) * K + k0 + ((ch ^ ((row >> 1) & 3)) << 3)],
                    &As[row0 * 32]);
        }
#pragma unroll
        for (int c2 = 0; c2 < BN / 64; c2++) {
            int row0 = (wv * (BN / 64) + c2) * 16;
            int row = row0 + (lane >> 2);
            int ch = lane & 3;
            gload16(&BT[(size_t)(n0 + row) * K + k0 + ((ch ^ ((row >> 1) & 3)) << 3)],
                    &Bs[row0 * 32]);
        }
        __syncthreads();  // vmcnt drained by barrier -> tiles in LDS
        bf16x8 af[TI], bf_[TJ];
#pragma unroll
        for (int i = 0; i < TI; i++) {
            int rr = wr * WM + i * 16 + m;
            af[i] = *reinterpret_cast<const bf16x8*>(&As[rr * 32 + ((quad ^ ((rr >> 1) & 3)) << 3)]);
        }
#pragma unroll
        for (int j = 0; j < TJ; j++) {
            int rr = wc * WN + j * 16 + m;
            bf_[j] = *reinterpret_cast<const bf16x8*>(&Bs[rr * 32 + ((quad ^ ((rr >> 1) & 3)) << 3)]);
        }
#pragma unroll
        for (int i = 0; i < TI; i++)
#pragma unroll
            for (int j = 0; j < TJ; j++)
                acc[i][j] = __builtin_amdgcn_mfma_f32_16x16x32_bf16(af[i], bf_[j], acc[i][j], 0, 0, 0);
    }
    bool isbf = (EPI == 1) ? (*flag != 0) : false;
#pragma unroll
    for (int i = 0; i < TI; i++) {
#pragma unroll
        for (int j = 0; j < TJ; j++) {
#pragma unroll
            for (int r = 0; r < 4; r++) {
                int row = m0 + wr * WM + i * 16 + quad * 4 + r;
                int col = n0 + wc * WN + j * 16 + m;
                size_t idx = (size_t)row * N + col;
                float v = acc[i][j][r];
                if (EPI == 0) Cb[idx] = f2bu(v);
                else if (EPI == 1) Cf[idx] = v + ldin(res, idx, isbf);
                else Cf[idx] = Cf[idx] + v;
            }
        }
    }
}

// ------------- Fused gated MLP MFMA: C(bf16) = gelu(A@Wg) * (A@Wu) -------------
template <int BM, int BN, int WRN, int WCN>
__global__ __launch_bounds__(256) void gemm_gated_mfma(const u16* __restrict__ A,
                                                       const u16* __restrict__ BgT,
                                                       const u16* __restrict__ BuT,
                                                       u16* __restrict__ C,
                                                       int M, int N, int K) {
    constexpr int BK = 32;
    constexpr int WM = BM / WRN, WN = BN / WCN, TI = WM / 16, TJ = WN / 16;
    __shared__ u16 As[BM * 32];
    __shared__ u16 Bgs[BN * 32];
    __shared__ u16 Bus[BN * 32];
    int tid = threadIdx.x, lane = tid & 63, wv = tid >> 6;
    int wr = wv / WCN, wc = wv % WCN;
    int m = lane & 15, quad = lane >> 4;
    int m0 = blockIdx.y * BM, n0 = blockIdx.x * BN;
    f32x4 accg[TI][TJ] = {};
    f32x4 accu[TI][TJ] = {};
    for (int k0 = 0; k0 < K; k0 += BK) {
        __syncthreads();
#pragma unroll
        for (int c2 = 0; c2 < BM / 64; c2++) {
            int row0 = (wv * (BM / 64) + c2) * 16;
            int row = row0 + (lane >> 2);
            int ch = lane & 3;
            gload16(&A[(size_t)(m0 + row) * K + k0 + ((ch ^ ((row >> 1) & 3)) << 3)],
                    &As[row0 * 32]);
        }
#pragma unroll
        for (int c2 = 0; c2 < BN / 64; c2++) {
            int row0 = (wv * (BN / 64) + c2) * 16;
            int row = row0 + (lane >> 2);
            int ch = lane & 3;
            gload16(&BgT[(size_t)(n0 + row) * K + k0 + ((ch ^ ((row >> 1) & 3)) << 3)],
                    &Bgs[row0 * 32]);
            gload16(&BuT[(size_t)(n0 + row) * K + k0 + ((ch ^ ((row >> 1) & 3)) << 3)],
                    &Bus[row0 * 32]);
        }
        __syncthreads();
        bf16x8 af[TI], bg[TJ], bu[TJ];
#pragma unroll
        for (int i = 0; i < TI; i++) {
            int rr = wr * WM + i * 16 + m;
            af[i] = *reinterpret_cast<const bf16x8*>(&As[rr * 32 + ((quad ^ ((rr >> 1) & 3)) << 3)]);
        }
#pragma unroll
        for (int j = 0; j < TJ; j++) {
            int rr = wc * WN + j * 16 + m;
            int off = rr * 32 + ((quad ^ ((rr >> 1) & 3)) << 3);
            bg[j] = *reinterpret_cast<const bf16x8*>(&Bgs[off]);
            bu[j] = *reinterpret_cast<const bf16x8*>(&Bus[off]);
        }
#pragma unroll
        for (int i = 0; i < TI; i++)
#pragma unroll
            for (int j = 0; j < TJ; j++) {
                accg[i][j] = __builtin_amdgcn_mfma_f32_16x16x32_bf16(af[i], bg[j], accg[i][j], 0, 0, 0);
                accu[i][j] = __builtin_amdgcn_mfma_f32_16x16x32_bf16(af[i], bu[j], accu[i][j], 0, 0, 0);
            }
    }
#pragma unroll
    for (int i = 0; i < TI; i++)
#pragma unroll
        for (int j = 0; j < TJ; j++)
#pragma unroll
            for (int r = 0; r < 4; r++) {
                int row = m0 + wr * WM + i * 16 + quad * 4 + r;
                int col = n0 + wc * WN + j * 16 + m;
                C[(size_t)row * N + col] = f2bu(gelu_tanh(accg[i][j][r]) * accu[i][j][r]);
            }
}

// ---------------- RoPE: read qkv (bf16, stride 3072), write qr/kr (bf16, stride 1024) ----------------
__global__ __launch_bounds__(64) void rope_kernel(const u16* __restrict__ qkv,
                                                  u16* __restrict__ qr,
                                                  u16* __restrict__ kr) {
    int b = blockIdx.x;
    int t = b >> 3, h = b & 7;
    int i = threadIdx.x;  // 0..63
    size_t ib = (size_t)t * 3072 + h * HD;
    size_t ob = (size_t)t * HID + h * HD;
    float inv = powf(THETA, -(float)(2 * i) / (float)HD);
    float f = (float)t * inv;
    float c = cosf(f), s = sinf(f);
    float q1 = bu2f(qkv[ib + i]), q2 = bu2f(qkv[ib + i + 64]);
    qr[ob + i] = f2bu(q1 * c - q2 * s);
    qr[ob + i + 64] = f2bu(q2 * c + q1 * s);
    float k1 = bu2f(qkv[ib + 1024 + i]), k2 = bu2f(qkv[ib + 1024 + i + 64]);
    kr[ob + i] = f2bu(k1 * c - k2 * s);
    kr[ob + i + 64] = f2bu(k2 * c + k1 * s);
}

// ============ MFMA flash attention (v3: + T14 async stage split) ============
// Structure as round 1 (swapped QK^T, in-register softmax, bpermute P redistribution,
// XOR-swizzled 32KB LDS). New: tile t+1's global loads are issued into registers BEFORE
// computing tile t; the LDS write happens after the read-done barrier. HBM/L2 latency
// hides under QK+softmax+PV (T14, +17% measured on attn in learn_hip m214).
__device__ inline int swz64(int row, int b) {
    return row * 64 + (b ^ (((row >> 1) & 3) << 4));
}

template <bool CAUSAL>
__global__ __launch_bounds__(256, 4) void attn_mfma_kernel(
    const u16* __restrict__ qa, const u16* __restrict__ qb, int sq,
    const u16* __restrict__ ka, const u16* __restrict__ kb, int sk,
    const u16* __restrict__ vta, const u16* __restrict__ vtb,
    u16* __restrict__ Out, int nkeys) {
    __shared__ char Ks[4 * 64 * 64];    // [t=d/32][key 0..63][32 d], swizzled 64B rows
    __shared__ char VTs[2 * 128 * 64];  // [ks=key/32][d 0..127][32 keys], swizzled

    int tid = threadIdx.x;
    int lane = tid & 63, w = tid >> 6;
    int col = lane & 15, quad = lane >> 4;
    // Causal: longest blocks (largest q0) first to reduce makespan tail.
    int bx = CAUSAL ? ((int)gridDim.x - 1 - (int)blockIdx.x) : (int)blockIdx.x;
    int q0 = bx * 64;
    int h = blockIdx.y;
    const float scale = 0.08838834764831845f;  // 1/sqrt(128)

    // Q b-frags (4 d-steps of 32) straight from global into registers
    int q0r = CAUSAL ? q0 : (q0 & (S - 1));
    const u16* qp = ((CAUSAL || q0 < S) ? qa : qb) + (size_t)q0r * sq;
    bf16x8 aq[4];
#pragma unroll
    for (int t = 0; t < 4; t++)
        aq[t] = *reinterpret_cast<const bf16x8*>(
            qp + (size_t)(16 * w + col) * sq + h * HD + 32 * t + quad * 8);

    f32x4 o[8] = {};           // O^T: o[nt][r] = O[q][d = 16nt + 4quad + r]
    float m_ = -1e30f, l_ = 0.f;

    // bpermute source lanes for P redistribution:
    // target quad t needs pu[2ks + (t>>1)] from source quads 2(t&1) and 2(t&1)+1.
    int sA = col + 16 * (2 * (quad & 1));
    int sB = sA + 16;
    bool hi = (quad >> 1) != 0;

    int ntiles = CAUSAL ? (q0 >> 6) + 1 : (nkeys >> 6);

    uint4 kreg[4], vreg[4];
    auto ld_tile = [&](int tt) {
        int j0 = tt * 64;
        int j0r = j0 & (S - 1);
        bool eb = (!CAUSAL) && (j0 >= S);
        const u16* kp = eb ? kb : ka;
        const u16* vp = eb ? vtb : vta;
#pragma unroll
        for (int i = 0; i < 4; i++) {
            int l = tid + 256 * i;
            int key = l >> 4, c = l & 15;
            kreg[i] = *reinterpret_cast<const uint4*>(kp + (size_t)(j0r + key) * sk + h * HD + c * 8);
        }
#pragma unroll
        for (int i = 0; i < 4; i++) {
            int l = tid + 256 * i;
            int d = l >> 3, c = l & 7;
            vreg[i] = *reinterpret_cast<const uint4*>(vp + (size_t)(h * HD + d) * S + j0r + c * 8);
        }
    };
    auto st_tile = [&]() {
#pragma unroll
        for (int i = 0; i < 4; i++) {
            int l = tid + 256 * i;
            int key = l >> 4, c = l & 15;
            int t = c >> 2, kq = c & 3;
            *reinterpret_cast<uint4*>(&Ks[t * 4096 + swz64(key, kq * 16)]) = kreg[i];
        }
#pragma unroll
        for (int i = 0; i < 4; i++) {
            int l = tid + 256 * i;
            int d = l >> 3, c = l & 7;
            int ks = c >> 2, kq = c & 3;
            *reinterpret_cast<uint4*>(&VTs[ks * 8192 + swz64(d, kq * 16)]) = vreg[i];
        }
    };

    ld_tile(0);
    st_tile();

    for (int tt = 0; tt < ntiles; tt++) {
        __syncthreads();  // staged tile tt visible to all waves
        if (tt + 1 < ntiles) ld_tile(tt + 1);  // issue next tile's loads early (T14)

        int j0 = tt * 64;
        // ---- QK^T (swapped): wave computes 64k x 16q ----
        f32x4 sc[4] = {};
        __builtin_amdgcn_s_setprio(1);
#pragma unroll
        for (int t = 0; t < 4; t++) {
#pragma unroll
            for (int ct = 0; ct < 4; ct++) {
                bf16x8 kf = *reinterpret_cast<const bf16x8*>(
                    &Ks[t * 4096 + swz64(16 * ct + col, quad * 16)]);
                sc[ct] = __builtin_amdgcn_mfma_f32_16x16x32_bf16(kf, aq[t], sc[ct], 0, 0, 0);
            }
        }
        __builtin_amdgcn_s_setprio(0);
        bool diag = CAUSAL && (j0 == q0);
#pragma unroll
        for (int ct = 0; ct < 4; ct++) {
#pragma unroll
            for (int r = 0; r < 4; r++) {
                float v = sc[ct][r] * scale;
                if (diag && (16 * ct + 4 * quad + r > 16 * w + col)) v = -1e30f;
                sc[ct][r] = v;
            }
        }

        // ---- per-lane online softmax (one query per lane) ----
        float mx0 = fmaxf(fmaxf(sc[0][0], sc[0][1]), fmaxf(sc[0][2], sc[0][3]));
        float mx1 = fmaxf(fmaxf(sc[1][0], sc[1][1]), fmaxf(sc[1][2], sc[1][3]));
        float mx2 = fmaxf(fmaxf(sc[2][0], sc[2][1]), fmaxf(sc[2][2], sc[2][3]));
        float mx3 = fmaxf(fmaxf(sc[3][0], sc[3][1]), fmaxf(sc[3][2], sc[3][3]));
        float rmax = fmaxf(fmaxf(mx0, mx1), fmaxf(mx2, mx3));
        rmax = fmaxf(rmax, __shfl_xor(rmax, 16));
        rmax = fmaxf(rmax, __shfl_xor(rmax, 32));
        float mn = fmaxf(m_, rmax);
        float al = __expf(m_ - mn);
#pragma unroll
        for (int ct = 0; ct < 4; ct++)
#pragma unroll
            for (int r = 0; r < 4; r++) sc[ct][r] = __expf(sc[ct][r] - mn);
        float s0 = (sc[0][0] + sc[0][1]) + (sc[0][2] + sc[0][3]);
        float s1 = (sc[1][0] + sc[1][1]) + (sc[1][2] + sc[1][3]);
        float s2 = (sc[2][0] + sc[2][1]) + (sc[2][2] + sc[2][3]);
        float s3 = (sc[3][0] + sc[3][1]) + (sc[3][2] + sc[3][3]);
        float rs = (s0 + s1) + (s2 + s3);
        rs += __shfl_xor(rs, 16);
        rs += __shfl_xor(rs, 32);
        l_ = l_ * al + rs;
        m_ = mn;

        // ---- pack P^T to bf16 pairs: pu[ct] covers keys 16ct+4quad+{0..3} ----
        unsigned int pu[4][2];
#pragma unroll
        for (int ct = 0; ct < 4; ct++) {
            pu[ct][0] = (unsigned int)f2bu(sc[ct][0]) | ((unsigned int)f2bu(sc[ct][1]) << 16);
            pu[ct][1] = (unsigned int)f2bu(sc[ct][2]) | ((unsigned int)f2bu(sc[ct][3]) << 16);
        }

        // ---- O^T rescale ----
#pragma unroll
        for (int nt = 0; nt < 8; nt++)
#pragma unroll
            for (int r = 0; r < 4; r++) o[nt][r] *= al;

        // ---- PV: O^T += V^T @ P^T; b-frag gathered via bpermute ----
#pragma unroll
        for (int ks = 0; ks < 2; ks++) {
            unsigned int a0 = __shfl(pu[2 * ks][0], sA);
            unsigned int a1 = __shfl(pu[2 * ks][1], sA);
            unsigned int c0 = __shfl(pu[2 * ks + 1][0], sA);
            unsigned int c1 = __shfl(pu[2 * ks + 1][1], sA);
            unsigned int b0 = __shfl(pu[2 * ks][0], sB);
            unsigned int b1 = __shfl(pu[2 * ks][1], sB);
            unsigned int g0 = __shfl(pu[2 * ks + 1][0], sB);
            unsigned int g1 = __shfl(pu[2 * ks + 1][1], sB);
            union {
                unsigned int u[4];
                bf16x8 v;
            } pb;
            pb.u[0] = hi ? c0 : a0;
            pb.u[1] = hi ? c1 : a1;
            pb.u[2] = hi ? g0 : b0;
            pb.u[3] = hi ? g1 : b1;
            __builtin_amdgcn_s_setprio(1);
#pragma unroll
            for (int nt = 0; nt < 8; nt++) {
                bf16x8 vf = *reinterpret_cast<const bf16x8*>(
                    &VTs[ks * 8192 + swz64(16 * nt + col, quad * 16)]);
                o[nt] = __builtin_amdgcn_mfma_f32_16x16x32_bf16(vf, pb.v, o[nt], 0, 0, 0);
            }
            __builtin_amdgcn_s_setprio(0);
        }

        __syncthreads();  // all waves done reading Ks/VTs for tile tt
        if (tt + 1 < ntiles) st_tile();  // write prefetched tile tt+1 to LDS
    }

    // ---- epilogue: O /= l, write bf16 (stride HID); r-values are contiguous in d ----
    float inv = 1.f / l_;
    size_t rowoff = (size_t)(q0 + 16 * w + col) * HID + (size_t)h * HD + 4 * quad;
#pragma unroll
    for (int nt = 0; nt < 8; nt++) {
        ushort4 st;
        st.x = f2bu(o[nt][0] * inv);
        st.y = f2bu(o[nt][1] * inv);
        st.z = f2bu(o[nt][2] * inv);
        st.w = f2bu(o[nt][3] * inv);
        *reinterpret_cast<ushort4*>(&Out[rowoff + 16 * nt]) = st;
    }
}

// ---------------- f32 -> output dtype (per flag) ----------------
__global__ __launch_bounds__(256) void store_out_kernel(const float* __restrict__ a,
                                                        const float* __restrict__ b,
                                                        void* __restrict__ out,
                                                        const int* __restrict__ flag) {
    bool isbf = (*flag != 0);
    size_t i = (size_t)blockIdx.x * 256 + threadIdx.x;
    const size_t MM = (size_t)S * HID;
    float v = (i < MM) ? a[i] : b[i - MM];
    if (isbf)
        ((bf16*)out)[i] = __float2bfloat16(v);
    else
        ((float*)out)[i] = v;
}

extern "C" void kernel_launch(void* const* d_in, const int* in_sizes, int n_in,
                              void* d_out, int out_size, void* d_ws, size_t ws_size,
                              hipStream_t stream) {
    const void* x[2] = {d_in[0], d_in[1]};
    const void* w_ln[2] = {d_in[5], d_in[14]};
    const void* w_q[2] = {d_in[6], d_in[15]};
    const void* w_k[2] = {d_in[7], d_in[16]};
    const void* w_v[2] = {d_in[8], d_in[17]};
    const void* w_o[2] = {d_in[9], d_in[18]};
    const void* w_pln[2] = {d_in[10], d_in[19]};
    const void* w_g[2] = {d_in[11], d_in[20]};
    const void* w_u[2] = {d_in[12], d_in[21]};
    const void* w_d[2] = {d_in[13], d_in[22]};

    char* base = (char*)d_ws;
    int* flag = (int*)base;
    u16* p = (u16*)(base + 256);
    const size_t E_QKV = (size_t)S * 3072;
    const size_t E_SH = (size_t)S * HID;
    const size_t E_GT = (size_t)S * INTER;
    const size_t E_VT = (size_t)NH * HD * S;  // 2.1M u16 per expert

    u16* qkv[2] = {p, p + E_QKV};            p += 2 * E_QKV;
    u16* qr = p;                             p += E_SH;
    u16* kr = p;                             p += E_SH;
    u16* h_bf = p;                           p += E_SH;
    u16* attnbuf = p;                        p += E_SH;
    u16* vtg[2] = {p, p + E_VT};             p += 2 * E_VT;
    u16* gated = p;                          p += E_GT;  // mixed overlays gated
    u16* mixed = gated;
    u16* wqkvT = p;                          p += (size_t)3072 * 1024;
    u16* woT[2] = {p, p + (size_t)1024 * 1024};  p += 2 * (size_t)1024 * 1024;
    u16* wgT = p;                            p += (size_t)INTER * 1024;
    u16* wuT = p;                            p += (size_t)INTER * 1024;
    u16* wdT = p;                            p += (size_t)1024 * INTER;
    float* fbase = (float*)(((size_t)p + 255) & ~(size_t)255);
    float* outX[2] = {fbase, fbase + E_SH};

    probe_kernel<<<1, 256, 0, stream>>>((const unsigned short*)d_in[0], flag);

    for (int e = 0; e < 2; e++) {
        transpose_w<<<dim3(1024 / 32, 1024 / 32), 256, 0, stream>>>(w_q[e], wqkvT, flag, 1024, 1024);
        transpose_w<<<dim3(1024 / 32, 1024 / 32), 256, 0, stream>>>(w_k[e], wqkvT + (size_t)1024 * 1024, flag, 1024, 1024);
        transpose_w<<<dim3(1024 / 32, 1024 / 32), 256, 0, stream>>>(w_v[e], wqkvT + (size_t)2048 * 1024, flag, 1024, 1024);
        transpose_w<<<dim3(1024 / 32, 1024 / 32), 256, 0, stream>>>(w_o[e], woT[e], flag, 1024, 1024);
        transpose_w<<<dim3(INTER / 32, 1024 / 32), 256, 0, stream>>>(w_g[e], wgT, flag, 1024, INTER);
        transpose_w<<<dim3(INTER / 32, 1024 / 32), 256, 0, stream>>>(w_u[e], wuT, flag, 1024, INTER);
        transpose_w<<<dim3(1024 / 32, INTER / 32), 256, 0, stream>>>(w_d[e], wdT, flag, INTER, 1024);

        rmsnorm_kernel<<<S, 256, 0, stream>>>(x[e], w_ln[e], h_bf, flag, 1);
        gemm_mfma<128, 128, 2, 2, 0><<<dim3(3072 / 128, S / 128), 256, 0, stream>>>(
            h_bf, wqkvT, nullptr, qkv[e], nullptr, flag, S, 3072, 1024);
        rope_kernel<<<S * NH, 64, 0, stream>>>(qkv[e], qr, kr);
        transpose_v<<<dim3(S / 32, 1024 / 32), 256, 0, stream>>>(qkv[e] + 2048, 3072, vtg[e]);
        attn_mfma_kernel<true><<<dim3(S / 64, NH), 256, 0, stream>>>(
            qr, qr, HID, kr, kr, HID, vtg[e], vtg[e], attnbuf, S);
        gemm_mfma<64, 128, 1, 4, 1><<<dim3(1024 / 128, S / 64), 256, 0, stream>>>(
            attnbuf, woT[e], outX[e], nullptr, x[e], flag, S, 1024, 1024);
        rmsnorm_kernel<<<S, 256, 0, stream>>>(outX[e], w_pln[e], h_bf, flag, 0);
        gemm_gated_mfma<128, 64, 2, 2><<<dim3(INTER / 64, S / 128), 256, 0, stream>>>(
            h_bf, wgT, wuT, gated, S, INTER, 1024);
        gemm_mfma<64, 128, 1, 4, 2><<<dim3(1024 / 128, S / 64), 256, 0, stream>>>(
            gated, wdT, outX[e], nullptr, nullptr, flag, S, 1024, INTER);
    }

    attn_mfma_kernel<false><<<dim3(2 * S / 64, NH), 256, 0, stream>>>(
        qkv[0], qkv[1], 3072, qkv[0] + 1024, qkv[1] + 1024, 3072,
        vtg[0], vtg[1], mixed, 2 * S);
    gemm_mfma<64, 128, 1, 4, 2><<<dim3(1024 / 128, S / 64), 256, 0, stream>>>(
        mixed, woT[0], outX[0], nullptr, nullptr, flag, S, 1024, 1024);
    gemm_mfma<64, 128, 1, 4, 2><<<dim3(1024 / 128, S / 64), 256, 0, stream>>>(
        mixed + E_SH, woT[1], outX[1], nullptr, nullptr, flag, S, 1024, 1024);

    store_out_kernel<<<(2 * E_SH) / 256, 256, 0, stream>>>(outX[0], outX[1], d_out, flag);
}

// Round 4
// 1004.643 us; speedup vs baseline: 1.4099x; 1.4099x over previous
//
#include <hip/hip_runtime.h>
#include <hip/hip_bf16.h>
#include <math.h>

#define S 2048
#define HID 1024
#define NH 8
#define HD 128
#define INTER 4096
#define EPSV 1e-6f
#define THETA 10000.0f

typedef __hip_bfloat16 bf16;
typedef unsigned short u16;
typedef __attribute__((ext_vector_type(8))) short bf16x8;  // 8 bf16 = 4 VGPRs
typedef __attribute__((ext_vector_type(4))) float f32x4;

__device__ inline float bu2f(u16 u) {
    unsigned int x = ((unsigned int)u) << 16;
    return __uint_as_float(x);
}
__device__ inline u16 f2bu(float f) {
    bf16 h = __float2bfloat16(f);
    return *reinterpret_cast<u16*>(&h);
}
// Dual-dtype input load (raw harness inputs): isbf ? bf16 : f32
__device__ inline float ldin(const void* p, size_t i, bool isbf) {
    return isbf ? bu2f(((const u16*)p)[i]) : ((const float*)p)[i];
}
__device__ inline float gelu_tanh(float x) {
    float x3 = x * x * x;
    return 0.5f * x * (1.f + tanhf(0.7978845608028654f * (x + 0.044715f * x3)));
}
// Direct global->LDS 16B/lane async copy. LDS dest must be wave-uniform;
// lane i's 16B lands at ldsbase + i*16. Global source IS per-lane.
__device__ inline void gload16(const u16* g, u16* l) {
    __builtin_amdgcn_global_load_lds(
        (const __attribute__((address_space(1))) void*)g,
        (__attribute__((address_space(3))) void*)l, 16, 0, 0);
}

// ---------------- dtype probe (round-1 notes) ----------------
__global__ __launch_bounds__(256) void probe_kernel(const unsigned short* __restrict__ x,
                                                    int* __restrict__ flag) {
    __shared__ int red[256];
    int tid = threadIdx.x;
    int cnt = 0;
    for (int i = tid; i < 2048; i += 256) {
        unsigned short u = x[2 * i];
        int e = (u >> 7) & 0xFF;
        cnt += (e >= 110 && e <= 135) ? 1 : 0;
    }
    red[tid] = cnt;
    __syncthreads();
    for (int off = 128; off > 0; off >>= 1) {
        if (tid < off) red[tid] += red[tid + off];
        __syncthreads();
    }
    if (tid == 0) *flag = (red[0] > 1024) ? 1 : 0;
}

// ---------------- weight transpose+convert: W (KxN, input dtype) -> WT (NxK, bf16) ----------------
__global__ __launch_bounds__(256) void transpose_w(const void* __restrict__ W,
                                                   u16* __restrict__ WT,
                                                   const int* __restrict__ flag,
                                                   int K, int N) {
    bool isbf = (*flag != 0);
    __shared__ float t[32][33];
    int n0 = blockIdx.x * 32, k0 = blockIdx.y * 32;
    int c = threadIdx.x & 31, r = threadIdx.x >> 5;
#pragma unroll
    for (int p = 0; p < 4; p++)
        t[r + 8 * p][c] = ldin(W, (size_t)(k0 + r + 8 * p) * N + n0 + c, isbf);
    __syncthreads();
#pragma unroll
    for (int p = 0; p < 4; p++) {
        int row = r + 8 * p;
        WT[(size_t)(n0 + row) * K + k0 + c] = f2bu(t[c][row]);
    }
}

// ---------------- V transpose: V[key][dh] (stride sv, bf16) -> VT[dh][key] (2048 keys) ----------------
__global__ __launch_bounds__(256) void transpose_v(const u16* __restrict__ V, int sv,
                                                   u16* __restrict__ VT) {
    __shared__ u16 t[32][33];
    int k0 = blockIdx.x * 32;  // key tile
    int d0 = blockIdx.y * 32;  // dh tile
    int c = threadIdx.x & 31, r = threadIdx.x >> 5;
#pragma unroll
    for (int p = 0; p < 4; p++)
        t[r + 8 * p][c] = V[(size_t)(k0 + r + 8 * p) * sv + d0 + c];
    __syncthreads();
#pragma unroll
    for (int p = 0; p < 4; p++)
        VT[(size_t)(d0 + r + 8 * p) * S + k0 + c] = t[c][r + 8 * p];
}

// ---------------- RMSNorm -> bf16 ----------------
__global__ __launch_bounds__(256) void rmsnorm_kernel(const void* __restrict__ x,
                                                      const void* __restrict__ w,
                                                      u16* __restrict__ y,
                                                      const int* __restrict__ flag,
                                                      int dual) {
    bool isbf = (*flag != 0);
    bool xbf = dual && isbf;
    int row = blockIdx.x;
    size_t base = (size_t)row * HID;
    __shared__ float red[256];
    float xv[4];
    float s = 0.f;
#pragma unroll
    for (int i = 0; i < 4; i++) {
        float v = ldin(x, base + threadIdx.x + 256 * i, xbf);
        xv[i] = v;
        s += v * v;
    }
    red[threadIdx.x] = s;
    __syncthreads();
    for (int off = 128; off > 0; off >>= 1) {
        if (threadIdx.x < off) red[threadIdx.x] += red[threadIdx.x + off];
        __syncthreads();
    }
    float scale = rsqrtf(red[0] / (float)HID + EPSV);
#pragma unroll
    for (int i = 0; i < 4; i++) {
        int c = threadIdx.x + 256 * i;
        y[base + c] = f2bu(xv[i] * scale * (1.f + ldin(w, c, isbf)));
    }
}

// ================= MFMA GEMM (v2: global_load_lds staging, XOR-swizzled LDS) =================
// LDS tiles are LINEAR [row][64B] (BK=32 bf16 per row). global_load_lds writes lane-linear,
// so the XOR swizzle (chunk ^= (row>>1)&3, 16B chunks within the 64B row) is applied on the
// per-lane GLOBAL SOURCE address at load time and again on the frag-read address (involution).
// Spreads the 16-row b128 column reads over 8 bank groups (2 lanes/bank = free).
template <int BM, int BN, int WRN, int WCN, int EPI>
__global__ __launch_bounds__(256) void gemm_mfma(const u16* __restrict__ A,
                                                 const u16* __restrict__ BT,
                                                 float* __restrict__ Cf,
                                                 u16* __restrict__ Cb,
                                                 const void* __restrict__ res,
                                                 const int* __restrict__ flag,
                                                 int M, int N, int K) {
    constexpr int BK = 32;
    constexpr int WM = BM / WRN, WN = BN / WCN, TI = WM / 16, TJ = WN / 16;
    __shared__ u16 As[BM * 32];
    __shared__ u16 Bs[BN * 32];
    int tid = threadIdx.x, lane = tid & 63, wv = tid >> 6;
    int wr = wv / WCN, wc = wv % WCN;
    int m = lane & 15, quad = lane >> 4;
    int m0 = blockIdx.y * BM, n0 = blockIdx.x * BN;
    f32x4 acc[TI][TJ] = {};
    for (int k0 = 0; k0 < K; k0 += BK) {
        __syncthreads();  // prev compute done reading LDS
#pragma unroll
        for (int c2 = 0; c2 < BM / 64; c2++) {
            int row0 = (wv * (BM / 64) + c2) * 16;
            int row = row0 + (lane >> 2);
            int ch = lane & 3;
            gload16(&A[(size_t)(m0 + row) * K + k0 + ((ch ^ ((row >> 1) & 3)) << 3)],
                    &As[row0 * 32]);
        }
#pragma unroll
        for (int c2 = 0; c2 < BN / 64; c2++) {
            int row0 = (wv * (BN / 64) + c2) * 16;
            int row = row0 + (lane >> 2);
            int ch = lane & 3;
            gload16(&BT[(size_t)(n0 + row) * K + k0 + ((ch ^ ((row >> 1) & 3)) << 3)],
                    &Bs[row0 * 32]);
        }
        __syncthreads();  // vmcnt drained by barrier -> tiles in LDS
        bf16x8 af[TI], bf_[TJ];
#pragma unroll
        for (int i = 0; i < TI; i++) {
            int rr = wr * WM + i * 16 + m;
            af[i] = *reinterpret_cast<const bf16x8*>(&As[rr * 32 + ((quad ^ ((rr >> 1) & 3)) << 3)]);
        }
#pragma unroll
        for (int j = 0; j < TJ; j++) {
            int rr = wc * WN + j * 16 + m;
            bf_[j] = *reinterpret_cast<const bf16x8*>(&Bs[rr * 32 + ((quad ^ ((rr >> 1) & 3)) << 3)]);
        }
#pragma unroll
        for (int i = 0; i < TI; i++)
#pragma unroll
            for (int j = 0; j < TJ; j++)
                acc[i][j] = __builtin_amdgcn_mfma_f32_16x16x32_bf16(af[i], bf_[j], acc[i][j], 0, 0, 0);
    }
    bool isbf = (EPI == 1) ? (*flag != 0) : false;
#pragma unroll
    for (int i = 0; i < TI; i++) {
#pragma unroll
        for (int j = 0; j < TJ; j++) {
#pragma unroll
            for (int r = 0; r < 4; r++) {
                int row = m0 + wr * WM + i * 16 + quad * 4 + r;
                int col = n0 + wc * WN + j * 16 + m;
                size_t idx = (size_t)row * N + col;
                float v = acc[i][j][r];
                if (EPI == 0) Cb[idx] = f2bu(v);
                else if (EPI == 1) Cf[idx] = v + ldin(res, idx, isbf);
                else Cf[idx] = Cf[idx] + v;
            }
        }
    }
}

// ------------- Fused gated MLP MFMA: C(bf16) = gelu(A@Wg) * (A@Wu) -------------
template <int BM, int BN, int WRN, int WCN>
__global__ __launch_bounds__(256) void gemm_gated_mfma(const u16* __restrict__ A,
                                                       const u16* __restrict__ BgT,
                                                       const u16* __restrict__ BuT,
                                                       u16* __restrict__ C,
                                                       int M, int N, int K) {
    constexpr int BK = 32;
    constexpr int WM = BM / WRN, WN = BN / WCN, TI = WM / 16, TJ = WN / 16;
    __shared__ u16 As[BM * 32];
    __shared__ u16 Bgs[BN * 32];
    __shared__ u16 Bus[BN * 32];
    int tid = threadIdx.x, lane = tid & 63, wv = tid >> 6;
    int wr = wv / WCN, wc = wv % WCN;
    int m = lane & 15, quad = lane >> 4;
    int m0 = blockIdx.y * BM, n0 = blockIdx.x * BN;
    f32x4 accg[TI][TJ] = {};
    f32x4 accu[TI][TJ] = {};
    for (int k0 = 0; k0 < K; k0 += BK) {
        __syncthreads();
#pragma unroll
        for (int c2 = 0; c2 < BM / 64; c2++) {
            int row0 = (wv * (BM / 64) + c2) * 16;
            int row = row0 + (lane >> 2);
            int ch = lane & 3;
            gload16(&A[(size_t)(m0 + row) * K + k0 + ((ch ^ ((row >> 1) & 3)) << 3)],
                    &As[row0 * 32]);
        }
#pragma unroll
        for (int c2 = 0; c2 < BN / 64; c2++) {
            int row0 = (wv * (BN / 64) + c2) * 16;
            int row = row0 + (lane >> 2);
            int ch = lane & 3;
            gload16(&BgT[(size_t)(n0 + row) * K + k0 + ((ch ^ ((row >> 1) & 3)) << 3)],
                    &Bgs[row0 * 32]);
            gload16(&BuT[(size_t)(n0 + row) * K + k0 + ((ch ^ ((row >> 1) & 3)) << 3)],
                    &Bus[row0 * 32]);
        }
        __syncthreads();
        bf16x8 af[TI], bg[TJ], bu[TJ];
#pragma unroll
        for (int i = 0; i < TI; i++) {
            int rr = wr * WM + i * 16 + m;
            af[i] = *reinterpret_cast<const bf16x8*>(&As[rr * 32 + ((quad ^ ((rr >> 1) & 3)) << 3)]);
        }
#pragma unroll
        for (int j = 0; j < TJ; j++) {
            int rr = wc * WN + j * 16 + m;
            int off = rr * 32 + ((quad ^ ((rr >> 1) & 3)) << 3);
            bg[j] = *reinterpret_cast<const bf16x8*>(&Bgs[off]);
            bu[j] = *reinterpret_cast<const bf16x8*>(&Bus[off]);
        }
#pragma unroll
        for (int i = 0; i < TI; i++)
#pragma unroll
            for (int j = 0; j < TJ; j++) {
                accg[i][j] = __builtin_amdgcn_mfma_f32_16x16x32_bf16(af[i], bg[j], accg[i][j], 0, 0, 0);
                accu[i][j] = __builtin_amdgcn_mfma_f32_16x16x32_bf16(af[i], bu[j], accu[i][j], 0, 0, 0);
            }
    }
#pragma unroll
    for (int i = 0; i < TI; i++)
#pragma unroll
        for (int j = 0; j < TJ; j++)
#pragma unroll
            for (int r = 0; r < 4; r++) {
                int row = m0 + wr * WM + i * 16 + quad * 4 + r;
                int col = n0 + wc * WN + j * 16 + m;
                C[(size_t)row * N + col] = f2bu(gelu_tanh(accg[i][j][r]) * accu[i][j][r]);
            }
}

// ---------------- RoPE: read qkv (bf16, stride 3072), write qr/kr (bf16, stride 1024) ----------------
__global__ __launch_bounds__(64) void rope_kernel(const u16* __restrict__ qkv,
                                                  u16* __restrict__ qr,
                                                  u16* __restrict__ kr) {
    int b = blockIdx.x;
    int t = b >> 3, h = b & 7;
    int i = threadIdx.x;  // 0..63
    size_t ib = (size_t)t * 3072 + h * HD;
    size_t ob = (size_t)t * HID + h * HD;
    float inv = powf(THETA, -(float)(2 * i) / (float)HD);
    float f = (float)t * inv;
    float c = cosf(f), s = sinf(f);
    float q1 = bu2f(qkv[ib + i]), q2 = bu2f(qkv[ib + i + 64]);
    qr[ob + i] = f2bu(q1 * c - q2 * s);
    qr[ob + i + 64] = f2bu(q2 * c + q1 * s);
    float k1 = bu2f(qkv[ib + 1024 + i]), k2 = bu2f(qkv[ib + 1024 + i + 64]);
    kr[ob + i] = f2bu(k1 * c - k2 * s);
    kr[ob + i + 64] = f2bu(k2 * c + k1 * s);
}

// ============ MFMA flash attention (round-1 verified structure) ============
// Swapped QK^T (sc = mfma(K,Q)), per-lane in-register softmax, bpermute P
// redistribution, XOR-swizzled 32KB LDS. T14 register prefetch REVERTED:
// round-2 counters showed the prefetch arrays were demoted to scratch
// (WRITE_SIZE 8MB -> 614MB, 2.5x slowdown). Causal blocks run longest-first.
__device__ inline int swz64(int row, int b) {
    return row * 64 + (b ^ (((row >> 1) & 3) << 4));
}

template <bool CAUSAL>
__global__ __launch_bounds__(256, 4) void attn_mfma_kernel(
    const u16* __restrict__ qa, const u16* __restrict__ qb, int sq,
    const u16* __restrict__ ka, const u16* __restrict__ kb, int sk,
    const u16* __restrict__ vta, const u16* __restrict__ vtb,
    u16* __restrict__ Out, int nkeys) {
    __shared__ char Ks[4 * 64 * 64];    // [t=d/32][key 0..63][32 d], swizzled 64B rows
    __shared__ char VTs[2 * 128 * 64];  // [ks=key/32][d 0..127][32 keys], swizzled

    int tid = threadIdx.x;
    int lane = tid & 63, w = tid >> 6;
    int col = lane & 15, quad = lane >> 4;
    // Causal: longest blocks (largest q0) first to reduce makespan tail.
    int bx = CAUSAL ? ((int)gridDim.x - 1 - (int)blockIdx.x) : (int)blockIdx.x;
    int q0 = bx * 64;
    int h = blockIdx.y;
    const float scale = 0.08838834764831845f;  // 1/sqrt(128)

    // Q b-frags (4 d-steps of 32) straight from global into registers
    int q0r = CAUSAL ? q0 : (q0 & (S - 1));
    const u16* qp = ((CAUSAL || q0 < S) ? qa : qb) + (size_t)q0r * sq;
    bf16x8 aq[4];
#pragma unroll
    for (int t = 0; t < 4; t++)
        aq[t] = *reinterpret_cast<const bf16x8*>(
            qp + (size_t)(16 * w + col) * sq + h * HD + 32 * t + quad * 8);

    f32x4 o[8] = {};           // O^T: o[nt][r] = O[q][d = 16nt + 4quad + r]
    float m_ = -1e30f, l_ = 0.f;

    // bpermute source lanes for P redistribution:
    // target quad t needs pu[2ks + (t>>1)] from source quads 2(t&1) and 2(t&1)+1.
    int sA = col + 16 * (2 * (quad & 1));
    int sB = sA + 16;
    bool hi = (quad >> 1) != 0;

    int ntiles = CAUSAL ? (q0 >> 6) + 1 : (nkeys >> 6);
    for (int tt = 0; tt < ntiles; tt++) {
        int j0 = tt * 64;
        int j0r = j0 & (S - 1);
        bool eb = (!CAUSAL) && (j0 >= S);
        const u16* kp = eb ? kb : ka;
        const u16* vp = eb ? vtb : vta;
        __syncthreads();  // prev iter's compute done before restaging
        // ---- stage K tile: 64 keys x 128 d ----
#pragma unroll
        for (int i = 0; i < 4; i++) {
            int l = tid + 256 * i;
            int key = l >> 4, c = l & 15;
            int t = c >> 2, kq = c & 3;
            *reinterpret_cast<uint4*>(&Ks[t * 4096 + swz64(key, kq * 16)]) =
                *reinterpret_cast<const uint4*>(kp + (size_t)(j0r + key) * sk + h * HD + c * 8);
        }
        // ---- stage V^T tile: 128 d x 64 keys ----
#pragma unroll
        for (int i = 0; i < 4; i++) {
            int l = tid + 256 * i;
            int d = l >> 3, c = l & 7;
            int ks = c >> 2, kq = c & 3;
            *reinterpret_cast<uint4*>(&VTs[ks * 8192 + swz64(d, kq * 16)]) =
                *reinterpret_cast<const uint4*>(vp + (size_t)(h * HD + d) * S + j0r + c * 8);
        }
        __syncthreads();

        // ---- QK^T (swapped): wave computes 64k x 16q ----
        f32x4 sc[4] = {};
        __builtin_amdgcn_s_setprio(1);
#pragma unroll
        for (int t = 0; t < 4; t++) {
#pragma unroll
            for (int ct = 0; ct < 4; ct++) {
                bf16x8 kf = *reinterpret_cast<const bf16x8*>(
                    &Ks[t * 4096 + swz64(16 * ct + col, quad * 16)]);
                sc[ct] = __builtin_amdgcn_mfma_f32_16x16x32_bf16(kf, aq[t], sc[ct], 0, 0, 0);
            }
        }
        __builtin_amdgcn_s_setprio(0);
        bool diag = CAUSAL && (j0 == q0);
#pragma unroll
        for (int ct = 0; ct < 4; ct++) {
#pragma unroll
            for (int r = 0; r < 4; r++) {
                float v = sc[ct][r] * scale;
                if (diag && (16 * ct + 4 * quad + r > 16 * w + col)) v = -1e30f;
                sc[ct][r] = v;
            }
        }

        // ---- per-lane online softmax (one query per lane) ----
        float mx0 = fmaxf(fmaxf(sc[0][0], sc[0][1]), fmaxf(sc[0][2], sc[0][3]));
        float mx1 = fmaxf(fmaxf(sc[1][0], sc[1][1]), fmaxf(sc[1][2], sc[1][3]));
        float mx2 = fmaxf(fmaxf(sc[2][0], sc[2][1]), fmaxf(sc[2][2], sc[2][3]));
        float mx3 = fmaxf(fmaxf(sc[3][0], sc[3][1]), fmaxf(sc[3][2], sc[3][3]));
        float rmax = fmaxf(fmaxf(mx0, mx1), fmaxf(mx2, mx3));
        rmax = fmaxf(rmax, __shfl_xor(rmax, 16));
        rmax = fmaxf(rmax, __shfl_xor(rmax, 32));
        float mn = fmaxf(m_, rmax);
        float al = __expf(m_ - mn);
#pragma unroll
        for (int ct = 0; ct < 4; ct++)
#pragma unroll
            for (int r = 0; r < 4; r++) sc[ct][r] = __expf(sc[ct][r] - mn);
        float s0 = (sc[0][0] + sc[0][1]) + (sc[0][2] + sc[0][3]);
        float s1 = (sc[1][0] + sc[1][1]) + (sc[1][2] + sc[1][3]);
        float s2 = (sc[2][0] + sc[2][1]) + (sc[2][2] + sc[2][3]);
        float s3 = (sc[3][0] + sc[3][1]) + (sc[3][2] + sc[3][3]);
        float rs = (s0 + s1) + (s2 + s3);
        rs += __shfl_xor(rs, 16);
        rs += __shfl_xor(rs, 32);
        l_ = l_ * al + rs;
        m_ = mn;

        // ---- pack P^T to bf16 pairs: pu[ct] covers keys 16ct+4quad+{0..3} ----
        unsigned int pu[4][2];
#pragma unroll
        for (int ct = 0; ct < 4; ct++) {
            pu[ct][0] = (unsigned int)f2bu(sc[ct][0]) | ((unsigned int)f2bu(sc[ct][1]) << 16);
            pu[ct][1] = (unsigned int)f2bu(sc[ct][2]) | ((unsigned int)f2bu(sc[ct][3]) << 16);
        }

        // ---- O^T rescale ----
#pragma unroll
        for (int nt = 0; nt < 8; nt++)
#pragma unroll
            for (int r = 0; r < 4; r++) o[nt][r] *= al;

        // ---- PV: O^T += V^T @ P^T; b-frag gathered via bpermute ----
#pragma unroll
        for (int ks = 0; ks < 2; ks++) {
            unsigned int a0 = __shfl(pu[2 * ks][0], sA);
            unsigned int a1 = __shfl(pu[2 * ks][1], sA);
            unsigned int c0 = __shfl(pu[2 * ks + 1][0], sA);
            unsigned int c1 = __shfl(pu[2 * ks + 1][1], sA);
            unsigned int b0 = __shfl(pu[2 * ks][0], sB);
            unsigned int b1 = __shfl(pu[2 * ks][1], sB);
            unsigned int g0 = __shfl(pu[2 * ks + 1][0], sB);
            unsigned int g1 = __shfl(pu[2 * ks + 1][1], sB);
            union {
                unsigned int u[4];
                bf16x8 v;
            } pb;
            pb.u[0] = hi ? c0 : a0;
            pb.u[1] = hi ? c1 : a1;
            pb.u[2] = hi ? g0 : b0;
            pb.u[3] = hi ? g1 : b1;
            __builtin_amdgcn_s_setprio(1);
#pragma unroll
            for (int nt = 0; nt < 8; nt++) {
                bf16x8 vf = *reinterpret_cast<const bf16x8*>(
                    &VTs[ks * 8192 + swz64(16 * nt + col, quad * 16)]);
                o[nt] = __builtin_amdgcn_mfma_f32_16x16x32_bf16(vf, pb.v, o[nt], 0, 0, 0);
            }
            __builtin_amdgcn_s_setprio(0);
        }
    }

    // ---- epilogue: O /= l, write bf16 (stride HID); r-values are contiguous in d ----
    float inv = 1.f / l_;
    size_t rowoff = (size_t)(q0 + 16 * w + col) * HID + (size_t)h * HD + 4 * quad;
#pragma unroll
    for (int nt = 0; nt < 8; nt++) {
        ushort4 st;
        st.x = f2bu(o[nt][0] * inv);
        st.y = f2bu(o[nt][1] * inv);
        st.z = f2bu(o[nt][2] * inv);
        st.w = f2bu(o[nt][3] * inv);
        *reinterpret_cast<ushort4*>(&Out[rowoff + 16 * nt]) = st;
    }
}

// ---------------- f32 -> output dtype (per flag) ----------------
__global__ __launch_bounds__(256) void store_out_kernel(const float* __restrict__ a,
                                                        const float* __restrict__ b,
                                                        void* __restrict__ out,
                                                        const int* __restrict__ flag) {
    bool isbf = (*flag != 0);
    size_t i = (size_t)blockIdx.x * 256 + threadIdx.x;
    const size_t MM = (size_t)S * HID;
    float v = (i < MM) ? a[i] : b[i - MM];
    if (isbf)
        ((bf16*)out)[i] = __float2bfloat16(v);
    else
        ((float*)out)[i] = v;
}

extern "C" void kernel_launch(void* const* d_in, const int* in_sizes, int n_in,
                              void* d_out, int out_size, void* d_ws, size_t ws_size,
                              hipStream_t stream) {
    const void* x[2] = {d_in[0], d_in[1]};
    const void* w_ln[2] = {d_in[5], d_in[14]};
    const void* w_q[2] = {d_in[6], d_in[15]};
    const void* w_k[2] = {d_in[7], d_in[16]};
    const void* w_v[2] = {d_in[8], d_in[17]};
    const void* w_o[2] = {d_in[9], d_in[18]};
    const void* w_pln[2] = {d_in[10], d_in[19]};
    const void* w_g[2] = {d_in[11], d_in[20]};
    const void* w_u[2] = {d_in[12], d_in[21]};
    const void* w_d[2] = {d_in[13], d_in[22]};

    char* base = (char*)d_ws;
    int* flag = (int*)base;
    u16* p = (u16*)(base + 256);
    const size_t E_QKV = (size_t)S * 3072;
    const size_t E_SH = (size_t)S * HID;
    const size_t E_GT = (size_t)S * INTER;
    const size_t E_VT = (size_t)NH * HD * S;  // 2.1M u16 per expert

    u16* qkv[2] = {p, p + E_QKV};            p += 2 * E_QKV;
    u16* qr = p;                             p += E_SH;
    u16* kr = p;                             p += E_SH;
    u16* h_bf = p;                           p += E_SH;
    u16* attnbuf = p;                        p += E_SH;
    u16* vtg[2] = {p, p + E_VT};             p += 2 * E_VT;
    u16* gated = p;                          p += E_GT;  // mixed overlays gated
    u16* mixed = gated;
    u16* wqkvT = p;                          p += (size_t)3072 * 1024;
    u16* woT[2] = {p, p + (size_t)1024 * 1024};  p += 2 * (size_t)1024 * 1024;
    u16* wgT = p;                            p += (size_t)INTER * 1024;
    u16* wuT = p;                            p += (size_t)INTER * 1024;
    u16* wdT = p;                            p += (size_t)1024 * INTER;
    float* fbase = (float*)(((size_t)p + 255) & ~(size_t)255);
    float* outX[2] = {fbase, fbase + E_SH};

    probe_kernel<<<1, 256, 0, stream>>>((const unsigned short*)d_in[0], flag);

    for (int e = 0; e < 2; e++) {
        transpose_w<<<dim3(1024 / 32, 1024 / 32), 256, 0, stream>>>(w_q[e], wqkvT, flag, 1024, 1024);
        transpose_w<<<dim3(1024 / 32, 1024 / 32), 256, 0, stream>>>(w_k[e], wqkvT + (size_t)1024 * 1024, flag, 1024, 1024);
        transpose_w<<<dim3(1024 / 32, 1024 / 32), 256, 0, stream>>>(w_v[e], wqkvT + (size_t)2048 * 1024, flag, 1024, 1024);
        transpose_w<<<dim3(1024 / 32, 1024 / 32), 256, 0, stream>>>(w_o[e], woT[e], flag, 1024, 1024);
        transpose_w<<<dim3(INTER / 32, 1024 / 32), 256, 0, stream>>>(w_g[e], wgT, flag, 1024, INTER);
        transpose_w<<<dim3(INTER / 32, 1024 / 32), 256, 0, stream>>>(w_u[e], wuT, flag, 1024, INTER);
        transpose_w<<<dim3(1024 / 32, INTER / 32), 256, 0, stream>>>(w_d[e], wdT, flag, INTER, 1024);

        rmsnorm_kernel<<<S, 256, 0, stream>>>(x[e], w_ln[e], h_bf, flag, 1);
        gemm_mfma<128, 128, 2, 2, 0><<<dim3(3072 / 128, S / 128), 256, 0, stream>>>(
            h_bf, wqkvT, nullptr, qkv[e], nullptr, flag, S, 3072, 1024);
        rope_kernel<<<S * NH, 64, 0, stream>>>(qkv[e], qr, kr);
        transpose_v<<<dim3(S / 32, 1024 / 32), 256, 0, stream>>>(qkv[e] + 2048, 3072, vtg[e]);
        attn_mfma_kernel<true><<<dim3(S / 64, NH), 256, 0, stream>>>(
            qr, qr, HID, kr, kr, HID, vtg[e], vtg[e], attnbuf, S);
        gemm_mfma<64, 128, 1, 4, 1><<<dim3(1024 / 128, S / 64), 256, 0, stream>>>(
            attnbuf, woT[e], outX[e], nullptr, x[e], flag, S, 1024, 1024);
        rmsnorm_kernel<<<S, 256, 0, stream>>>(outX[e], w_pln[e], h_bf, flag, 0);
        gemm_gated_mfma<128, 64, 2, 2><<<dim3(INTER / 64, S / 128), 256, 0, stream>>>(
            h_bf, wgT, wuT, gated, S, INTER, 1024);
        gemm_mfma<64, 128, 1, 4, 2><<<dim3(1024 / 128, S / 64), 256, 0, stream>>>(
            gated, wdT, outX[e], nullptr, nullptr, flag, S, 1024, INTER);
    }

    attn_mfma_kernel<false><<<dim3(2 * S / 64, NH), 256, 0, stream>>>(
        qkv[0], qkv[1], 3072, qkv[0] + 1024, qkv[1] + 1024, 3072,
        vtg[0], vtg[1], mixed, 2 * S);
    gemm_mfma<64, 128, 1, 4, 2><<<dim3(1024 / 128, S / 64), 256, 0, stream>>>(
        mixed, woT[0], outX[0], nullptr, nullptr, flag, S, 1024, 1024);
    gemm_mfma<64, 128, 1, 4, 2><<<dim3(1024 / 128, S / 64), 256, 0, stream>>>(
        mixed + E_SH, woT[1], outX[1], nullptr, nullptr, flag, S, 1024, 1024);

    store_out_kernel<<<(2 * E_SH) / 256, 256, 0, stream>>>(outX[0], outX[1], d_out, flag);
}

// Round 5
// 874.326 us; speedup vs baseline: 1.6200x; 1.1490x over previous
//
#include <hip/hip_runtime.h>
#include <hip/hip_bf16.h>
#include <math.h>

#define S 2048
#define HID 1024
#define NH 8
#define HD 128
#define INTER 4096
#define EPSV 1e-6f
#define THETA 10000.0f

typedef __hip_bfloat16 bf16;
typedef unsigned short u16;
typedef __attribute__((ext_vector_type(8))) short bf16x8;  // 8 bf16 = 4 VGPRs
typedef __attribute__((ext_vector_type(4))) float f32x4;

__device__ inline float bu2f(u16 u) {
    unsigned int x = ((unsigned int)u) << 16;
    return __uint_as_float(x);
}
__device__ inline u16 f2bu(float f) {
    bf16 h = __float2bfloat16(f);
    return *reinterpret_cast<u16*>(&h);
}
// Dual-dtype input load (raw harness inputs): isbf ? bf16 : f32
__device__ inline float ldin(const void* p, size_t i, bool isbf) {
    return isbf ? bu2f(((const u16*)p)[i]) : ((const float*)p)[i];
}
__device__ inline float gelu_tanh(float x) {
    float x3 = x * x * x;
    return 0.5f * x * (1.f + tanhf(0.7978845608028654f * (x + 0.044715f * x3)));
}
// Direct global->LDS 16B/lane async copy. LDS dest must be wave-uniform;
// lane i's 16B lands at ldsbase + i*16. Global source IS per-lane.
__device__ inline void gload16(const u16* g, u16* l) {
    __builtin_amdgcn_global_load_lds(
        (const __attribute__((address_space(1))) void*)g,
        (__attribute__((address_space(3))) void*)l, 16, 0, 0);
}

// ---------------- dtype probe (round-1 notes) ----------------
__global__ __launch_bounds__(256) void probe_kernel(const unsigned short* __restrict__ x,
                                                    int* __restrict__ flag) {
    __shared__ int red[256];
    int tid = threadIdx.x;
    int cnt = 0;
    for (int i = tid; i < 2048; i += 256) {
        unsigned short u = x[2 * i];
        int e = (u >> 7) & 0xFF;
        cnt += (e >= 110 && e <= 135) ? 1 : 0;
    }
    red[tid] = cnt;
    __syncthreads();
    for (int off = 128; off > 0; off >>= 1) {
        if (tid < off) red[tid] += red[tid + off];
        __syncthreads();
    }
    if (tid == 0) *flag = (red[0] > 1024) ? 1 : 0;
}

// ---------------- weight transpose+convert: W (KxN, input dtype) -> WT (NxK, bf16) ----------------
__global__ __launch_bounds__(256) void transpose_w(const void* __restrict__ W,
                                                   u16* __restrict__ WT,
                                                   const int* __restrict__ flag,
                                                   int K, int N) {
    bool isbf = (*flag != 0);
    __shared__ float t[32][33];
    int n0 = blockIdx.x * 32, k0 = blockIdx.y * 32;
    int c = threadIdx.x & 31, r = threadIdx.x >> 5;
#pragma unroll
    for (int p = 0; p < 4; p++)
        t[r + 8 * p][c] = ldin(W, (size_t)(k0 + r + 8 * p) * N + n0 + c, isbf);
    __syncthreads();
#pragma unroll
    for (int p = 0; p < 4; p++) {
        int row = r + 8 * p;
        WT[(size_t)(n0 + row) * K + k0 + c] = f2bu(t[c][row]);
    }
}

// ---------------- V transpose (dual-expert via z): V[key][dh] -> VT[dh][key] ----------------
__global__ __launch_bounds__(256) void transpose_v(const u16* __restrict__ V0,
                                                   const u16* __restrict__ V1, int sv,
                                                   u16* __restrict__ VT) {
    const u16* V = blockIdx.z ? V1 : V0;
    VT += (size_t)blockIdx.z * ((size_t)NH * HD * S);
    __shared__ u16 t[32][33];
    int k0 = blockIdx.x * 32;  // key tile
    int d0 = blockIdx.y * 32;  // dh tile
    int c = threadIdx.x & 31, r = threadIdx.x >> 5;
#pragma unroll
    for (int p = 0; p < 4; p++)
        t[r + 8 * p][c] = V[(size_t)(k0 + r + 8 * p) * sv + d0 + c];
    __syncthreads();
#pragma unroll
    for (int p = 0; p < 4; p++)
        VT[(size_t)(d0 + r + 8 * p) * S + k0 + c] = t[c][r + 8 * p];
}

// ---------------- RMSNorm -> bf16 (dual-expert via blockIdx.y) ----------------
struct RmsDual {
    const void* x[2];
    const void* w[2];
    u16* y[2];
};
__global__ __launch_bounds__(256) void rmsnorm_kernel(RmsDual rd,
                                                      const int* __restrict__ flag,
                                                      int dual) {
    int e = blockIdx.y;
    const void* x = rd.x[e];
    const void* w = rd.w[e];
    u16* y = rd.y[e];
    bool isbf = (*flag != 0);
    bool xbf = dual && isbf;
    int row = blockIdx.x;
    size_t base = (size_t)row * HID;
    __shared__ float red[256];
    float xv[4];
    float s = 0.f;
#pragma unroll
    for (int i = 0; i < 4; i++) {
        float v = ldin(x, base + threadIdx.x + 256 * i, xbf);
        xv[i] = v;
        s += v * v;
    }
    red[threadIdx.x] = s;
    __syncthreads();
    for (int off = 128; off > 0; off >>= 1) {
        if (threadIdx.x < off) red[threadIdx.x] += red[threadIdx.x + off];
        __syncthreads();
    }
    float scale = rsqrtf(red[0] / (float)HID + EPSV);
#pragma unroll
    for (int i = 0; i < 4; i++) {
        int c = threadIdx.x + 256 * i;
        y[base + c] = f2bu(xv[i] * scale * (1.f + ldin(w, c, isbf)));
    }
}

// ================= MFMA GEMM (v3: gload16 staging + dual-expert via blockIdx.z) =================
// LDS tiles are LINEAR [row][64B] (BK=32 bf16 per row). global_load_lds writes lane-linear,
// so the XOR swizzle (chunk ^= (row>>1)&3, 16B chunks within the 64B row) is applied on the
// per-lane GLOBAL SOURCE address at load time and again on the frag-read address (involution).
struct GemmDual {
    const u16* A[2];
    const u16* BT[2];
    float* Cf[2];
    u16* Cb[2];
    const void* res[2];
};
template <int BM, int BN, int WRN, int WCN, int EPI>
__global__ __launch_bounds__(256) void gemm_mfma(GemmDual g, const int* __restrict__ flag,
                                                 int M, int N, int K) {
    int eZ = blockIdx.z;
    const u16* __restrict__ A = g.A[eZ];
    const u16* __restrict__ BT = g.BT[eZ];
    float* __restrict__ Cf = g.Cf[eZ];
    u16* __restrict__ Cb = g.Cb[eZ];
    const void* __restrict__ res = g.res[eZ];
    constexpr int BK = 32;
    constexpr int WM = BM / WRN, WN = BN / WCN, TI = WM / 16, TJ = WN / 16;
    __shared__ u16 As[BM * 32];
    __shared__ u16 Bs[BN * 32];
    int tid = threadIdx.x, lane = tid & 63, wv = tid >> 6;
    int wr = wv / WCN, wc = wv % WCN;
    int m = lane & 15, quad = lane >> 4;
    int m0 = blockIdx.y * BM, n0 = blockIdx.x * BN;
    f32x4 acc[TI][TJ] = {};
    for (int k0 = 0; k0 < K; k0 += BK) {
        __syncthreads();  // prev compute done reading LDS
#pragma unroll
        for (int c2 = 0; c2 < BM / 64; c2++) {
            int row0 = (wv * (BM / 64) + c2) * 16;
            int row = row0 + (lane >> 2);
            int ch = lane & 3;
            gload16(&A[(size_t)(m0 + row) * K + k0 + ((ch ^ ((row >> 1) & 3)) << 3)],
                    &As[row0 * 32]);
        }
#pragma unroll
        for (int c2 = 0; c2 < BN / 64; c2++) {
            int row0 = (wv * (BN / 64) + c2) * 16;
            int row = row0 + (lane >> 2);
            int ch = lane & 3;
            gload16(&BT[(size_t)(n0 + row) * K + k0 + ((ch ^ ((row >> 1) & 3)) << 3)],
                    &Bs[row0 * 32]);
        }
        __syncthreads();  // vmcnt drained by barrier -> tiles in LDS
        bf16x8 af[TI], bf_[TJ];
#pragma unroll
        for (int i = 0; i < TI; i++) {
            int rr = wr * WM + i * 16 + m;
            af[i] = *reinterpret_cast<const bf16x8*>(&As[rr * 32 + ((quad ^ ((rr >> 1) & 3)) << 3)]);
        }
#pragma unroll
        for (int j = 0; j < TJ; j++) {
            int rr = wc * WN + j * 16 + m;
            bf_[j] = *reinterpret_cast<const bf16x8*>(&Bs[rr * 32 + ((quad ^ ((rr >> 1) & 3)) << 3)]);
        }
#pragma unroll
        for (int i = 0; i < TI; i++)
#pragma unroll
            for (int j = 0; j < TJ; j++)
                acc[i][j] = __builtin_amdgcn_mfma_f32_16x16x32_bf16(af[i], bf_[j], acc[i][j], 0, 0, 0);
    }
    bool isbf = (EPI == 1) ? (*flag != 0) : false;
#pragma unroll
    for (int i = 0; i < TI; i++) {
#pragma unroll
        for (int j = 0; j < TJ; j++) {
#pragma unroll
            for (int r = 0; r < 4; r++) {
                int row = m0 + wr * WM + i * 16 + quad * 4 + r;
                int col = n0 + wc * WN + j * 16 + m;
                size_t idx = (size_t)row * N + col;
                float v = acc[i][j][r];
                if (EPI == 0) Cb[idx] = f2bu(v);
                else if (EPI == 1) Cf[idx] = v + ldin(res, idx, isbf);
                else Cf[idx] = Cf[idx] + v;
            }
        }
    }
}

// ------------- Fused gated MLP MFMA: C(bf16) = gelu(A@Wg) * (A@Wu) -------------
template <int BM, int BN, int WRN, int WCN>
__global__ __launch_bounds__(256) void gemm_gated_mfma(const u16* __restrict__ A,
                                                       const u16* __restrict__ BgT,
                                                       const u16* __restrict__ BuT,
                                                       u16* __restrict__ C,
                                                       int M, int N, int K) {
    constexpr int BK = 32;
    constexpr int WM = BM / WRN, WN = BN / WCN, TI = WM / 16, TJ = WN / 16;
    __shared__ u16 As[BM * 32];
    __shared__ u16 Bgs[BN * 32];
    __shared__ u16 Bus[BN * 32];
    int tid = threadIdx.x, lane = tid & 63, wv = tid >> 6;
    int wr = wv / WCN, wc = wv % WCN;
    int m = lane & 15, quad = lane >> 4;
    int m0 = blockIdx.y * BM, n0 = blockIdx.x * BN;
    f32x4 accg[TI][TJ] = {};
    f32x4 accu[TI][TJ] = {};
    for (int k0 = 0; k0 < K; k0 += BK) {
        __syncthreads();
#pragma unroll
        for (int c2 = 0; c2 < BM / 64; c2++) {
            int row0 = (wv * (BM / 64) + c2) * 16;
            int row = row0 + (lane >> 2);
            int ch = lane & 3;
            gload16(&A[(size_t)(m0 + row) * K + k0 + ((ch ^ ((row >> 1) & 3)) << 3)],
                    &As[row0 * 32]);
        }
#pragma unroll
        for (int c2 = 0; c2 < BN / 64; c2++) {
            int row0 = (wv * (BN / 64) + c2) * 16;
            int row = row0 + (lane >> 2);
            int ch = lane & 3;
            gload16(&BgT[(size_t)(n0 + row) * K + k0 + ((ch ^ ((row >> 1) & 3)) << 3)],
                    &Bgs[row0 * 32]);
            gload16(&BuT[(size_t)(n0 + row) * K + k0 + ((ch ^ ((row >> 1) & 3)) << 3)],
                    &Bus[row0 * 32]);
        }
        __syncthreads();
        bf16x8 af[TI], bg[TJ], bu[TJ];
#pragma unroll
        for (int i = 0; i < TI; i++) {
            int rr = wr * WM + i * 16 + m;
            af[i] = *reinterpret_cast<const bf16x8*>(&As[rr * 32 + ((quad ^ ((rr >> 1) & 3)) << 3)]);
        }
#pragma unroll
        for (int j = 0; j < TJ; j++) {
            int rr = wc * WN + j * 16 + m;
            int off = rr * 32 + ((quad ^ ((rr >> 1) & 3)) << 3);
            bg[j] = *reinterpret_cast<const bf16x8*>(&Bgs[off]);
            bu[j] = *reinterpret_cast<const bf16x8*>(&Bus[off]);
        }
#pragma unroll
        for (int i = 0; i < TI; i++)
#pragma unroll
            for (int j = 0; j < TJ; j++) {
                accg[i][j] = __builtin_amdgcn_mfma_f32_16x16x32_bf16(af[i], bg[j], accg[i][j], 0, 0, 0);
                accu[i][j] = __builtin_amdgcn_mfma_f32_16x16x32_bf16(af[i], bu[j], accu[i][j], 0, 0, 0);
            }
    }
#pragma unroll
    for (int i = 0; i < TI; i++)
#pragma unroll
        for (int j = 0; j < TJ; j++)
#pragma unroll
            for (int r = 0; r < 4; r++) {
                int row = m0 + wr * WM + i * 16 + quad * 4 + r;
                int col = n0 + wc * WN + j * 16 + m;
                C[(size_t)row * N + col] = f2bu(gelu_tanh(accg[i][j][r]) * accu[i][j][r]);
            }
}

// ---------------- RoPE (dual-expert via z): qkv (stride 3072) -> qr/kr (stride 1024) ----------------
__global__ __launch_bounds__(64) void rope_kernel(const u16* __restrict__ qkv0,
                                                  const u16* __restrict__ qkv1,
                                                  u16* __restrict__ qr,
                                                  u16* __restrict__ kr) {
    const u16* qkv = blockIdx.z ? qkv1 : qkv0;
    size_t zo = (size_t)blockIdx.z * ((size_t)S * HID);
    int b = blockIdx.x;
    int t = b >> 3, h = b & 7;
    int i = threadIdx.x;  // 0..63
    size_t ib = (size_t)t * 3072 + h * HD;
    size_t ob = zo + (size_t)t * HID + h * HD;
    float inv = powf(THETA, -(float)(2 * i) / (float)HD);
    float f = (float)t * inv;
    float c = cosf(f), s = sinf(f);
    float q1 = bu2f(qkv[ib + i]), q2 = bu2f(qkv[ib + i + 64]);
    qr[ob + i] = f2bu(q1 * c - q2 * s);
    qr[ob + i + 64] = f2bu(q2 * c + q1 * s);
    float k1 = bu2f(qkv[ib + 1024 + i]), k2 = bu2f(qkv[ib + 1024 + i + 64]);
    kr[ob + i] = f2bu(k1 * c - k2 * s);
    kr[ob + i + 64] = f2bu(k2 * c + k1 * s);
}

// ============ MFMA flash attention (round-1 verified structure + z-fused causal) ============
// Swapped QK^T (sc = mfma(K,Q)), per-lane in-register softmax, bpermute P
// redistribution, XOR-swizzled 32KB LDS. CAUSAL mode: blockIdx.z selects expert
// ((qa,ka,vta)=e0, (qb,kb,vtb)=e1), Out offset by z*S*HID. Expert 0 walks q0
// ascending, expert 1 descending so a CU's block pair (d, d+256) sums to a
// constant 33 tiles (dispatch order heuristic; correctness unaffected).
__device__ inline int swz64(int row, int b) {
    return row * 64 + (b ^ (((row >> 1) & 3) << 4));
}

template <bool CAUSAL>
__global__ __launch_bounds__(256, 4) void attn_mfma_kernel(
    const u16* __restrict__ qa, const u16* __restrict__ qb, int sq,
    const u16* __restrict__ ka, const u16* __restrict__ kb, int sk,
    const u16* __restrict__ vta, const u16* __restrict__ vtb,
    u16* __restrict__ Out, int nkeys) {
    __shared__ char Ks[4 * 64 * 64];    // [t=d/32][key 0..63][32 d], swizzled 64B rows
    __shared__ char VTs[2 * 128 * 64];  // [ks=key/32][d 0..127][32 keys], swizzled

    int tid = threadIdx.x;
    int lane = tid & 63, w = tid >> 6;
    int col = lane & 15, quad = lane >> 4;
    int eZ = CAUSAL ? (int)blockIdx.z : 0;
    int bx = (CAUSAL && eZ) ? ((int)gridDim.x - 1 - (int)blockIdx.x) : (int)blockIdx.x;
    int q0 = bx * 64;
    int h = blockIdx.y;
    const float scale = 0.08838834764831845f;  // 1/sqrt(128)

    // Q b-frags (4 d-steps of 32) straight from global into registers
    int q0r = CAUSAL ? q0 : (q0 & (S - 1));
    const u16* qsel = CAUSAL ? (eZ ? qb : qa) : ((q0 < S) ? qa : qb);
    const u16* qp = qsel + (size_t)q0r * sq;
    bf16x8 aq[4];
#pragma unroll
    for (int t = 0; t < 4; t++)
        aq[t] = *reinterpret_cast<const bf16x8*>(
            qp + (size_t)(16 * w + col) * sq + h * HD + 32 * t + quad * 8);

    // low-key (or per-expert) K/V pointers
    const u16* kplo = (CAUSAL && eZ) ? kb : ka;
    const u16* vplo = (CAUSAL && eZ) ? vtb : vta;

    f32x4 o[8] = {};           // O^T: o[nt][r] = O[q][d = 16nt + 4quad + r]
    float m_ = -1e30f, l_ = 0.f;

    // bpermute source lanes for P redistribution:
    // target quad t needs pu[2ks + (t>>1)] from source quads 2(t&1) and 2(t&1)+1.
    int sA = col + 16 * (2 * (quad & 1));
    int sB = sA + 16;
    bool hi = (quad >> 1) != 0;

    int ntiles = CAUSAL ? (q0 >> 6) + 1 : (nkeys >> 6);
    for (int tt = 0; tt < ntiles; tt++) {
        int j0 = tt * 64;
        int j0r = j0 & (S - 1);
        bool eb = (!CAUSAL) && (j0 >= S);
        const u16* kp = eb ? kb : kplo;
        const u16* vp = eb ? vtb : vplo;
        __syncthreads();  // prev iter's compute done before restaging
        // ---- stage K tile: 64 keys x 128 d ----
#pragma unroll
        for (int i = 0; i < 4; i++) {
            int l = tid + 256 * i;
            int key = l >> 4, c = l & 15;
            int t = c >> 2, kq = c & 3;
            *reinterpret_cast<uint4*>(&Ks[t * 4096 + swz64(key, kq * 16)]) =
                *reinterpret_cast<const uint4*>(kp + (size_t)(j0r + key) * sk + h * HD + c * 8);
        }
        // ---- stage V^T tile: 128 d x 64 keys ----
#pragma unroll
        for (int i = 0; i < 4; i++) {
            int l = tid + 256 * i;
            int d = l >> 3, c = l & 7;
            int ks = c >> 2, kq = c & 3;
            *reinterpret_cast<uint4*>(&VTs[ks * 8192 + swz64(d, kq * 16)]) =
                *reinterpret_cast<const uint4*>(vp + (size_t)(h * HD + d) * S + j0r + c * 8);
        }
        __syncthreads();

        // ---- QK^T (swapped): wave computes 64k x 16q ----
        f32x4 sc[4] = {};
        __builtin_amdgcn_s_setprio(1);
#pragma unroll
        for (int t = 0; t < 4; t++) {
#pragma unroll
            for (int ct = 0; ct < 4; ct++) {
                bf16x8 kf = *reinterpret_cast<const bf16x8*>(
                    &Ks[t * 4096 + swz64(16 * ct + col, quad * 16)]);
                sc[ct] = __builtin_amdgcn_mfma_f32_16x16x32_bf16(kf, aq[t], sc[ct], 0, 0, 0);
            }
        }
        __builtin_amdgcn_s_setprio(0);
        bool diag = CAUSAL && (j0 == q0);
#pragma unroll
        for (int ct = 0; ct < 4; ct++) {
#pragma unroll
            for (int r = 0; r < 4; r++) {
                float v = sc[ct][r] * scale;
                if (diag && (16 * ct + 4 * quad + r > 16 * w + col)) v = -1e30f;
                sc[ct][r] = v;
            }
        }

        // ---- per-lane online softmax (one query per lane) ----
        float mx0 = fmaxf(fmaxf(sc[0][0], sc[0][1]), fmaxf(sc[0][2], sc[0][3]));
        float mx1 = fmaxf(fmaxf(sc[1][0], sc[1][1]), fmaxf(sc[1][2], sc[1][3]));
        float mx2 = fmaxf(fmaxf(sc[2][0], sc[2][1]), fmaxf(sc[2][2], sc[2][3]));
        float mx3 = fmaxf(fmaxf(sc[3][0], sc[3][1]), fmaxf(sc[3][2], sc[3][3]));
        float rmax = fmaxf(fmaxf(mx0, mx1), fmaxf(mx2, mx3));
        rmax = fmaxf(rmax, __shfl_xor(rmax, 16));
        rmax = fmaxf(rmax, __shfl_xor(rmax, 32));
        float mn = fmaxf(m_, rmax);
        float al = __expf(m_ - mn);
#pragma unroll
        for (int ct = 0; ct < 4; ct++)
#pragma unroll
            for (int r = 0; r < 4; r++) sc[ct][r] = __expf(sc[ct][r] - mn);
        float s0 = (sc[0][0] + sc[0][1]) + (sc[0][2] + sc[0][3]);
        float s1 = (sc[1][0] + sc[1][1]) + (sc[1][2] + sc[1][3]);
        float s2 = (sc[2][0] + sc[2][1]) + (sc[2][2] + sc[2][3]);
        float s3 = (sc[3][0] + sc[3][1]) + (sc[3][2] + sc[3][3]);
        float rs = (s0 + s1) + (s2 + s3);
        rs += __shfl_xor(rs, 16);
        rs += __shfl_xor(rs, 32);
        l_ = l_ * al + rs;
        m_ = mn;

        // ---- pack P^T to bf16 pairs: pu[ct] covers keys 16ct+4quad+{0..3} ----
        unsigned int pu[4][2];
#pragma unroll
        for (int ct = 0; ct < 4; ct++) {
            pu[ct][0] = (unsigned int)f2bu(sc[ct][0]) | ((unsigned int)f2bu(sc[ct][1]) << 16);
            pu[ct][1] = (unsigned int)f2bu(sc[ct][2]) | ((unsigned int)f2bu(sc[ct][3]) << 16);
        }

        // ---- O^T rescale ----
#pragma unroll
        for (int nt = 0; nt < 8; nt++)
#pragma unroll
            for (int r = 0; r < 4; r++) o[nt][r] *= al;

        // ---- PV: O^T += V^T @ P^T; b-frag gathered via bpermute ----
#pragma unroll
        for (int ks = 0; ks < 2; ks++) {
            unsigned int a0 = __shfl(pu[2 * ks][0], sA);
            unsigned int a1 = __shfl(pu[2 * ks][1], sA);
            unsigned int c0 = __shfl(pu[2 * ks + 1][0], sA);
            unsigned int c1 = __shfl(pu[2 * ks + 1][1], sA);
            unsigned int b0 = __shfl(pu[2 * ks][0], sB);
            unsigned int b1 = __shfl(pu[2 * ks][1], sB);
            unsigned int g0 = __shfl(pu[2 * ks + 1][0], sB);
            unsigned int g1 = __shfl(pu[2 * ks + 1][1], sB);
            union {
                unsigned int u[4];
                bf16x8 v;
            } pb;
            pb.u[0] = hi ? c0 : a0;
            pb.u[1] = hi ? c1 : a1;
            pb.u[2] = hi ? g0 : b0;
            pb.u[3] = hi ? g1 : b1;
            __builtin_amdgcn_s_setprio(1);
#pragma unroll
            for (int nt = 0; nt < 8; nt++) {
                bf16x8 vf = *reinterpret_cast<const bf16x8*>(
                    &VTs[ks * 8192 + swz64(16 * nt + col, quad * 16)]);
                o[nt] = __builtin_amdgcn_mfma_f32_16x16x32_bf16(vf, pb.v, o[nt], 0, 0, 0);
            }
            __builtin_amdgcn_s_setprio(0);
        }
    }

    // ---- epilogue: O /= l, write bf16 (stride HID); r-values are contiguous in d ----
    u16* outp = Out + (CAUSAL ? (size_t)eZ * ((size_t)S * HID) : (size_t)0);
    float inv = 1.f / l_;
    size_t rowoff = (size_t)(q0 + 16 * w + col) * HID + (size_t)h * HD + 4 * quad;
#pragma unroll
    for (int nt = 0; nt < 8; nt++) {
        ushort4 st;
        st.x = f2bu(o[nt][0] * inv);
        st.y = f2bu(o[nt][1] * inv);
        st.z = f2bu(o[nt][2] * inv);
        st.w = f2bu(o[nt][3] * inv);
        *reinterpret_cast<ushort4*>(&outp[rowoff + 16 * nt]) = st;
    }
}

// ---------------- f32 -> output dtype (per flag) ----------------
__global__ __launch_bounds__(256) void store_out_kernel(const float* __restrict__ a,
                                                        const float* __restrict__ b,
                                                        void* __restrict__ out,
                                                        const int* __restrict__ flag) {
    bool isbf = (*flag != 0);
    size_t i = (size_t)blockIdx.x * 256 + threadIdx.x;
    const size_t MM = (size_t)S * HID;
    float v = (i < MM) ? a[i] : b[i - MM];
    if (isbf)
        ((bf16*)out)[i] = __float2bfloat16(v);
    else
        ((float*)out)[i] = v;
}

extern "C" void kernel_launch(void* const* d_in, const int* in_sizes, int n_in,
                              void* d_out, int out_size, void* d_ws, size_t ws_size,
                              hipStream_t stream) {
    const void* x[2] = {d_in[0], d_in[1]};
    const void* w_ln[2] = {d_in[5], d_in[14]};
    const void* w_q[2] = {d_in[6], d_in[15]};
    const void* w_k[2] = {d_in[7], d_in[16]};
    const void* w_v[2] = {d_in[8], d_in[17]};
    const void* w_o[2] = {d_in[9], d_in[18]};
    const void* w_pln[2] = {d_in[10], d_in[19]};
    const void* w_g[2] = {d_in[11], d_in[20]};
    const void* w_u[2] = {d_in[12], d_in[21]};
    const void* w_d[2] = {d_in[13], d_in[22]};

    char* base = (char*)d_ws;
    int* flag = (int*)base;
    u16* p = (u16*)(base + 256);
    const size_t E_QKV = (size_t)S * 3072;
    const size_t E_SH = (size_t)S * HID;
    const size_t E_VT = (size_t)NH * HD * S;  // == E_SH

    u16* qkv[2] = {p, p + E_QKV};            p += 2 * E_QKV;
    u16* qr = p;                             p += 2 * E_SH;  // [expert]
    u16* kr = p;                             p += 2 * E_SH;  // adjacent to qr
    u16* h_bf = p;                           p += 2 * E_SH;
    u16* attnbuf = p;                        p += 2 * E_SH;
    u16* vtg = p;                            p += 2 * E_VT;
    // gated (S*INTER = 8M u16) overlays qr+kr (free after causal attn);
    // mixed (2S*HID = 4M u16) overlays the same region (free after down GEMMs).
    u16* gated = qr;
    u16* mixed = qr;
    u16* wqkvT = p;                          p += 2 * (size_t)3072 * 1024;
    u16* woT[2] = {p, p + (size_t)1024 * 1024};  p += 2 * (size_t)1024 * 1024;
    u16* wgT = p;                            p += (size_t)INTER * 1024;
    u16* wuT = p;                            p += (size_t)INTER * 1024;
    u16* wdT = p;                            p += (size_t)1024 * INTER;
    float* fbase = (float*)(((size_t)p + 255) & ~(size_t)255);
    float* outX[2] = {fbase, fbase + E_SH};

    probe_kernel<<<1, 256, 0, stream>>>((const unsigned short*)d_in[0], flag);

    // ---- upfront transposes: qkv + wo weights for both experts ----
    for (int e = 0; e < 2; e++) {
        u16* wt = wqkvT + (size_t)e * 3072 * 1024;
        transpose_w<<<dim3(32, 32), 256, 0, stream>>>(w_q[e], wt, flag, 1024, 1024);
        transpose_w<<<dim3(32, 32), 256, 0, stream>>>(w_k[e], wt + (size_t)1024 * 1024, flag, 1024, 1024);
        transpose_w<<<dim3(32, 32), 256, 0, stream>>>(w_v[e], wt + (size_t)2048 * 1024, flag, 1024, 1024);
        transpose_w<<<dim3(32, 32), 256, 0, stream>>>(w_o[e], woT[e], flag, 1024, 1024);
    }

    // ---- fused attention path (both experts per dispatch) ----
    {
        RmsDual rd = {{x[0], x[1]}, {w_ln[0], w_ln[1]}, {h_bf, h_bf + E_SH}};
        rmsnorm_kernel<<<dim3(S, 2), 256, 0, stream>>>(rd, flag, 1);
    }
    {
        GemmDual g = {{h_bf, h_bf + E_SH},
                      {wqkvT, wqkvT + (size_t)3072 * 1024},
                      {nullptr, nullptr},
                      {qkv[0], qkv[1]},
                      {nullptr, nullptr}};
        gemm_mfma<128, 128, 2, 2, 0><<<dim3(3072 / 128, S / 128, 2), 256, 0, stream>>>(
            g, flag, S, 3072, 1024);
    }
    rope_kernel<<<dim3(S * NH, 1, 2), 64, 0, stream>>>(qkv[0], qkv[1], qr, kr);
    transpose_v<<<dim3(S / 32, 1024 / 32, 2), 256, 0, stream>>>(qkv[0] + 2048, qkv[1] + 2048, 3072, vtg);
    attn_mfma_kernel<true><<<dim3(S / 64, NH, 2), 256, 0, stream>>>(
        qr, qr + E_SH, HID, kr, kr + E_SH, HID, vtg, vtg + E_VT, attnbuf, S);
    {
        GemmDual g = {{attnbuf, attnbuf + E_SH},
                      {woT[0], woT[1]},
                      {outX[0], outX[1]},
                      {nullptr, nullptr},
                      {x[0], x[1]}};
        gemm_mfma<64, 128, 1, 4, 1><<<dim3(1024 / 128, S / 64, 2), 256, 0, stream>>>(
            g, flag, S, 1024, 1024);
    }
    {
        RmsDual rd = {{outX[0], outX[1]}, {w_pln[0], w_pln[1]}, {h_bf, h_bf + E_SH}};
        rmsnorm_kernel<<<dim3(S, 2), 256, 0, stream>>>(rd, flag, 0);
    }

    // ---- MLP per expert (weight buffers reused; gated overlays dead qr/kr) ----
    for (int e = 0; e < 2; e++) {
        transpose_w<<<dim3(INTER / 32, 1024 / 32), 256, 0, stream>>>(w_g[e], wgT, flag, 1024, INTER);
        transpose_w<<<dim3(INTER / 32, 1024 / 32), 256, 0, stream>>>(w_u[e], wuT, flag, 1024, INTER);
        gemm_gated_mfma<128, 64, 2, 2><<<dim3(INTER / 64, S / 128), 256, 0, stream>>>(
            h_bf + e * E_SH, wgT, wuT, gated, S, INTER, 1024);
        transpose_w<<<dim3(1024 / 32, INTER / 32), 256, 0, stream>>>(w_d[e], wdT, flag, INTER, 1024);
        GemmDual g = {{gated, gated}, {wdT, wdT}, {outX[e], outX[e]}, {nullptr, nullptr}, {nullptr, nullptr}};
        gemm_mfma<64, 128, 1, 4, 2><<<dim3(1024 / 128, S / 64, 1), 256, 0, stream>>>(
            g, flag, S, 1024, INTER);
    }

    // ---- mixed attention + fused output projections ----
    attn_mfma_kernel<false><<<dim3(2 * S / 64, NH), 256, 0, stream>>>(
        qkv[0], qkv[1], 3072, qkv[0] + 1024, qkv[1] + 1024, 3072,
        vtg, vtg + E_VT, mixed, 2 * S);
    {
        GemmDual g = {{mixed, mixed + E_SH},
                      {woT[0], woT[1]},
                      {outX[0], outX[1]},
                      {nullptr, nullptr},
                      {nullptr, nullptr}};
        gemm_mfma<64, 128, 1, 4, 2><<<dim3(1024 / 128, S / 64, 2), 256, 0, stream>>>(
            g, flag, S, 1024, 1024);
    }

    store_out_kernel<<<(2 * E_SH) / 256, 256, 0, stream>>>(outX[0], outX[1], d_out, flag);
}

// Round 6
// 796.308 us; speedup vs baseline: 1.7788x; 1.0980x over previous
//
#include <hip/hip_runtime.h>
#include <hip/hip_bf16.h>
#include <math.h>

#define S 2048
#define HID 1024
#define NH 8
#define HD 128
#define INTER 4096
#define EPSV 1e-6f
#define THETA 10000.0f

typedef __hip_bfloat16 bf16;
typedef unsigned short u16;
typedef __attribute__((ext_vector_type(8))) short bf16x8;  // 8 bf16 = 4 VGPRs
typedef __attribute__((ext_vector_type(4))) float f32x4;

__device__ inline float bu2f(u16 u) {
    unsigned int x = ((unsigned int)u) << 16;
    return __uint_as_float(x);
}
__device__ inline u16 f2bu(float f) {
    bf16 h = __float2bfloat16(f);
    return *reinterpret_cast<u16*>(&h);
}
// Dual-dtype input load (raw harness inputs): isbf ? bf16 : f32
__device__ inline float ldin(const void* p, size_t i, bool isbf) {
    return isbf ? bu2f(((const u16*)p)[i]) : ((const float*)p)[i];
}
__device__ inline float gelu_tanh(float x) {
    float x3 = x * x * x;
    return 0.5f * x * (1.f + tanhf(0.7978845608028654f * (x + 0.044715f * x3)));
}
// Direct global->LDS 16B/lane async copy. LDS dest must be wave-uniform;
// lane i's 16B lands at ldsbase + i*16. Global source IS per-lane.
__device__ inline void gload16(const u16* g, u16* l) {
    __builtin_amdgcn_global_load_lds(
        (const __attribute__((address_space(1))) void*)g,
        (__attribute__((address_space(3))) void*)l, 16, 0, 0);
}

// ---------------- dtype probe (round-1 notes) ----------------
__global__ __launch_bounds__(256) void probe_kernel(const unsigned short* __restrict__ x,
                                                    int* __restrict__ flag) {
    __shared__ int red[256];
    int tid = threadIdx.x;
    int cnt = 0;
    for (int i = tid; i < 2048; i += 256) {
        unsigned short u = x[2 * i];
        int e = (u >> 7) & 0xFF;
        cnt += (e >= 110 && e <= 135) ? 1 : 0;
    }
    red[tid] = cnt;
    __syncthreads();
    for (int off = 128; off > 0; off >>= 1) {
        if (tid < off) red[tid] += red[tid + off];
        __syncthreads();
    }
    if (tid == 0) *flag = (red[0] > 1024) ? 1 : 0;
}

// ---------------- weight transpose+convert, z-batched: W (KxN) -> WT (NxK, bf16) ----------------
struct TransN {
    const void* W[8];
    u16* T[8];
};
__global__ __launch_bounds__(256) void transpose_wN(TransN tn, const int* __restrict__ flag,
                                                    int K, int N) {
    bool isbf = (*flag != 0);
    const void* W = tn.W[blockIdx.z];
    u16* WT = tn.T[blockIdx.z];
    __shared__ float t[32][33];
    int n0 = blockIdx.x * 32, k0 = blockIdx.y * 32;
    int c = threadIdx.x & 31, r = threadIdx.x >> 5;
#pragma unroll
    for (int p = 0; p < 4; p++)
        t[r + 8 * p][c] = ldin(W, (size_t)(k0 + r + 8 * p) * N + n0 + c, isbf);
    __syncthreads();
#pragma unroll
    for (int p = 0; p < 4; p++) {
        int row = r + 8 * p;
        WT[(size_t)(n0 + row) * K + k0 + c] = f2bu(t[c][row]);
    }
}

// ---------------- V transpose (dual-expert via z): V[key][dh] -> VT[dh][key] ----------------
__global__ __launch_bounds__(256) void transpose_v(const u16* __restrict__ V0,
                                                   const u16* __restrict__ V1, int sv,
                                                   u16* __restrict__ VT) {
    const u16* V = blockIdx.z ? V1 : V0;
    VT += (size_t)blockIdx.z * ((size_t)NH * HD * S);
    __shared__ u16 t[32][33];
    int k0 = blockIdx.x * 32;  // key tile
    int d0 = blockIdx.y * 32;  // dh tile
    int c = threadIdx.x & 31, r = threadIdx.x >> 5;
#pragma unroll
    for (int p = 0; p < 4; p++)
        t[r + 8 * p][c] = V[(size_t)(k0 + r + 8 * p) * sv + d0 + c];
    __syncthreads();
#pragma unroll
    for (int p = 0; p < 4; p++)
        VT[(size_t)(d0 + r + 8 * p) * S + k0 + c] = t[c][r + 8 * p];
}

// ---------------- RMSNorm -> bf16 (dual-expert via blockIdx.y) ----------------
struct RmsDual {
    const void* x[2];
    const void* w[2];
    u16* y[2];
};
__global__ __launch_bounds__(256) void rmsnorm_kernel(RmsDual rd,
                                                      const int* __restrict__ flag,
                                                      int dual) {
    int e = blockIdx.y;
    const void* x = rd.x[e];
    const void* w = rd.w[e];
    u16* y = rd.y[e];
    bool isbf = (*flag != 0);
    bool xbf = dual && isbf;
    int row = blockIdx.x;
    size_t base = (size_t)row * HID;
    __shared__ float red[256];
    float xv[4];
    float s = 0.f;
#pragma unroll
    for (int i = 0; i < 4; i++) {
        float v = ldin(x, base + threadIdx.x + 256 * i, xbf);
        xv[i] = v;
        s += v * v;
    }
    red[threadIdx.x] = s;
    __syncthreads();
    for (int off = 128; off > 0; off >>= 1) {
        if (threadIdx.x < off) red[threadIdx.x] += red[threadIdx.x + off];
        __syncthreads();
    }
    float scale = rsqrtf(red[0] / (float)HID + EPSV);
#pragma unroll
    for (int i = 0; i < 4; i++) {
        int c = threadIdx.x + 256 * i;
        y[base + c] = f2bu(xv[i] * scale * (1.f + ldin(w, c, isbf)));
    }
}

// ================= MFMA GEMM (v3: gload16 staging + dual-expert via blockIdx.z) =================
// LDS tiles are LINEAR [row][64B] (BK=32 bf16 per row). global_load_lds writes lane-linear,
// so the XOR swizzle (chunk ^= (row>>1)&3, 16B chunks within the 64B row) is applied on the
// per-lane GLOBAL SOURCE address at load time and again on the frag-read address (involution).
struct GemmDual {
    const u16* A[2];
    const u16* BT[2];
    float* Cf[2];
    u16* Cb[2];
    const void* res[2];
};
template <int BM, int BN, int WRN, int WCN, int EPI>
__global__ __launch_bounds__(256) void gemm_mfma(GemmDual g, const int* __restrict__ flag,
                                                 int M, int N, int K) {
    int eZ = blockIdx.z;
    const u16* __restrict__ A = g.A[eZ];
    const u16* __restrict__ BT = g.BT[eZ];
    float* __restrict__ Cf = g.Cf[eZ];
    u16* __restrict__ Cb = g.Cb[eZ];
    const void* __restrict__ res = g.res[eZ];
    constexpr int BK = 32;
    constexpr int WM = BM / WRN, WN = BN / WCN, TI = WM / 16, TJ = WN / 16;
    __shared__ u16 As[BM * 32];
    __shared__ u16 Bs[BN * 32];
    int tid = threadIdx.x, lane = tid & 63, wv = tid >> 6;
    int wr = wv / WCN, wc = wv % WCN;
    int m = lane & 15, quad = lane >> 4;
    int m0 = blockIdx.y * BM, n0 = blockIdx.x * BN;
    f32x4 acc[TI][TJ] = {};
    for (int k0 = 0; k0 < K; k0 += BK) {
        __syncthreads();  // prev compute done reading LDS
#pragma unroll
        for (int c2 = 0; c2 < BM / 64; c2++) {
            int row0 = (wv * (BM / 64) + c2) * 16;
            int row = row0 + (lane >> 2);
            int ch = lane & 3;
            gload16(&A[(size_t)(m0 + row) * K + k0 + ((ch ^ ((row >> 1) & 3)) << 3)],
                    &As[row0 * 32]);
        }
#pragma unroll
        for (int c2 = 0; c2 < BN / 64; c2++) {
            int row0 = (wv * (BN / 64) + c2) * 16;
            int row = row0 + (lane >> 2);
            int ch = lane & 3;
            gload16(&BT[(size_t)(n0 + row) * K + k0 + ((ch ^ ((row >> 1) & 3)) << 3)],
                    &Bs[row0 * 32]);
        }
        __syncthreads();  // vmcnt drained by barrier -> tiles in LDS
        bf16x8 af[TI], bf_[TJ];
#pragma unroll
        for (int i = 0; i < TI; i++) {
            int rr = wr * WM + i * 16 + m;
            af[i] = *reinterpret_cast<const bf16x8*>(&As[rr * 32 + ((quad ^ ((rr >> 1) & 3)) << 3)]);
        }
#pragma unroll
        for (int j = 0; j < TJ; j++) {
            int rr = wc * WN + j * 16 + m;
            bf_[j] = *reinterpret_cast<const bf16x8*>(&Bs[rr * 32 + ((quad ^ ((rr >> 1) & 3)) << 3)]);
        }
#pragma unroll
        for (int i = 0; i < TI; i++)
#pragma unroll
            for (int j = 0; j < TJ; j++)
                acc[i][j] = __builtin_amdgcn_mfma_f32_16x16x32_bf16(af[i], bf_[j], acc[i][j], 0, 0, 0);
    }
    bool isbf = (EPI == 1) ? (*flag != 0) : false;
#pragma unroll
    for (int i = 0; i < TI; i++) {
#pragma unroll
        for (int j = 0; j < TJ; j++) {
#pragma unroll
            for (int r = 0; r < 4; r++) {
                int row = m0 + wr * WM + i * 16 + quad * 4 + r;
                int col = n0 + wc * WN + j * 16 + m;
                size_t idx = (size_t)row * N + col;
                float v = acc[i][j][r];
                if (EPI == 0) Cb[idx] = f2bu(v);
                else if (EPI == 1) Cf[idx] = v + ldin(res, idx, isbf);
                else Cf[idx] = Cf[idx] + v;
            }
        }
    }
}

// ------------- Fused gated MLP MFMA: C(bf16) = gelu(A@Wg) * (A@Wu) -------------
template <int BM, int BN, int WRN, int WCN>
__global__ __launch_bounds__(256) void gemm_gated_mfma(const u16* __restrict__ A,
                                                       const u16* __restrict__ BgT,
                                                       const u16* __restrict__ BuT,
                                                       u16* __restrict__ C,
                                                       int M, int N, int K) {
    constexpr int BK = 32;
    constexpr int WM = BM / WRN, WN = BN / WCN, TI = WM / 16, TJ = WN / 16;
    __shared__ u16 As[BM * 32];
    __shared__ u16 Bgs[BN * 32];
    __shared__ u16 Bus[BN * 32];
    int tid = threadIdx.x, lane = tid & 63, wv = tid >> 6;
    int wr = wv / WCN, wc = wv % WCN;
    int m = lane & 15, quad = lane >> 4;
    int m0 = blockIdx.y * BM, n0 = blockIdx.x * BN;
    f32x4 accg[TI][TJ] = {};
    f32x4 accu[TI][TJ] = {};
    for (int k0 = 0; k0 < K; k0 += BK) {
        __syncthreads();
#pragma unroll
        for (int c2 = 0; c2 < BM / 64; c2++) {
            int row0 = (wv * (BM / 64) + c2) * 16;
            int row = row0 + (lane >> 2);
            int ch = lane & 3;
            gload16(&A[(size_t)(m0 + row) * K + k0 + ((ch ^ ((row >> 1) & 3)) << 3)],
                    &As[row0 * 32]);
        }
#pragma unroll
        for (int c2 = 0; c2 < BN / 64; c2++) {
            int row0 = (wv * (BN / 64) + c2) * 16;
            int row = row0 + (lane >> 2);
            int ch = lane & 3;
            gload16(&BgT[(size_t)(n0 + row) * K + k0 + ((ch ^ ((row >> 1) & 3)) << 3)],
                    &Bgs[row0 * 32]);
            gload16(&BuT[(size_t)(n0 + row) * K + k0 + ((ch ^ ((row >> 1) & 3)) << 3)],
                    &Bus[row0 * 32]);
        }
        __syncthreads();
        bf16x8 af[TI], bg[TJ], bu[TJ];
#pragma unroll
        for (int i = 0; i < TI; i++) {
            int rr = wr * WM + i * 16 + m;
            af[i] = *reinterpret_cast<const bf16x8*>(&As[rr * 32 + ((quad ^ ((rr >> 1) & 3)) << 3)]);
        }
#pragma unroll
        for (int j = 0; j < TJ; j++) {
            int rr = wc * WN + j * 16 + m;
            int off = rr * 32 + ((quad ^ ((rr >> 1) & 3)) << 3);
            bg[j] = *reinterpret_cast<const bf16x8*>(&Bgs[off]);
            bu[j] = *reinterpret_cast<const bf16x8*>(&Bus[off]);
        }
#pragma unroll
        for (int i = 0; i < TI; i++)
#pragma unroll
            for (int j = 0; j < TJ; j++) {
                accg[i][j] = __builtin_amdgcn_mfma_f32_16x16x32_bf16(af[i], bg[j], accg[i][j], 0, 0, 0);
                accu[i][j] = __builtin_amdgcn_mfma_f32_16x16x32_bf16(af[i], bu[j], accu[i][j], 0, 0, 0);
            }
    }
#pragma unroll
    for (int i = 0; i < TI; i++)
#pragma unroll
        for (int j = 0; j < TJ; j++)
#pragma unroll
            for (int r = 0; r < 4; r++) {
                int row = m0 + wr * WM + i * 16 + quad * 4 + r;
                int col = n0 + wc * WN + j * 16 + m;
                C[(size_t)row * N + col] = f2bu(gelu_tanh(accg[i][j][r]) * accu[i][j][r]);
            }
}

// ---------------- RoPE (dual-expert via z): qkv (stride 3072) -> qr/kr (stride 1024) ----------------
__global__ __launch_bounds__(64) void rope_kernel(const u16* __restrict__ qkv0,
                                                  const u16* __restrict__ qkv1,
                                                  u16* __restrict__ qr,
                                                  u16* __restrict__ kr) {
    const u16* qkv = blockIdx.z ? qkv1 : qkv0;
    size_t zo = (size_t)blockIdx.z * ((size_t)S * HID);
    int b = blockIdx.x;
    int t = b >> 3, h = b & 7;
    int i = threadIdx.x;  // 0..63
    size_t ib = (size_t)t * 3072 + h * HD;
    size_t ob = zo + (size_t)t * HID + h * HD;
    // powf(THETA, -x) == exp(-x * ln(THETA)); ln(10000) = 9.210340372
    float inv = __expf(-9.210340372f * (float)(2 * i) / (float)HD);
    float f = (float)t * inv;
    float c = cosf(f), s = sinf(f);
    float q1 = bu2f(qkv[ib + i]), q2 = bu2f(qkv[ib + i + 64]);
    qr[ob + i] = f2bu(q1 * c - q2 * s);
    qr[ob + i + 64] = f2bu(q2 * c + q1 * s);
    float k1 = bu2f(qkv[ib + 1024 + i]), k2 = bu2f(qkv[ib + 1024 + i + 64]);
    kr[ob + i] = f2bu(k1 * c - k2 * s);
    kr[ob + i + 64] = f2bu(k2 * c + k1 * s);
}

// ============ MFMA flash attention (v4: gload16 double-buffered pipeline) ============
// Round-1 verified compute structure (swapped QK^T, per-lane in-register softmax,
// bpermute P redistribution, XOR-swizzled reads). NEW: K/V tiles double-buffered in
// LDS (2x32KB) and staged with global_load_lds (T3 minimum 2-phase recipe): tile t+1's
// async loads are issued BEFORE computing tile t; the single __syncthreads per tile
// drains vmcnt. No register staging -> no scratch (round-2 lesson). LDS dest is
// lane-linear, so the inverse swizzle is applied to the per-lane GLOBAL source address;
// the swizzled frag reads are unchanged. Occupancy unchanged (both grids = 512 blocks
// = 2/CU, grid-limited). Causal: expert 1 walks q0 descending for pair balance.
__device__ inline int swz64(int row, int b) {
    return row * 64 + (b ^ (((row >> 1) & 3) << 4));
}

template <bool CAUSAL>
__global__ __launch_bounds__(256, 2) void attn_mfma_kernel(
    const u16* __restrict__ qa, const u16* __restrict__ qb, int sq,
    const u16* __restrict__ ka, const u16* __restrict__ kb, int sk,
    const u16* __restrict__ vta, const u16* __restrict__ vtb,
    u16* __restrict__ Out, int nkeys) {
    __shared__ char Ks[2][16384];   // [buf][t=d/32][key][32 d] swizzled 64B rows
    __shared__ char VTs[2][16384];  // [buf][ks=key/32][d][32 keys] swizzled

    int tid = threadIdx.x;
    int lane = tid & 63, w = tid >> 6;
    int col = lane & 15, quad = lane >> 4;
    int eZ = CAUSAL ? (int)blockIdx.z : 0;
    int bx = (CAUSAL && eZ) ? ((int)gridDim.x - 1 - (int)blockIdx.x) : (int)blockIdx.x;
    int q0 = bx * 64;
    int h = blockIdx.y;
    const float scale = 0.08838834764831845f;  // 1/sqrt(128)

    // Q b-frags (4 d-steps of 32) straight from global into registers
    int q0r = CAUSAL ? q0 : (q0 & (S - 1));
    const u16* qsel = CAUSAL ? (eZ ? qb : qa) : ((q0 < S) ? qa : qb);
    const u16* qp = qsel + (size_t)q0r * sq;
    bf16x8 aq[4];
#pragma unroll
    for (int t = 0; t < 4; t++)
        aq[t] = *reinterpret_cast<const bf16x8*>(
            qp + (size_t)(16 * w + col) * sq + h * HD + 32 * t + quad * 8);

    // low-key (or per-expert) K/V pointers
    const u16* kplo = (CAUSAL && eZ) ? kb : ka;
    const u16* vplo = (CAUSAL && eZ) ? vtb : vta;

    f32x4 o[8] = {};           // O^T: o[nt][r] = O[q][d = 16nt + 4quad + r]
    float m_ = -1e30f, l_ = 0.f;

    // bpermute source lanes for P redistribution:
    // target quad t needs pu[2ks + (t>>1)] from source quads 2(t&1) and 2(t&1)+1.
    int sA = col + 16 * (2 * (quad & 1));
    int sB = sA + 16;
    bool hi = (quad >> 1) != 0;

    int ntiles = CAUSAL ? (q0 >> 6) + 1 : (nkeys >> 6);

    // Async-stage tile tt into buffer buf. gload16 writes lane-linear (l = 256i+tid,
    // byte L = l*16); the inverse of the swizzled layout is applied on the SOURCE:
    //   K : t=l>>8,  key=(l>>2)&63,  c = t*4  + ((l&3) ^ ((key>>1)&3))
    //   VT: ks=l>>9, d  =(l>>2)&127, c = ks*4 + ((l&3) ^ ((d  >>1)&3))
    auto stage = [&](int buf, int tt) {
        int j0r = (tt * 64) & (S - 1);
        bool eb = (!CAUSAL) && (tt >= (S >> 6));
        const u16* kp = eb ? kb : kplo;
        const u16* vp = eb ? vtb : vplo;
        char* kd = &Ks[buf][(tid >> 6) * 1024];
        char* vd = &VTs[buf][(tid >> 6) * 1024];
#pragma unroll
        for (int i = 0; i < 4; i++) {
            int l = 256 * i + tid;
            int key = (l >> 2) & 63;
            int c = (l >> 8) * 4 + ((l & 3) ^ ((key >> 1) & 3));
            gload16(kp + (size_t)(j0r + key) * sk + h * HD + c * 8, (u16*)(kd + i * 4096));
        }
#pragma unroll
        for (int i = 0; i < 4; i++) {
            int l = 256 * i + tid;
            int d = (l >> 2) & 127;
            int c = (l >> 9) * 4 + ((l & 3) ^ ((d >> 1) & 3));
            gload16(vp + (size_t)(h * HD + d) * S + j0r + c * 8, (u16*)(vd + i * 4096));
        }
    };

    stage(0, 0);
    __syncthreads();  // prologue tile landed (vmcnt drained per-wave before barrier)
    int cur = 0;

    for (int tt = 0; tt < ntiles; tt++) {
        if (tt + 1 < ntiles) stage(cur ^ 1, tt + 1);  // async loads fly under compute
        const char* Kb = Ks[cur];
        const char* Vb = VTs[cur];

        // ---- QK^T (swapped): wave computes 64k x 16q ----
        f32x4 sc[4] = {};
        __builtin_amdgcn_s_setprio(1);
#pragma unroll
        for (int t = 0; t < 4; t++) {
#pragma unroll
            for (int ct = 0; ct < 4; ct++) {
                bf16x8 kf = *reinterpret_cast<const bf16x8*>(
                    Kb + t * 4096 + swz64(16 * ct + col, quad * 16));
                sc[ct] = __builtin_amdgcn_mfma_f32_16x16x32_bf16(kf, aq[t], sc[ct], 0, 0, 0);
            }
        }
        __builtin_amdgcn_s_setprio(0);
        bool diag = CAUSAL && (tt == ntiles - 1);
#pragma unroll
        for (int ct = 0; ct < 4; ct++) {
#pragma unroll
            for (int r = 0; r < 4; r++) {
                float v = sc[ct][r] * scale;
                if (diag && (16 * ct + 4 * quad + r > 16 * w + col)) v = -1e30f;
                sc[ct][r] = v;
            }
        }

        // ---- per-lane online softmax (one query per lane) ----
        float mx0 = fmaxf(fmaxf(sc[0][0], sc[0][1]), fmaxf(sc[0][2], sc[0][3]));
        float mx1 = fmaxf(fmaxf(sc[1][0], sc[1][1]), fmaxf(sc[1][2], sc[1][3]));
        float mx2 = fmaxf(fmaxf(sc[2][0], sc[2][1]), fmaxf(sc[2][2], sc[2][3]));
        float mx3 = fmaxf(fmaxf(sc[3][0], sc[3][1]), fmaxf(sc[3][2], sc[3][3]));
        float rmax = fmaxf(fmaxf(mx0, mx1), fmaxf(mx2, mx3));
        rmax = fmaxf(rmax, __shfl_xor(rmax, 16));
        rmax = fmaxf(rmax, __shfl_xor(rmax, 32));
        float mn = fmaxf(m_, rmax);
        float al = __expf(m_ - mn);
#pragma unroll
        for (int ct = 0; ct < 4; ct++)
#pragma unroll
            for (int r = 0; r < 4; r++) sc[ct][r] = __expf(sc[ct][r] - mn);
        float s0 = (sc[0][0] + sc[0][1]) + (sc[0][2] + sc[0][3]);
        float s1 = (sc[1][0] + sc[1][1]) + (sc[1][2] + sc[1][3]);
        float s2 = (sc[2][0] + sc[2][1]) + (sc[2][2] + sc[2][3]);
        float s3 = (sc[3][0] + sc[3][1]) + (sc[3][2] + sc[3][3]);
        float rs = (s0 + s1) + (s2 + s3);
        rs += __shfl_xor(rs, 16);
        rs += __shfl_xor(rs, 32);
        l_ = l_ * al + rs;
        m_ = mn;

        // ---- pack P^T to bf16 pairs: pu[ct] covers keys 16ct+4quad+{0..3} ----
        unsigned int pu[4][2];
#pragma unroll
        for (int ct = 0; ct < 4; ct++) {
            pu[ct][0] = (unsigned int)f2bu(sc[ct][0]) | ((unsigned int)f2bu(sc[ct][1]) << 16);
            pu[ct][1] = (unsigned int)f2bu(sc[ct][2]) | ((unsigned int)f2bu(sc[ct][3]) << 16);
        }

        // ---- O^T rescale ----
#pragma unroll
        for (int nt = 0; nt < 8; nt++)
#pragma unroll
            for (int r = 0; r < 4; r++) o[nt][r] *= al;

        // ---- PV: O^T += V^T @ P^T; b-frag gathered via bpermute ----
#pragma unroll
        for (int ks = 0; ks < 2; ks++) {
            unsigned int a0 = __shfl(pu[2 * ks][0], sA);
            unsigned int a1 = __shfl(pu[2 * ks][1], sA);
            unsigned int c0 = __shfl(pu[2 * ks + 1][0], sA);
            unsigned int c1 = __shfl(pu[2 * ks + 1][1], sA);
            unsigned int b0 = __shfl(pu[2 * ks][0], sB);
            unsigned int b1 = __shfl(pu[2 * ks][1], sB);
            unsigned int g0 = __shfl(pu[2 * ks + 1][0], sB);
            unsigned int g1 = __shfl(pu[2 * ks + 1][1], sB);
            union {
                unsigned int u[4];
                bf16x8 v;
            } pb;
            pb.u[0] = hi ? c0 : a0;
            pb.u[1] = hi ? c1 : a1;
            pb.u[2] = hi ? g0 : b0;
            pb.u[3] = hi ? g1 : b1;
            __builtin_amdgcn_s_setprio(1);
#pragma unroll
            for (int nt = 0; nt < 8; nt++) {
                bf16x8 vf = *reinterpret_cast<const bf16x8*>(
                    Vb + ks * 8192 + swz64(16 * nt + col, quad * 16));
                o[nt] = __builtin_amdgcn_mfma_f32_16x16x32_bf16(vf, pb.v, o[nt], 0, 0, 0);
            }
            __builtin_amdgcn_s_setprio(0);
        }

        __syncthreads();  // drains vmcnt (tile tt+1 landed) + all waves done with buf[cur]
        cur ^= 1;
    }

    // ---- epilogue: O /= l, write bf16 (stride HID); r-values are contiguous in d ----
    u16* outp = Out + (CAUSAL ? (size_t)eZ * ((size_t)S * HID) : (size_t)0);
    float inv = 1.f / l_;
    size_t rowoff = (size_t)(q0 + 16 * w + col) * HID + (size_t)h * HD + 4 * quad;
#pragma unroll
    for (int nt = 0; nt < 8; nt++) {
        ushort4 st;
        st.x = f2bu(o[nt][0] * inv);
        st.y = f2bu(o[nt][1] * inv);
        st.z = f2bu(o[nt][2] * inv);
        st.w = f2bu(o[nt][3] * inv);
        *reinterpret_cast<ushort4*>(&outp[rowoff + 16 * nt]) = st;
    }
}

// ---------------- f32 -> output dtype (per flag) ----------------
__global__ __launch_bounds__(256) void store_out_kernel(const float* __restrict__ a,
                                                        const float* __restrict__ b,
                                                        void* __restrict__ out,
                                                        const int* __restrict__ flag) {
    bool isbf = (*flag != 0);
    size_t i = (size_t)blockIdx.x * 256 + threadIdx.x;
    const size_t MM = (size_t)S * HID;
    float v = (i < MM) ? a[i] : b[i - MM];
    if (isbf)
        ((bf16*)out)[i] = __float2bfloat16(v);
    else
        ((float*)out)[i] = v;
}

extern "C" void kernel_launch(void* const* d_in, const int* in_sizes, int n_in,
                              void* d_out, int out_size, void* d_ws, size_t ws_size,
                              hipStream_t stream) {
    const void* x[2] = {d_in[0], d_in[1]};
    const void* w_ln[2] = {d_in[5], d_in[14]};
    const void* w_q[2] = {d_in[6], d_in[15]};
    const void* w_k[2] = {d_in[7], d_in[16]};
    const void* w_v[2] = {d_in[8], d_in[17]};
    const void* w_o[2] = {d_in[9], d_in[18]};
    const void* w_pln[2] = {d_in[10], d_in[19]};
    const void* w_g[2] = {d_in[11], d_in[20]};
    const void* w_u[2] = {d_in[12], d_in[21]};
    const void* w_d[2] = {d_in[13], d_in[22]};

    char* base = (char*)d_ws;
    int* flag = (int*)base;
    u16* p = (u16*)(base + 256);
    const size_t E_QKV = (size_t)S * 3072;
    const size_t E_SH = (size_t)S * HID;
    const size_t E_VT = (size_t)NH * HD * S;  // == E_SH

    u16* qkv[2] = {p, p + E_QKV};            p += 2 * E_QKV;
    u16* qr = p;                             p += 2 * E_SH;  // [expert]
    u16* kr = p;                             p += 2 * E_SH;  // adjacent to qr
    u16* h_bf = p;                           p += 2 * E_SH;
    u16* attnbuf = p;                        p += 2 * E_SH;
    u16* vtg = p;                            p += 2 * E_VT;
    // gated (S*INTER = 8.39M u16) overlays qr+kr (4*E_SH = 8.39M, free after causal attn);
    // mixed (2S*HID = 4.19M u16) overlays the same region (free after down GEMMs).
    u16* gated = qr;
    u16* mixed = qr;
    u16* wqkvT = p;                          p += 2 * (size_t)3072 * 1024;
    u16* woT[2] = {p, p + (size_t)1024 * 1024};  p += 2 * (size_t)1024 * 1024;
    u16* wgT = p;                            p += (size_t)INTER * 1024;
    u16* wuT = p;                            p += (size_t)INTER * 1024;
    u16* wdT = p;                            p += (size_t)1024 * INTER;
    float* fbase = (float*)(((size_t)p + 255) & ~(size_t)255);
    float* outX[2] = {fbase, fbase + E_SH};

    probe_kernel<<<1, 256, 0, stream>>>((const unsigned short*)d_in[0], flag);

    // ---- upfront transposes: qkv + wo weights for both experts, one z=8 dispatch ----
    {
        TransN tn = {};
        for (int e = 0; e < 2; e++) {
            u16* wt = wqkvT + (size_t)e * 3072 * 1024;
            tn.W[4 * e + 0] = w_q[e];  tn.T[4 * e + 0] = wt;
            tn.W[4 * e + 1] = w_k[e];  tn.T[4 * e + 1] = wt + (size_t)1024 * 1024;
            tn.W[4 * e + 2] = w_v[e];  tn.T[4 * e + 2] = wt + (size_t)2048 * 1024;
            tn.W[4 * e + 3] = w_o[e];  tn.T[4 * e + 3] = woT[e];
        }
        transpose_wN<<<dim3(32, 32, 8), 256, 0, stream>>>(tn, flag, 1024, 1024);
    }

    // ---- fused attention path (both experts per dispatch) ----
    {
        RmsDual rd = {{x[0], x[1]}, {w_ln[0], w_ln[1]}, {h_bf, h_bf + E_SH}};
        rmsnorm_kernel<<<dim3(S, 2), 256, 0, stream>>>(rd, flag, 1);
    }
    {
        GemmDual g = {{h_bf, h_bf + E_SH},
                      {wqkvT, wqkvT + (size_t)3072 * 1024},
                      {nullptr, nullptr},
                      {qkv[0], qkv[1]},
                      {nullptr, nullptr}};
        gemm_mfma<128, 128, 2, 2, 0><<<dim3(3072 / 128, S / 128, 2), 256, 0, stream>>>(
            g, flag, S, 3072, 1024);
    }
    rope_kernel<<<dim3(S * NH, 1, 2), 64, 0, stream>>>(qkv[0], qkv[1], qr, kr);
    transpose_v<<<dim3(S / 32, 1024 / 32, 2), 256, 0, stream>>>(qkv[0] + 2048, qkv[1] + 2048, 3072, vtg);
    attn_mfma_kernel<true><<<dim3(S / 64, NH, 2), 256, 0, stream>>>(
        qr, qr + E_SH, HID, kr, kr + E_SH, HID, vtg, vtg + E_VT, attnbuf, S);
    {
        GemmDual g = {{attnbuf, attnbuf + E_SH},
                      {woT[0], woT[1]},
                      {outX[0], outX[1]},
                      {nullptr, nullptr},
                      {x[0], x[1]}};
        gemm_mfma<64, 64, 2, 2, 1><<<dim3(1024 / 64, S / 64, 2), 256, 0, stream>>>(
            g, flag, S, 1024, 1024);
    }
    {
        RmsDual rd = {{outX[0], outX[1]}, {w_pln[0], w_pln[1]}, {h_bf, h_bf + E_SH}};
        rmsnorm_kernel<<<dim3(S, 2), 256, 0, stream>>>(rd, flag, 0);
    }

    // ---- MLP per expert (weight buffers reused; gated overlays dead qr/kr) ----
    for (int e = 0; e < 2; e++) {
        {
            TransN tg = {};
            tg.W[0] = w_g[e];  tg.T[0] = wgT;
            tg.W[1] = w_u[e];  tg.T[1] = wuT;
            transpose_wN<<<dim3(INTER / 32, 1024 / 32, 2), 256, 0, stream>>>(tg, flag, 1024, INTER);
        }
        gemm_gated_mfma<128, 64, 2, 2><<<dim3(INTER / 64, S / 128), 256, 0, stream>>>(
            h_bf + e * E_SH, wgT, wuT, gated, S, INTER, 1024);
        {
            TransN td = {};
            td.W[0] = w_d[e];  td.T[0] = wdT;
            transpose_wN<<<dim3(1024 / 32, INTER / 32, 1), 256, 0, stream>>>(td, flag, INTER, 1024);
        }
        GemmDual g = {{gated, gated}, {wdT, wdT}, {outX[e], outX[e]}, {nullptr, nullptr}, {nullptr, nullptr}};
        gemm_mfma<64, 64, 2, 2, 2><<<dim3(1024 / 64, S / 64, 1), 256, 0, stream>>>(
            g, flag, S, 1024, INTER);
    }

    // ---- mixed attention + fused output projections ----
    attn_mfma_kernel<false><<<dim3(2 * S / 64, NH), 256, 0, stream>>>(
        qkv[0], qkv[1], 3072, qkv[0] + 1024, qkv[1] + 1024, 3072,
        vtg, vtg + E_VT, mixed, 2 * S);
    {
        GemmDual g = {{mixed, mixed + E_SH},
                      {woT[0], woT[1]},
                      {outX[0], outX[1]},
                      {nullptr, nullptr},
                      {nullptr, nullptr}};
        gemm_mfma<64, 64, 2, 2, 2><<<dim3(1024 / 64, S / 64, 2), 256, 0, stream>>>(
            g, flag, S, 1024, 1024);
    }

    store_out_kernel<<<(2 * E_SH) / 256, 256, 0, stream>>>(outX[0], outX[1], d_out, flag);
}

// Round 7
// 784.830 us; speedup vs baseline: 1.8048x; 1.0146x over previous
//
#include <hip/hip_runtime.h>
#include <hip/hip_bf16.h>
#include <math.h>

#define S 2048
#define HID 1024
#define NH 8
#define HD 128
#define INTER 4096
#define EPSV 1e-6f
#define THETA 10000.0f

typedef __hip_bfloat16 bf16;
typedef unsigned short u16;
typedef __attribute__((ext_vector_type(8))) short bf16x8;  // 8 bf16 = 4 VGPRs
typedef __attribute__((ext_vector_type(4))) float f32x4;

__device__ inline float bu2f(u16 u) {
    unsigned int x = ((unsigned int)u) << 16;
    return __uint_as_float(x);
}
__device__ inline u16 f2bu(float f) {
    bf16 h = __float2bfloat16(f);
    return *reinterpret_cast<u16*>(&h);
}
// Dual-dtype input load (raw harness inputs): isbf ? bf16 : f32
__device__ inline float ldin(const void* p, size_t i, bool isbf) {
    return isbf ? bu2f(((const u16*)p)[i]) : ((const float*)p)[i];
}
__device__ inline float gelu_tanh(float x) {
    float x3 = x * x * x;
    return 0.5f * x * (1.f + tanhf(0.7978845608028654f * (x + 0.044715f * x3)));
}
// Direct global->LDS 16B/lane async copy. LDS dest must be wave-uniform;
// lane i's 16B lands at ldsbase + i*16. Global source IS per-lane.
__device__ inline void gload16(const u16* g, u16* l) {
    __builtin_amdgcn_global_load_lds(
        (const __attribute__((address_space(1))) void*)g,
        (__attribute__((address_space(3))) void*)l, 16, 0, 0);
}

// ---------------- dtype probe (round-1 notes) ----------------
__global__ __launch_bounds__(256) void probe_kernel(const unsigned short* __restrict__ x,
                                                    int* __restrict__ flag) {
    __shared__ int red[256];
    int tid = threadIdx.x;
    int cnt = 0;
    for (int i = tid; i < 2048; i += 256) {
        unsigned short u = x[2 * i];
        int e = (u >> 7) & 0xFF;
        cnt += (e >= 110 && e <= 135) ? 1 : 0;
    }
    red[tid] = cnt;
    __syncthreads();
    for (int off = 128; off > 0; off >>= 1) {
        if (tid < off) red[tid] += red[tid + off];
        __syncthreads();
    }
    if (tid == 0) *flag = (red[0] > 1024) ? 1 : 0;
}

// ---------------- weight transpose+convert, z-batched: W (KxN) -> WT (NxK, bf16) ----------------
struct TransN {
    const void* W[8];
    u16* T[8];
};
__global__ __launch_bounds__(256) void transpose_wN(TransN tn, const int* __restrict__ flag,
                                                    int K, int N) {
    bool isbf = (*flag != 0);
    const void* W = tn.W[blockIdx.z];
    u16* WT = tn.T[blockIdx.z];
    __shared__ float t[32][33];
    int n0 = blockIdx.x * 32, k0 = blockIdx.y * 32;
    int c = threadIdx.x & 31, r = threadIdx.x >> 5;
#pragma unroll
    for (int p = 0; p < 4; p++)
        t[r + 8 * p][c] = ldin(W, (size_t)(k0 + r + 8 * p) * N + n0 + c, isbf);
    __syncthreads();
#pragma unroll
    for (int p = 0; p < 4; p++) {
        int row = r + 8 * p;
        WT[(size_t)(n0 + row) * K + k0 + c] = f2bu(t[c][row]);
    }
}

// ---------------- V transpose (dual-expert via z): V[key][dh] -> VT[dh][key] ----------------
__global__ __launch_bounds__(256) void transpose_v(const u16* __restrict__ V0,
                                                   const u16* __restrict__ V1, int sv,
                                                   u16* __restrict__ VT) {
    const u16* V = blockIdx.z ? V1 : V0;
    VT += (size_t)blockIdx.z * ((size_t)NH * HD * S);
    __shared__ u16 t[32][33];
    int k0 = blockIdx.x * 32;  // key tile
    int d0 = blockIdx.y * 32;  // dh tile
    int c = threadIdx.x & 31, r = threadIdx.x >> 5;
#pragma unroll
    for (int p = 0; p < 4; p++)
        t[r + 8 * p][c] = V[(size_t)(k0 + r + 8 * p) * sv + d0 + c];
    __syncthreads();
#pragma unroll
    for (int p = 0; p < 4; p++)
        VT[(size_t)(d0 + r + 8 * p) * S + k0 + c] = t[c][r + 8 * p];
}

// ---------------- RMSNorm -> bf16 (dual-expert via blockIdx.y) ----------------
struct RmsDual {
    const void* x[2];
    const void* w[2];
    u16* y[2];
};
__global__ __launch_bounds__(256) void rmsnorm_kernel(RmsDual rd,
                                                      const int* __restrict__ flag,
                                                      int dual) {
    int e = blockIdx.y;
    const void* x = rd.x[e];
    const void* w = rd.w[e];
    u16* y = rd.y[e];
    bool isbf = (*flag != 0);
    bool xbf = dual && isbf;
    int row = blockIdx.x;
    size_t base = (size_t)row * HID;
    __shared__ float red[256];
    float xv[4];
    float s = 0.f;
#pragma unroll
    for (int i = 0; i < 4; i++) {
        float v = ldin(x, base + threadIdx.x + 256 * i, xbf);
        xv[i] = v;
        s += v * v;
    }
    red[threadIdx.x] = s;
    __syncthreads();
    for (int off = 128; off > 0; off >>= 1) {
        if (threadIdx.x < off) red[threadIdx.x] += red[threadIdx.x + off];
        __syncthreads();
    }
    float scale = rsqrtf(red[0] / (float)HID + EPSV);
#pragma unroll
    for (int i = 0; i < 4; i++) {
        int c = threadIdx.x + 256 * i;
        y[base + c] = f2bu(xv[i] * scale * (1.f + ldin(w, c, isbf)));
    }
}

// ================= MFMA GEMM (v3: gload16 staging + dual-expert via blockIdx.z) =================
// LDS tiles are LINEAR [row][64B] (BK=32 bf16 per row). global_load_lds writes lane-linear,
// so the XOR swizzle (chunk ^= (row>>1)&3, 16B chunks within the 64B row) is applied on the
// per-lane GLOBAL SOURCE address at load time and again on the frag-read address (involution).
struct GemmDual {
    const u16* A[2];
    const u16* BT[2];
    float* Cf[2];
    u16* Cb[2];
    const void* res[2];
};
template <int BM, int BN, int WRN, int WCN, int EPI>
__global__ __launch_bounds__(256) void gemm_mfma(GemmDual g, const int* __restrict__ flag,
                                                 int M, int N, int K) {
    int eZ = blockIdx.z;
    const u16* __restrict__ A = g.A[eZ];
    const u16* __restrict__ BT = g.BT[eZ];
    float* __restrict__ Cf = g.Cf[eZ];
    u16* __restrict__ Cb = g.Cb[eZ];
    const void* __restrict__ res = g.res[eZ];
    constexpr int BK = 32;
    constexpr int WM = BM / WRN, WN = BN / WCN, TI = WM / 16, TJ = WN / 16;
    __shared__ u16 As[BM * 32];
    __shared__ u16 Bs[BN * 32];
    int tid = threadIdx.x, lane = tid & 63, wv = tid >> 6;
    int wr = wv / WCN, wc = wv % WCN;
    int m = lane & 15, quad = lane >> 4;
    int m0 = blockIdx.y * BM, n0 = blockIdx.x * BN;
    f32x4 acc[TI][TJ] = {};
    for (int k0 = 0; k0 < K; k0 += BK) {
        __syncthreads();  // prev compute done reading LDS
#pragma unroll
        for (int c2 = 0; c2 < BM / 64; c2++) {
            int row0 = (wv * (BM / 64) + c2) * 16;
            int row = row0 + (lane >> 2);
            int ch = lane & 3;
            gload16(&A[(size_t)(m0 + row) * K + k0 + ((ch ^ ((row >> 1) & 3)) << 3)],
                    &As[row0 * 32]);
        }
#pragma unroll
        for (int c2 = 0; c2 < BN / 64; c2++) {
            int row0 = (wv * (BN / 64) + c2) * 16;
            int row = row0 + (lane >> 2);
            int ch = lane & 3;
            gload16(&BT[(size_t)(n0 + row) * K + k0 + ((ch ^ ((row >> 1) & 3)) << 3)],
                    &Bs[row0 * 32]);
        }
        __syncthreads();  // vmcnt drained by barrier -> tiles in LDS
        bf16x8 af[TI], bf_[TJ];
#pragma unroll
        for (int i = 0; i < TI; i++) {
            int rr = wr * WM + i * 16 + m;
            af[i] = *reinterpret_cast<const bf16x8*>(&As[rr * 32 + ((quad ^ ((rr >> 1) & 3)) << 3)]);
        }
#pragma unroll
        for (int j = 0; j < TJ; j++) {
            int rr = wc * WN + j * 16 + m;
            bf_[j] = *reinterpret_cast<const bf16x8*>(&Bs[rr * 32 + ((quad ^ ((rr >> 1) & 3)) << 3)]);
        }
#pragma unroll
        for (int i = 0; i < TI; i++)
#pragma unroll
            for (int j = 0; j < TJ; j++)
                acc[i][j] = __builtin_amdgcn_mfma_f32_16x16x32_bf16(af[i], bf_[j], acc[i][j], 0, 0, 0);
    }
    bool isbf = (EPI == 1) ? (*flag != 0) : false;
#pragma unroll
    for (int i = 0; i < TI; i++) {
#pragma unroll
        for (int j = 0; j < TJ; j++) {
#pragma unroll
            for (int r = 0; r < 4; r++) {
                int row = m0 + wr * WM + i * 16 + quad * 4 + r;
                int col = n0 + wc * WN + j * 16 + m;
                size_t idx = (size_t)row * N + col;
                float v = acc[i][j][r];
                if (EPI == 0) Cb[idx] = f2bu(v);
                else if (EPI == 1) Cf[idx] = v + ldin(res, idx, isbf);
                else Cf[idx] = Cf[idx] + v;
            }
        }
    }
}

// ------------- Fused gated MLP MFMA: C(bf16) = gelu(A@Wg) * (A@Wu) -------------
template <int BM, int BN, int WRN, int WCN>
__global__ __launch_bounds__(256) void gemm_gated_mfma(const u16* __restrict__ A,
                                                       const u16* __restrict__ BgT,
                                                       const u16* __restrict__ BuT,
                                                       u16* __restrict__ C,
                                                       int M, int N, int K) {
    constexpr int BK = 32;
    constexpr int WM = BM / WRN, WN = BN / WCN, TI = WM / 16, TJ = WN / 16;
    __shared__ u16 As[BM * 32];
    __shared__ u16 Bgs[BN * 32];
    __shared__ u16 Bus[BN * 32];
    int tid = threadIdx.x, lane = tid & 63, wv = tid >> 6;
    int wr = wv / WCN, wc = wv % WCN;
    int m = lane & 15, quad = lane >> 4;
    int m0 = blockIdx.y * BM, n0 = blockIdx.x * BN;
    f32x4 accg[TI][TJ] = {};
    f32x4 accu[TI][TJ] = {};
    for (int k0 = 0; k0 < K; k0 += BK) {
        __syncthreads();
#pragma unroll
        for (int c2 = 0; c2 < BM / 64; c2++) {
            int row0 = (wv * (BM / 64) + c2) * 16;
            int row = row0 + (lane >> 2);
            int ch = lane & 3;
            gload16(&A[(size_t)(m0 + row) * K + k0 + ((ch ^ ((row >> 1) & 3)) << 3)],
                    &As[row0 * 32]);
        }
#pragma unroll
        for (int c2 = 0; c2 < BN / 64; c2++) {
            int row0 = (wv * (BN / 64) + c2) * 16;
            int row = row0 + (lane >> 2);
            int ch = lane & 3;
            gload16(&BgT[(size_t)(n0 + row) * K + k0 + ((ch ^ ((row >> 1) & 3)) << 3)],
                    &Bgs[row0 * 32]);
            gload16(&BuT[(size_t)(n0 + row) * K + k0 + ((ch ^ ((row >> 1) & 3)) << 3)],
                    &Bus[row0 * 32]);
        }
        __syncthreads();
        bf16x8 af[TI], bg[TJ], bu[TJ];
#pragma unroll
        for (int i = 0; i < TI; i++) {
            int rr = wr * WM + i * 16 + m;
            af[i] = *reinterpret_cast<const bf16x8*>(&As[rr * 32 + ((quad ^ ((rr >> 1) & 3)) << 3)]);
        }
#pragma unroll
        for (int j = 0; j < TJ; j++) {
            int rr = wc * WN + j * 16 + m;
            int off = rr * 32 + ((quad ^ ((rr >> 1) & 3)) << 3);
            bg[j] = *reinterpret_cast<const bf16x8*>(&Bgs[off]);
            bu[j] = *reinterpret_cast<const bf16x8*>(&Bus[off]);
        }
#pragma unroll
        for (int i = 0; i < TI; i++)
#pragma unroll
            for (int j = 0; j < TJ; j++) {
                accg[i][j] = __builtin_amdgcn_mfma_f32_16x16x32_bf16(af[i], bg[j], accg[i][j], 0, 0, 0);
                accu[i][j] = __builtin_amdgcn_mfma_f32_16x16x32_bf16(af[i], bu[j], accu[i][j], 0, 0, 0);
            }
    }
#pragma unroll
    for (int i = 0; i < TI; i++)
#pragma unroll
        for (int j = 0; j < TJ; j++)
#pragma unroll
            for (int r = 0; r < 4; r++) {
                int row = m0 + wr * WM + i * 16 + quad * 4 + r;
                int col = n0 + wc * WN + j * 16 + m;
                C[(size_t)row * N + col] = f2bu(gelu_tanh(accg[i][j][r]) * accu[i][j][r]);
            }
}

// ---------------- RoPE (dual-expert via z): qkv (stride 3072) -> qr/kr (stride 1024) ----------------
__global__ __launch_bounds__(64) void rope_kernel(const u16* __restrict__ qkv0,
                                                  const u16* __restrict__ qkv1,
                                                  u16* __restrict__ qr,
                                                  u16* __restrict__ kr) {
    const u16* qkv = blockIdx.z ? qkv1 : qkv0;
    size_t zo = (size_t)blockIdx.z * ((size_t)S * HID);
    int b = blockIdx.x;
    int t = b >> 3, h = b & 7;
    int i = threadIdx.x;  // 0..63
    size_t ib = (size_t)t * 3072 + h * HD;
    size_t ob = zo + (size_t)t * HID + h * HD;
    // powf(THETA, -x) == exp(-x * ln(THETA)); ln(10000) = 9.210340372
    float inv = __expf(-9.210340372f * (float)(2 * i) / (float)HD);
    float f = (float)t * inv;
    float c = cosf(f), s = sinf(f);
    float q1 = bu2f(qkv[ib + i]), q2 = bu2f(qkv[ib + i + 64]);
    qr[ob + i] = f2bu(q1 * c - q2 * s);
    qr[ob + i + 64] = f2bu(q2 * c + q1 * s);
    float k1 = bu2f(qkv[ib + 1024 + i]), k2 = bu2f(qkv[ib + 1024 + i + 64]);
    kr[ob + i] = f2bu(k1 * c - k2 * s);
    kr[ob + i + 64] = f2bu(k2 * c + k1 * s);
}

__device__ inline int swz64(int row, int b) {
    return row * 64 + (b ^ (((row >> 1) & 3) << 4));
}

// ============ MFMA flash attention, CAUSAL (v4: gload16 double-buffered) ============
// Grid-limited at 2 blocks/CU (512 blocks) so 64KB double-buffer LDS costs nothing.
template <bool CAUSAL>
__global__ __launch_bounds__(256, 2) void attn_mfma_kernel(
    const u16* __restrict__ qa, const u16* __restrict__ qb, int sq,
    const u16* __restrict__ ka, const u16* __restrict__ kb, int sk,
    const u16* __restrict__ vta, const u16* __restrict__ vtb,
    u16* __restrict__ Out, int nkeys) {
    __shared__ char Ks[2][16384];   // [buf][t=d/32][key][32 d] swizzled 64B rows
    __shared__ char VTs[2][16384];  // [buf][ks=key/32][d][32 keys] swizzled

    int tid = threadIdx.x;
    int lane = tid & 63, w = tid >> 6;
    int col = lane & 15, quad = lane >> 4;
    int eZ = CAUSAL ? (int)blockIdx.z : 0;
    int bx = (CAUSAL && eZ) ? ((int)gridDim.x - 1 - (int)blockIdx.x) : (int)blockIdx.x;
    int q0 = bx * 64;
    int h = blockIdx.y;
    const float scale = 0.08838834764831845f;  // 1/sqrt(128)

    int q0r = CAUSAL ? q0 : (q0 & (S - 1));
    const u16* qsel = CAUSAL ? (eZ ? qb : qa) : ((q0 < S) ? qa : qb);
    const u16* qp = qsel + (size_t)q0r * sq;
    bf16x8 aq[4];
#pragma unroll
    for (int t = 0; t < 4; t++)
        aq[t] = *reinterpret_cast<const bf16x8*>(
            qp + (size_t)(16 * w + col) * sq + h * HD + 32 * t + quad * 8);

    const u16* kplo = (CAUSAL && eZ) ? kb : ka;
    const u16* vplo = (CAUSAL && eZ) ? vtb : vta;

    f32x4 o[8] = {};           // O^T: o[nt][r] = O[q][d = 16nt + 4quad + r]
    float m_ = -1e30f, l_ = 0.f;

    int sA = col + 16 * (2 * (quad & 1));
    int sB = sA + 16;
    bool hi = (quad >> 1) != 0;

    int ntiles = CAUSAL ? (q0 >> 6) + 1 : (nkeys >> 6);

    auto stage = [&](int buf, int tt) {
        int j0r = (tt * 64) & (S - 1);
        bool eb = (!CAUSAL) && (tt >= (S >> 6));
        const u16* kp = eb ? kb : kplo;
        const u16* vp = eb ? vtb : vplo;
        char* kd = &Ks[buf][(tid >> 6) * 1024];
        char* vd = &VTs[buf][(tid >> 6) * 1024];
#pragma unroll
        for (int i = 0; i < 4; i++) {
            int l = 256 * i + tid;
            int key = (l >> 2) & 63;
            int c = (l >> 8) * 4 + ((l & 3) ^ ((key >> 1) & 3));
            gload16(kp + (size_t)(j0r + key) * sk + h * HD + c * 8, (u16*)(kd + i * 4096));
        }
#pragma unroll
        for (int i = 0; i < 4; i++) {
            int l = 256 * i + tid;
            int d = (l >> 2) & 127;
            int c = (l >> 9) * 4 + ((l & 3) ^ ((d >> 1) & 3));
            gload16(vp + (size_t)(h * HD + d) * S + j0r + c * 8, (u16*)(vd + i * 4096));
        }
    };

    stage(0, 0);
    __syncthreads();
    int cur = 0;

    for (int tt = 0; tt < ntiles; tt++) {
        if (tt + 1 < ntiles) stage(cur ^ 1, tt + 1);
        const char* Kb = Ks[cur];
        const char* Vb = VTs[cur];

        f32x4 sc[4] = {};
        __builtin_amdgcn_s_setprio(1);
#pragma unroll
        for (int t = 0; t < 4; t++) {
#pragma unroll
            for (int ct = 0; ct < 4; ct++) {
                bf16x8 kf = *reinterpret_cast<const bf16x8*>(
                    Kb + t * 4096 + swz64(16 * ct + col, quad * 16));
                sc[ct] = __builtin_amdgcn_mfma_f32_16x16x32_bf16(kf, aq[t], sc[ct], 0, 0, 0);
            }
        }
        __builtin_amdgcn_s_setprio(0);
        bool diag = CAUSAL && (tt == ntiles - 1);
#pragma unroll
        for (int ct = 0; ct < 4; ct++) {
#pragma unroll
            for (int r = 0; r < 4; r++) {
                float v = sc[ct][r] * scale;
                if (diag && (16 * ct + 4 * quad + r > 16 * w + col)) v = -1e30f;
                sc[ct][r] = v;
            }
        }

        float mx0 = fmaxf(fmaxf(sc[0][0], sc[0][1]), fmaxf(sc[0][2], sc[0][3]));
        float mx1 = fmaxf(fmaxf(sc[1][0], sc[1][1]), fmaxf(sc[1][2], sc[1][3]));
        float mx2 = fmaxf(fmaxf(sc[2][0], sc[2][1]), fmaxf(sc[2][2], sc[2][3]));
        float mx3 = fmaxf(fmaxf(sc[3][0], sc[3][1]), fmaxf(sc[3][2], sc[3][3]));
        float rmax = fmaxf(fmaxf(mx0, mx1), fmaxf(mx2, mx3));
        rmax = fmaxf(rmax, __shfl_xor(rmax, 16));
        rmax = fmaxf(rmax, __shfl_xor(rmax, 32));
        float mn = fmaxf(m_, rmax);
        float al = __expf(m_ - mn);
#pragma unroll
        for (int ct = 0; ct < 4; ct++)
#pragma unroll
            for (int r = 0; r < 4; r++) sc[ct][r] = __expf(sc[ct][r] - mn);
        float s0 = (sc[0][0] + sc[0][1]) + (sc[0][2] + sc[0][3]);
        float s1 = (sc[1][0] + sc[1][1]) + (sc[1][2] + sc[1][3]);
        float s2 = (sc[2][0] + sc[2][1]) + (sc[2][2] + sc[2][3]);
        float s3 = (sc[3][0] + sc[3][1]) + (sc[3][2] + sc[3][3]);
        float rs = (s0 + s1) + (s2 + s3);
        rs += __shfl_xor(rs, 16);
        rs += __shfl_xor(rs, 32);
        l_ = l_ * al + rs;
        m_ = mn;

        unsigned int pu[4][2];
#pragma unroll
        for (int ct = 0; ct < 4; ct++) {
            pu[ct][0] = (unsigned int)f2bu(sc[ct][0]) | ((unsigned int)f2bu(sc[ct][1]) << 16);
            pu[ct][1] = (unsigned int)f2bu(sc[ct][2]) | ((unsigned int)f2bu(sc[ct][3]) << 16);
        }

#pragma unroll
        for (int nt = 0; nt < 8; nt++)
#pragma unroll
            for (int r = 0; r < 4; r++) o[nt][r] *= al;

#pragma unroll
        for (int ks = 0; ks < 2; ks++) {
            unsigned int a0 = __shfl(pu[2 * ks][0], sA);
            unsigned int a1 = __shfl(pu[2 * ks][1], sA);
            unsigned int c0 = __shfl(pu[2 * ks + 1][0], sA);
            unsigned int c1 = __shfl(pu[2 * ks + 1][1], sA);
            unsigned int b0 = __shfl(pu[2 * ks][0], sB);
            unsigned int b1 = __shfl(pu[2 * ks][1], sB);
            unsigned int g0 = __shfl(pu[2 * ks + 1][0], sB);
            unsigned int g1 = __shfl(pu[2 * ks + 1][1], sB);
            union {
                unsigned int u[4];
                bf16x8 v;
            } pb;
            pb.u[0] = hi ? c0 : a0;
            pb.u[1] = hi ? c1 : a1;
            pb.u[2] = hi ? g0 : b0;
            pb.u[3] = hi ? g1 : b1;
            __builtin_amdgcn_s_setprio(1);
#pragma unroll
            for (int nt = 0; nt < 8; nt++) {
                bf16x8 vf = *reinterpret_cast<const bf16x8*>(
                    Vb + ks * 8192 + swz64(16 * nt + col, quad * 16));
                o[nt] = __builtin_amdgcn_mfma_f32_16x16x32_bf16(vf, pb.v, o[nt], 0, 0, 0);
            }
            __builtin_amdgcn_s_setprio(0);
        }

        __syncthreads();
        cur ^= 1;
    }

    u16* outp = Out + (CAUSAL ? (size_t)eZ * ((size_t)S * HID) : (size_t)0);
    float inv = 1.f / l_;
    size_t rowoff = (size_t)(q0 + 16 * w + col) * HID + (size_t)h * HD + 4 * quad;
#pragma unroll
    for (int nt = 0; nt < 8; nt++) {
        ushort4 st;
        st.x = f2bu(o[nt][0] * inv);
        st.y = f2bu(o[nt][1] * inv);
        st.z = f2bu(o[nt][2] * inv);
        st.w = f2bu(o[nt][3] * inv);
        *reinterpret_cast<ushort4*>(&outp[rowoff + 16 * nt]) = st;
    }
}

// ============ Mixed attention, key-split (flash-decoding, 2 splits) ============
// blockIdx.z = split = expert whose 2048 keys this block processes. Single-buffer
// 32KB LDS -> 4 blocks/CU resident (16 waves) on the 1024-block grid. Writes
// UNNORMALIZED partial O (bf16, referenced to local max m) + per-row (m, l);
// attn_combine merges the two splits.
__global__ __launch_bounds__(256, 4) void attn_mixed_split(
    const u16* __restrict__ qa, const u16* __restrict__ qb, int sq,
    const u16* __restrict__ ka, const u16* __restrict__ kb, int sk,
    const u16* __restrict__ vta, const u16* __restrict__ vtb,
    u16* __restrict__ Opart, float2* __restrict__ ml) {
    __shared__ char Ks[16384];
    __shared__ char VTs[16384];

    int tid = threadIdx.x;
    int lane = tid & 63, w = tid >> 6;
    int col = lane & 15, quad = lane >> 4;
    int q0 = blockIdx.x * 64;  // 0..4032 over 2S queries
    int h = blockIdx.y;
    int z = blockIdx.z;  // split/expert
    const float scale = 0.08838834764831845f;

    const u16* qp = ((q0 < S) ? qa : qb) + (size_t)(q0 & (S - 1)) * sq;
    bf16x8 aq[4];
#pragma unroll
    for (int t = 0; t < 4; t++)
        aq[t] = *reinterpret_cast<const bf16x8*>(
            qp + (size_t)(16 * w + col) * sq + h * HD + 32 * t + quad * 8);

    const u16* kp = z ? kb : ka;
    const u16* vp = z ? vtb : vta;

    f32x4 o[8] = {};
    float m_ = -1e30f, l_ = 0.f;

    int sA = col + 16 * (2 * (quad & 1));
    int sB = sA + 16;
    bool hi = (quad >> 1) != 0;

    for (int tt = 0; tt < (S >> 6); tt++) {
        int j0r = tt * 64;
        __syncthreads();  // prev compute done reading LDS
        {
            char* kd = &Ks[(tid >> 6) * 1024];
            char* vd = &VTs[(tid >> 6) * 1024];
#pragma unroll
            for (int i = 0; i < 4; i++) {
                int l = 256 * i + tid;
                int key = (l >> 2) & 63;
                int c = (l >> 8) * 4 + ((l & 3) ^ ((key >> 1) & 3));
                gload16(kp + (size_t)(j0r + key) * sk + h * HD + c * 8, (u16*)(kd + i * 4096));
            }
#pragma unroll
            for (int i = 0; i < 4; i++) {
                int l = 256 * i + tid;
                int d = (l >> 2) & 127;
                int c = (l >> 9) * 4 + ((l & 3) ^ ((d >> 1) & 3));
                gload16(vp + (size_t)(h * HD + d) * S + j0r + c * 8, (u16*)(vd + i * 4096));
            }
        }
        __syncthreads();  // vmcnt drained -> tile in LDS

        f32x4 sc[4] = {};
        __builtin_amdgcn_s_setprio(1);
#pragma unroll
        for (int t = 0; t < 4; t++) {
#pragma unroll
            for (int ct = 0; ct < 4; ct++) {
                bf16x8 kf = *reinterpret_cast<const bf16x8*>(
                    Ks + t * 4096 + swz64(16 * ct + col, quad * 16));
                sc[ct] = __builtin_amdgcn_mfma_f32_16x16x32_bf16(kf, aq[t], sc[ct], 0, 0, 0);
            }
        }
        __builtin_amdgcn_s_setprio(0);
#pragma unroll
        for (int ct = 0; ct < 4; ct++)
#pragma unroll
            for (int r = 0; r < 4; r++) sc[ct][r] *= scale;

        float mx0 = fmaxf(fmaxf(sc[0][0], sc[0][1]), fmaxf(sc[0][2], sc[0][3]));
        float mx1 = fmaxf(fmaxf(sc[1][0], sc[1][1]), fmaxf(sc[1][2], sc[1][3]));
        float mx2 = fmaxf(fmaxf(sc[2][0], sc[2][1]), fmaxf(sc[2][2], sc[2][3]));
        float mx3 = fmaxf(fmaxf(sc[3][0], sc[3][1]), fmaxf(sc[3][2], sc[3][3]));
        float rmax = fmaxf(fmaxf(mx0, mx1), fmaxf(mx2, mx3));
        rmax = fmaxf(rmax, __shfl_xor(rmax, 16));
        rmax = fmaxf(rmax, __shfl_xor(rmax, 32));
        float mn = fmaxf(m_, rmax);
        float al = __expf(m_ - mn);
#pragma unroll
        for (int ct = 0; ct < 4; ct++)
#pragma unroll
            for (int r = 0; r < 4; r++) sc[ct][r] = __expf(sc[ct][r] - mn);
        float s0 = (sc[0][0] + sc[0][1]) + (sc[0][2] + sc[0][3]);
        float s1 = (sc[1][0] + sc[1][1]) + (sc[1][2] + sc[1][3]);
        float s2 = (sc[2][0] + sc[2][1]) + (sc[2][2] + sc[2][3]);
        float s3 = (sc[3][0] + sc[3][1]) + (sc[3][2] + sc[3][3]);
        float rs = (s0 + s1) + (s2 + s3);
        rs += __shfl_xor(rs, 16);
        rs += __shfl_xor(rs, 32);
        l_ = l_ * al + rs;
        m_ = mn;

        unsigned int pu[4][2];
#pragma unroll
        for (int ct = 0; ct < 4; ct++) {
            pu[ct][0] = (unsigned int)f2bu(sc[ct][0]) | ((unsigned int)f2bu(sc[ct][1]) << 16);
            pu[ct][1] = (unsigned int)f2bu(sc[ct][2]) | ((unsigned int)f2bu(sc[ct][3]) << 16);
        }

#pragma unroll
        for (int nt = 0; nt < 8; nt++)
#pragma unroll
            for (int r = 0; r < 4; r++) o[nt][r] *= al;

#pragma unroll
        for (int ks = 0; ks < 2; ks++) {
            unsigned int a0 = __shfl(pu[2 * ks][0], sA);
            unsigned int a1 = __shfl(pu[2 * ks][1], sA);
            unsigned int c0 = __shfl(pu[2 * ks + 1][0], sA);
            unsigned int c1 = __shfl(pu[2 * ks + 1][1], sA);
            unsigned int b0 = __shfl(pu[2 * ks][0], sB);
            unsigned int b1 = __shfl(pu[2 * ks][1], sB);
            unsigned int g0 = __shfl(pu[2 * ks + 1][0], sB);
            unsigned int g1 = __shfl(pu[2 * ks + 1][1], sB);
            union {
                unsigned int u[4];
                bf16x8 v;
            } pb;
            pb.u[0] = hi ? c0 : a0;
            pb.u[1] = hi ? c1 : a1;
            pb.u[2] = hi ? g0 : b0;
            pb.u[3] = hi ? g1 : b1;
            __builtin_amdgcn_s_setprio(1);
#pragma unroll
            for (int nt = 0; nt < 8; nt++) {
                bf16x8 vf = *reinterpret_cast<const bf16x8*>(
                    VTs + ks * 8192 + swz64(16 * nt + col, quad * 16));
                o[nt] = __builtin_amdgcn_mfma_f32_16x16x32_bf16(vf, pb.v, o[nt], 0, 0, 0);
            }
            __builtin_amdgcn_s_setprio(0);
        }
    }

    // partial epilogue: UNNORMALIZED O (bf16) + (m,l) per q-row
    const size_t SPL = (size_t)2 * S * HID;  // per-split element count
    size_t rowoff = (size_t)z * SPL + (size_t)(q0 + 16 * w + col) * HID + (size_t)h * HD + 4 * quad;
#pragma unroll
    for (int nt = 0; nt < 8; nt++) {
        ushort4 st;
        st.x = f2bu(o[nt][0]);
        st.y = f2bu(o[nt][1]);
        st.z = f2bu(o[nt][2]);
        st.w = f2bu(o[nt][3]);
        *reinterpret_cast<ushort4*>(&Opart[rowoff + 16 * nt]) = st;
    }
    if (quad == 0)
        ml[((size_t)z * 2 * S + q0 + 16 * w + col) * NH + h] = make_float2(m_, l_);
}

// ---------------- combine the 2 key-splits: out = (w0*O0 + w1*O1)/(w0*l0 + w1*l1) ----------------
__global__ __launch_bounds__(256) void attn_combine(const u16* __restrict__ Opart,
                                                    const float2* __restrict__ ml,
                                                    u16* __restrict__ out) {
    size_t idx = ((size_t)blockIdx.x * 256 + threadIdx.x) * 8;  // over 2S*HID elements
    int q = (int)(idx >> 10);
    int c0 = (int)(idx & 1023);
    int h = c0 >> 7;
    float2 ml0 = ml[(size_t)q * NH + h];
    float2 ml1 = ml[((size_t)2 * S + q) * NH + h];
    float ms = fmaxf(ml0.x, ml1.x);
    float w0 = __expf(ml0.x - ms), w1 = __expf(ml1.x - ms);
    float rden = 1.f / (w0 * ml0.y + w1 * ml1.y);
    const size_t SPL = (size_t)2 * S * HID;
    uint4 a = *reinterpret_cast<const uint4*>(&Opart[idx]);
    uint4 b = *reinterpret_cast<const uint4*>(&Opart[SPL + idx]);
    const u16* ap = reinterpret_cast<const u16*>(&a);
    const u16* bp = reinterpret_cast<const u16*>(&b);
    u16 res[8];
#pragma unroll
    for (int j = 0; j < 8; j++)
        res[j] = f2bu((w0 * bu2f(ap[j]) + w1 * bu2f(bp[j])) * rden);
    *reinterpret_cast<uint4*>(&out[idx]) = *reinterpret_cast<const uint4*>(res);
}

// ---------------- f32 -> output dtype (per flag) ----------------
__global__ __launch_bounds__(256) void store_out_kernel(const float* __restrict__ a,
                                                        const float* __restrict__ b,
                                                        void* __restrict__ out,
                                                        const int* __restrict__ flag) {
    bool isbf = (*flag != 0);
    size_t i = (size_t)blockIdx.x * 256 + threadIdx.x;
    const size_t MM = (size_t)S * HID;
    float v = (i < MM) ? a[i] : b[i - MM];
    if (isbf)
        ((bf16*)out)[i] = __float2bfloat16(v);
    else
        ((float*)out)[i] = v;
}

extern "C" void kernel_launch(void* const* d_in, const int* in_sizes, int n_in,
                              void* d_out, int out_size, void* d_ws, size_t ws_size,
                              hipStream_t stream) {
    const void* x[2] = {d_in[0], d_in[1]};
    const void* w_ln[2] = {d_in[5], d_in[14]};
    const void* w_q[2] = {d_in[6], d_in[15]};
    const void* w_k[2] = {d_in[7], d_in[16]};
    const void* w_v[2] = {d_in[8], d_in[17]};
    const void* w_o[2] = {d_in[9], d_in[18]};
    const void* w_pln[2] = {d_in[10], d_in[19]};
    const void* w_g[2] = {d_in[11], d_in[20]};
    const void* w_u[2] = {d_in[12], d_in[21]};
    const void* w_d[2] = {d_in[13], d_in[22]};

    char* base = (char*)d_ws;
    int* flag = (int*)base;
    u16* p = (u16*)(base + 256);
    const size_t E_QKV = (size_t)S * 3072;
    const size_t E_SH = (size_t)S * HID;
    const size_t E_VT = (size_t)NH * HD * S;  // == E_SH

    u16* qkv[2] = {p, p + E_QKV};            p += 2 * E_QKV;
    u16* qr = p;                             p += 2 * E_SH;  // [expert]
    u16* kr = p;                             p += 2 * E_SH;  // adjacent to qr
    u16* h_bf = p;                           p += 2 * E_SH;
    u16* attnbuf = p;                        p += 2 * E_SH;
    u16* vtg = p;                            p += 2 * E_VT;
    // Overlays (all dead by the time of reuse):
    //   gated (S*INTER = 8.39M u16) overlays qr+kr (4*E_SH) after causal attn;
    //   Opart (2 splits x 2S x HID = 8.39M u16) overlays qr+kr after down GEMMs;
    //   mixed (2S*HID = 4.19M u16) overlays h_bf after the MLP loop.
    u16* gated = qr;
    u16* Opart = qr;
    u16* mixed = h_bf;
    u16* wqkvT = p;                          p += 2 * (size_t)3072 * 1024;
    u16* woT[2] = {p, p + (size_t)1024 * 1024};  p += 2 * (size_t)1024 * 1024;
    u16* wgT = p;                            p += (size_t)INTER * 1024;
    u16* wuT = p;                            p += (size_t)INTER * 1024;
    u16* wdT = p;                            p += (size_t)1024 * INTER;
    float* fbase = (float*)(((size_t)p + 255) & ~(size_t)255);
    float* outX[2] = {fbase, fbase + E_SH};
    float2* mlbuf = (float2*)(fbase + 2 * E_SH);  // 2 splits x 2S x NH = 512 KB

    probe_kernel<<<1, 256, 0, stream>>>((const unsigned short*)d_in[0], flag);

    // ---- upfront transposes: qkv + wo weights for both experts, one z=8 dispatch ----
    {
        TransN tn = {};
        for (int e = 0; e < 2; e++) {
            u16* wt = wqkvT + (size_t)e * 3072 * 1024;
            tn.W[4 * e + 0] = w_q[e];  tn.T[4 * e + 0] = wt;
            tn.W[4 * e + 1] = w_k[e];  tn.T[4 * e + 1] = wt + (size_t)1024 * 1024;
            tn.W[4 * e + 2] = w_v[e];  tn.T[4 * e + 2] = wt + (size_t)2048 * 1024;
            tn.W[4 * e + 3] = w_o[e];  tn.T[4 * e + 3] = woT[e];
        }
        transpose_wN<<<dim3(32, 32, 8), 256, 0, stream>>>(tn, flag, 1024, 1024);
    }

    // ---- fused attention path (both experts per dispatch) ----
    {
        RmsDual rd = {{x[0], x[1]}, {w_ln[0], w_ln[1]}, {h_bf, h_bf + E_SH}};
        rmsnorm_kernel<<<dim3(S, 2), 256, 0, stream>>>(rd, flag, 1);
    }
    {
        GemmDual g = {{h_bf, h_bf + E_SH},
                      {wqkvT, wqkvT + (size_t)3072 * 1024},
                      {nullptr, nullptr},
                      {qkv[0], qkv[1]},
                      {nullptr, nullptr}};
        gemm_mfma<128, 128, 2, 2, 0><<<dim3(3072 / 128, S / 128, 2), 256, 0, stream>>>(
            g, flag, S, 3072, 1024);
    }
    rope_kernel<<<dim3(S * NH, 1, 2), 64, 0, stream>>>(qkv[0], qkv[1], qr, kr);
    transpose_v<<<dim3(S / 32, 1024 / 32, 2), 256, 0, stream>>>(qkv[0] + 2048, qkv[1] + 2048, 3072, vtg);
    attn_mfma_kernel<true><<<dim3(S / 64, NH, 2), 256, 0, stream>>>(
        qr, qr + E_SH, HID, kr, kr + E_SH, HID, vtg, vtg + E_VT, attnbuf, S);
    {
        GemmDual g = {{attnbuf, attnbuf + E_SH},
                      {woT[0], woT[1]},
                      {outX[0], outX[1]},
                      {nullptr, nullptr},
                      {x[0], x[1]}};
        gemm_mfma<64, 64, 2, 2, 1><<<dim3(1024 / 64, S / 64, 2), 256, 0, stream>>>(
            g, flag, S, 1024, 1024);
    }
    {
        RmsDual rd = {{outX[0], outX[1]}, {w_pln[0], w_pln[1]}, {h_bf, h_bf + E_SH}};
        rmsnorm_kernel<<<dim3(S, 2), 256, 0, stream>>>(rd, flag, 0);
    }

    // ---- MLP per expert (weight buffers reused; gated overlays dead qr/kr) ----
    for (int e = 0; e < 2; e++) {
        {
            TransN tg = {};
            tg.W[0] = w_g[e];  tg.T[0] = wgT;
            tg.W[1] = w_u[e];  tg.T[1] = wuT;
            transpose_wN<<<dim3(INTER / 32, 1024 / 32, 2), 256, 0, stream>>>(tg, flag, 1024, INTER);
        }
        gemm_gated_mfma<128, 64, 2, 2><<<dim3(INTER / 64, S / 128), 256, 0, stream>>>(
            h_bf + e * E_SH, wgT, wuT, gated, S, INTER, 1024);
        {
            TransN td = {};
            td.W[0] = w_d[e];  td.T[0] = wdT;
            transpose_wN<<<dim3(1024 / 32, INTER / 32, 1), 256, 0, stream>>>(td, flag, INTER, 1024);
        }
        GemmDual g = {{gated, gated}, {wdT, wdT}, {outX[e], outX[e]}, {nullptr, nullptr}, {nullptr, nullptr}};
        gemm_mfma<64, 64, 2, 2, 2><<<dim3(1024 / 64, S / 64, 1), 256, 0, stream>>>(
            g, flag, S, 1024, INTER);
    }

    // ---- mixed attention (key-split over the 2 experts) + combine + output projections ----
    attn_mixed_split<<<dim3(2 * S / 64, NH, 2), 256, 0, stream>>>(
        qkv[0], qkv[1], 3072, qkv[0] + 1024, qkv[1] + 1024, 3072,
        vtg, vtg + E_VT, Opart, mlbuf);
    attn_combine<<<(2 * E_SH) / (256 * 8), 256, 0, stream>>>(Opart, mlbuf, mixed);
    {
        GemmDual g = {{mixed, mixed + E_SH},
                      {woT[0], woT[1]},
                      {outX[0], outX[1]},
                      {nullptr, nullptr},
                      {nullptr, nullptr}};
        gemm_mfma<64, 64, 2, 2, 2><<<dim3(1024 / 64, S / 64, 2), 256, 0, stream>>>(
            g, flag, S, 1024, 1024);
    }

    store_out_kernel<<<(2 * E_SH) / 256, 256, 0, stream>>>(outX[0], outX[1], d_out, flag);
}

// Round 9
// 745.210 us; speedup vs baseline: 1.9007x; 1.0532x over previous
//
#include <hip/hip_runtime.h>
#include <hip/hip_bf16.h>
#include <math.h>

#define S 2048
#define HID 1024
#define NH 8
#define HD 128
#define INTER 4096
#define EPSV 1e-6f
#define THETA 10000.0f

typedef __hip_bfloat16 bf16;
typedef unsigned short u16;
typedef __attribute__((ext_vector_type(8))) short bf16x8;  // 8 bf16 = 4 VGPRs
typedef __attribute__((ext_vector_type(4))) float f32x4;

__device__ inline float bu2f(u16 u) {
    unsigned int x = ((unsigned int)u) << 16;
    return __uint_as_float(x);
}
__device__ inline u16 f2bu(float f) {
    bf16 h = __float2bfloat16(f);
    return *reinterpret_cast<u16*>(&h);
}
// Dual-dtype input load (raw harness inputs): isbf ? bf16 : f32
__device__ inline float ldin(const void* p, size_t i, bool isbf) {
    return isbf ? bu2f(((const u16*)p)[i]) : ((const float*)p)[i];
}
__device__ inline float gelu_tanh(float x) {
    float x3 = x * x * x;
    return 0.5f * x * (1.f + tanhf(0.7978845608028654f * (x + 0.044715f * x3)));
}
// Direct global->LDS 16B/lane async copy. LDS dest must be wave-uniform;
// lane i's 16B lands at ldsbase + i*16. Global source IS per-lane.
__device__ inline void gload16(const u16* g, u16* l) {
    __builtin_amdgcn_global_load_lds(
        (const __attribute__((address_space(1))) void*)g,
        (__attribute__((address_space(3))) void*)l, 16, 0, 0);
}

// ---------------- dtype probe (round-1 notes) ----------------
__global__ __launch_bounds__(256) void probe_kernel(const unsigned short* __restrict__ x,
                                                    int* __restrict__ flag) {
    __shared__ int red[256];
    int tid = threadIdx.x;
    int cnt = 0;
    for (int i = tid; i < 2048; i += 256) {
        unsigned short u = x[2 * i];
        int e = (u >> 7) & 0xFF;
        cnt += (e >= 110 && e <= 135) ? 1 : 0;
    }
    red[tid] = cnt;
    __syncthreads();
    for (int off = 128; off > 0; off >>= 1) {
        if (tid < off) red[tid] += red[tid + off];
        __syncthreads();
    }
    if (tid == 0) *flag = (red[0] > 1024) ? 1 : 0;
}

// ---------------- weight transpose+convert, z-batched: W (KxN) -> WT (NxK, bf16) ----------------
struct TransN {
    const void* W[8];
    u16* T[8];
};
__global__ __launch_bounds__(256) void transpose_wN(TransN tn, const int* __restrict__ flag,
                                                    int K, int N) {
    bool isbf = (*flag != 0);
    const void* W = tn.W[blockIdx.z];
    u16* WT = tn.T[blockIdx.z];
    __shared__ float t[32][33];
    int n0 = blockIdx.x * 32, k0 = blockIdx.y * 32;
    int c = threadIdx.x & 31, r = threadIdx.x >> 5;
#pragma unroll
    for (int p = 0; p < 4; p++)
        t[r + 8 * p][c] = ldin(W, (size_t)(k0 + r + 8 * p) * N + n0 + c, isbf);
    __syncthreads();
#pragma unroll
    for (int p = 0; p < 4; p++) {
        int row = r + 8 * p;
        WT[(size_t)(n0 + row) * K + k0 + c] = f2bu(t[c][row]);
    }
}

// ---------------- V transpose (dual-expert via z): V[key][dh] -> VT[dh][key] ----------------
__global__ __launch_bounds__(256) void transpose_v(const u16* __restrict__ V0,
                                                   const u16* __restrict__ V1, int sv,
                                                   u16* __restrict__ VT) {
    const u16* V = blockIdx.z ? V1 : V0;
    VT += (size_t)blockIdx.z * ((size_t)NH * HD * S);
    __shared__ u16 t[32][33];
    int k0 = blockIdx.x * 32;  // key tile
    int d0 = blockIdx.y * 32;  // dh tile
    int c = threadIdx.x & 31, r = threadIdx.x >> 5;
#pragma unroll
    for (int p = 0; p < 4; p++)
        t[r + 8 * p][c] = V[(size_t)(k0 + r + 8 * p) * sv + d0 + c];
    __syncthreads();
#pragma unroll
    for (int p = 0; p < 4; p++)
        VT[(size_t)(d0 + r + 8 * p) * S + k0 + c] = t[c][r + 8 * p];
}

// ---------------- RMSNorm -> bf16 (dual-expert via blockIdx.y) ----------------
struct RmsDual {
    const void* x[2];
    const void* w[2];
    u16* y[2];
};
__global__ __launch_bounds__(256) void rmsnorm_kernel(RmsDual rd,
                                                      const int* __restrict__ flag,
                                                      int dual) {
    int e = blockIdx.y;
    const void* x = rd.x[e];
    const void* w = rd.w[e];
    u16* y = rd.y[e];
    bool isbf = (*flag != 0);
    bool xbf = dual && isbf;
    int row = blockIdx.x;
    size_t base = (size_t)row * HID;
    __shared__ float red[256];
    float xv[4];
    float s = 0.f;
#pragma unroll
    for (int i = 0; i < 4; i++) {
        float v = ldin(x, base + threadIdx.x + 256 * i, xbf);
        xv[i] = v;
        s += v * v;
    }
    red[threadIdx.x] = s;
    __syncthreads();
    for (int off = 128; off > 0; off >>= 1) {
        if (threadIdx.x < off) red[threadIdx.x] += red[threadIdx.x + off];
        __syncthreads();
    }
    float scale = rsqrtf(red[0] / (float)HID + EPSV);
#pragma unroll
    for (int i = 0; i < 4; i++) {
        int c = threadIdx.x + 256 * i;
        y[base + c] = f2bu(xv[i] * scale * (1.f + ldin(w, c, isbf)));
    }
}

// ================= MFMA GEMM (v4: 2-panel K staging, effective BK=64) =================
// Two BK=32 panels staged per barrier-pair -> half the barriers, 2x MFMA per phase.
// Per-panel layout/swizzle identical to the verified v3 (chunk ^= (row>>1)&3 applied
// on the global SOURCE address and again on the frag-read address).
struct GemmDual {
    const u16* A[2];
    const u16* BT[2];
    float* Cf[2];
    u16* Cb[2];
    const void* res[2];
};
template <int BM, int BN, int WRN, int WCN, int EPI>
__global__ __launch_bounds__(256) void gemm_mfma(GemmDual g, const int* __restrict__ flag,
                                                 int M, int N, int K) {
    int eZ = blockIdx.z;
    const u16* __restrict__ A = g.A[eZ];
    const u16* __restrict__ BT = g.BT[eZ];
    float* __restrict__ Cf = g.Cf[eZ];
    u16* __restrict__ Cb = g.Cb[eZ];
    const void* __restrict__ res = g.res[eZ];
    constexpr int WM = BM / WRN, WN = BN / WCN, TI = WM / 16, TJ = WN / 16;
    __shared__ u16 As[2][BM * 32];
    __shared__ u16 Bs[2][BN * 32];
    int tid = threadIdx.x, lane = tid & 63, wv = tid >> 6;
    int wr = wv / WCN, wc = wv % WCN;
    int m = lane & 15, quad = lane >> 4;
    int m0 = blockIdx.y * BM, n0 = blockIdx.x * BN;
    f32x4 acc[TI][TJ] = {};
    for (int k0 = 0; k0 < K; k0 += 64) {
        __syncthreads();  // prev compute done reading LDS
#pragma unroll
        for (int pan = 0; pan < 2; pan++) {
            int kp = k0 + 32 * pan;
#pragma unroll
            for (int c2 = 0; c2 < BM / 64; c2++) {
                int row0 = (wv * (BM / 64) + c2) * 16;
                int row = row0 + (lane >> 2);
                int ch = lane & 3;
                gload16(&A[(size_t)(m0 + row) * K + kp + ((ch ^ ((row >> 1) & 3)) << 3)],
                        &As[pan][row0 * 32]);
            }
#pragma unroll
            for (int c2 = 0; c2 < BN / 64; c2++) {
                int row0 = (wv * (BN / 64) + c2) * 16;
                int row = row0 + (lane >> 2);
                int ch = lane & 3;
                gload16(&BT[(size_t)(n0 + row) * K + kp + ((ch ^ ((row >> 1) & 3)) << 3)],
                        &Bs[pan][row0 * 32]);
            }
        }
        __syncthreads();  // vmcnt drained by barrier -> both panels in LDS
#pragma unroll
        for (int pan = 0; pan < 2; pan++) {
            bf16x8 af[TI], bf_[TJ];
#pragma unroll
            for (int i = 0; i < TI; i++) {
                int rr = wr * WM + i * 16 + m;
                af[i] = *reinterpret_cast<const bf16x8*>(
                    &As[pan][rr * 32 + ((quad ^ ((rr >> 1) & 3)) << 3)]);
            }
#pragma unroll
            for (int j = 0; j < TJ; j++) {
                int rr = wc * WN + j * 16 + m;
                bf_[j] = *reinterpret_cast<const bf16x8*>(
                    &Bs[pan][rr * 32 + ((quad ^ ((rr >> 1) & 3)) << 3)]);
            }
#pragma unroll
            for (int i = 0; i < TI; i++)
#pragma unroll
                for (int j = 0; j < TJ; j++)
                    acc[i][j] = __builtin_amdgcn_mfma_f32_16x16x32_bf16(af[i], bf_[j], acc[i][j], 0, 0, 0);
        }
    }
    bool isbf = (EPI == 1) ? (*flag != 0) : false;
#pragma unroll
    for (int i = 0; i < TI; i++) {
#pragma unroll
        for (int j = 0; j < TJ; j++) {
#pragma unroll
            for (int r = 0; r < 4; r++) {
                int row = m0 + wr * WM + i * 16 + quad * 4 + r;
                int col = n0 + wc * WN + j * 16 + m;
                size_t idx = (size_t)row * N + col;
                float v = acc[i][j][r];
                if (EPI == 0) Cb[idx] = f2bu(v);
                else if (EPI == 1) Cf[idx] = v + ldin(res, idx, isbf);
                else Cf[idx] = Cf[idx] + v;
            }
        }
    }
}

// ------------- Fused gated MLP MFMA (2-panel): C(bf16) = gelu(A@Wg) * (A@Wu) -------------
template <int BM, int BN, int WRN, int WCN>
__global__ __launch_bounds__(256) void gemm_gated_mfma(const u16* __restrict__ A,
                                                       const u16* __restrict__ BgT,
                                                       const u16* __restrict__ BuT,
                                                       u16* __restrict__ C,
                                                       int M, int N, int K) {
    constexpr int WM = BM / WRN, WN = BN / WCN, TI = WM / 16, TJ = WN / 16;
    __shared__ u16 As[2][BM * 32];
    __shared__ u16 Bgs[2][BN * 32];
    __shared__ u16 Bus[2][BN * 32];
    int tid = threadIdx.x, lane = tid & 63, wv = tid >> 6;
    int wr = wv / WCN, wc = wv % WCN;
    int m = lane & 15, quad = lane >> 4;
    int m0 = blockIdx.y * BM, n0 = blockIdx.x * BN;
    f32x4 accg[TI][TJ] = {};
    f32x4 accu[TI][TJ] = {};
    for (int k0 = 0; k0 < K; k0 += 64) {
        __syncthreads();
#pragma unroll
        for (int pan = 0; pan < 2; pan++) {
            int kp = k0 + 32 * pan;
#pragma unroll
            for (int c2 = 0; c2 < BM / 64; c2++) {
                int row0 = (wv * (BM / 64) + c2) * 16;
                int row = row0 + (lane >> 2);
                int ch = lane & 3;
                gload16(&A[(size_t)(m0 + row) * K + kp + ((ch ^ ((row >> 1) & 3)) << 3)],
                        &As[pan][row0 * 32]);
            }
#pragma unroll
            for (int c2 = 0; c2 < BN / 64; c2++) {
                int row0 = (wv * (BN / 64) + c2) * 16;
                int row = row0 + (lane >> 2);
                int ch = lane & 3;
                gload16(&BgT[(size_t)(n0 + row) * K + kp + ((ch ^ ((row >> 1) & 3)) << 3)],
                        &Bgs[pan][row0 * 32]);
                gload16(&BuT[(size_t)(n0 + row) * K + kp + ((ch ^ ((row >> 1) & 3)) << 3)],
                        &Bus[pan][row0 * 32]);
            }
        }
        __syncthreads();
#pragma unroll
        for (int pan = 0; pan < 2; pan++) {
            bf16x8 af[TI], bg[TJ], bu[TJ];
#pragma unroll
            for (int i = 0; i < TI; i++) {
                int rr = wr * WM + i * 16 + m;
                af[i] = *reinterpret_cast<const bf16x8*>(
                    &As[pan][rr * 32 + ((quad ^ ((rr >> 1) & 3)) << 3)]);
            }
#pragma unroll
            for (int j = 0; j < TJ; j++) {
                int rr = wc * WN + j * 16 + m;
                int off = rr * 32 + ((quad ^ ((rr >> 1) & 3)) << 3);
                bg[j] = *reinterpret_cast<const bf16x8*>(&Bgs[pan][off]);
                bu[j] = *reinterpret_cast<const bf16x8*>(&Bus[pan][off]);
            }
#pragma unroll
            for (int i = 0; i < TI; i++)
#pragma unroll
                for (int j = 0; j < TJ; j++) {
                    accg[i][j] = __builtin_amdgcn_mfma_f32_16x16x32_bf16(af[i], bg[j], accg[i][j], 0, 0, 0);
                    accu[i][j] = __builtin_amdgcn_mfma_f32_16x16x32_bf16(af[i], bu[j], accu[i][j], 0, 0, 0);
                }
        }
    }
#pragma unroll
    for (int i = 0; i < TI; i++)
#pragma unroll
        for (int j = 0; j < TJ; j++)
#pragma unroll
            for (int r = 0; r < 4; r++) {
                int row = m0 + wr * WM + i * 16 + quad * 4 + r;
                int col = n0 + wc * WN + j * 16 + m;
                C[(size_t)row * N + col] = f2bu(gelu_tanh(accg[i][j][r]) * accu[i][j][r]);
            }
}

// ---------------- RoPE (dual-expert via z): qkv (stride 3072) -> qr/kr (stride 1024) ----------------
__global__ __launch_bounds__(64) void rope_kernel(const u16* __restrict__ qkv0,
                                                  const u16* __restrict__ qkv1,
                                                  u16* __restrict__ qr,
                                                  u16* __restrict__ kr) {
    const u16* qkv = blockIdx.z ? qkv1 : qkv0;
    size_t zo = (size_t)blockIdx.z * ((size_t)S * HID);
    int b = blockIdx.x;
    int t = b >> 3, h = b & 7;
    int i = threadIdx.x;  // 0..63
    size_t ib = (size_t)t * 3072 + h * HD;
    size_t ob = zo + (size_t)t * HID + h * HD;
    // powf(THETA, -x) == exp(-x * ln(THETA)); ln(10000) = 9.210340372
    float inv = __expf(-9.210340372f * (float)(2 * i) / (float)HD);
    float f = (float)t * inv;
    float c = cosf(f), s = sinf(f);
    float q1 = bu2f(qkv[ib + i]), q2 = bu2f(qkv[ib + i + 64]);
    qr[ob + i] = f2bu(q1 * c - q2 * s);
    qr[ob + i + 64] = f2bu(q2 * c + q1 * s);
    float k1 = bu2f(qkv[ib + 1024 + i]), k2 = bu2f(qkv[ib + 1024 + i + 64]);
    kr[ob + i] = f2bu(k1 * c - k2 * s);
    kr[ob + i + 64] = f2bu(k2 * c + k1 * s);
}

__device__ inline int swz64(int row, int b) {
    return row * 64 + (b ^ (((row >> 1) & 3) << 4));
}

// ============ MFMA flash attention, CAUSAL (v4: gload16 double-buffered) ============
// Grid-limited at 2 blocks/CU (512 blocks) so 64KB double-buffer LDS costs nothing.
template <bool CAUSAL>
__global__ __launch_bounds__(256, 2) void attn_mfma_kernel(
    const u16* __restrict__ qa, const u16* __restrict__ qb, int sq,
    const u16* __restrict__ ka, const u16* __restrict__ kb, int sk,
    const u16* __restrict__ vta, const u16* __restrict__ vtb,
    u16* __restrict__ Out, int nkeys) {
    __shared__ char Ks[2][16384];   // [buf][t=d/32][key][32 d] swizzled 64B rows
    __shared__ char VTs[2][16384];  // [buf][ks=key/32][d][32 keys] swizzled

    int tid = threadIdx.x;
    int lane = tid & 63, w = tid >> 6;
    int col = lane & 15, quad = lane >> 4;
    int eZ = CAUSAL ? (int)blockIdx.z : 0;
    int bx = (CAUSAL && eZ) ? ((int)gridDim.x - 1 - (int)blockIdx.x) : (int)blockIdx.x;
    int q0 = bx * 64;
    int h = blockIdx.y;
    const float scale = 0.08838834764831845f;  // 1/sqrt(128)

    int q0r = CAUSAL ? q0 : (q0 & (S - 1));
    const u16* qsel = CAUSAL ? (eZ ? qb : qa) : ((q0 < S) ? qa : qb);
    const u16* qp = qsel + (size_t)q0r * sq;
    bf16x8 aq[4];
#pragma unroll
    for (int t = 0; t < 4; t++)
        aq[t] = *reinterpret_cast<const bf16x8*>(
            qp + (size_t)(16 * w + col) * sq + h * HD + 32 * t + quad * 8);

    const u16* kplo = (CAUSAL && eZ) ? kb : ka;
    const u16* vplo = (CAUSAL && eZ) ? vtb : vta;

    f32x4 o[8] = {};           // O^T: o[nt][r] = O[q][d = 16nt + 4quad + r]
    float m_ = -1e30f, l_ = 0.f;

    int sA = col + 16 * (2 * (quad & 1));
    int sB = sA + 16;
    bool hi = (quad >> 1) != 0;

    int ntiles = CAUSAL ? (q0 >> 6) + 1 : (nkeys >> 6);

    auto stage = [&](int buf, int tt) {
        int j0r = (tt * 64) & (S - 1);
        bool eb = (!CAUSAL) && (tt >= (S >> 6));
        const u16* kp = eb ? kb : kplo;
        const u16* vp = eb ? vtb : vplo;
        char* kd = &Ks[buf][(tid >> 6) * 1024];
        char* vd = &VTs[buf][(tid >> 6) * 1024];
#pragma unroll
        for (int i = 0; i < 4; i++) {
            int l = 256 * i + tid;
            int key = (l >> 2) & 63;
            int c = (l >> 8) * 4 + ((l & 3) ^ ((key >> 1) & 3));
            gload16(kp + (size_t)(j0r + key) * sk + h * HD + c * 8, (u16*)(kd + i * 4096));
        }
#pragma unroll
        for (int i = 0; i < 4; i++) {
            int l = 256 * i + tid;
            int d = (l >> 2) & 127;
            int c = (l >> 9) * 4 + ((l & 3) ^ ((d >> 1) & 3));
            gload16(vp + (size_t)(h * HD + d) * S + j0r + c * 8, (u16*)(vd + i * 4096));
        }
    };

    stage(0, 0);
    __syncthreads();
    int cur = 0;

    for (int tt = 0; tt < ntiles; tt++) {
        if (tt + 1 < ntiles) stage(cur ^ 1, tt + 1);
        const char* Kb = Ks[cur];
        const char* Vb = VTs[cur];

        f32x4 sc[4] = {};
        __builtin_amdgcn_s_setprio(1);
#pragma unroll
        for (int t = 0; t < 4; t++) {
#pragma unroll
            for (int ct = 0; ct < 4; ct++) {
                bf16x8 kf = *reinterpret_cast<const bf16x8*>(
                    Kb + t * 4096 + swz64(16 * ct + col, quad * 16));
                sc[ct] = __builtin_amdgcn_mfma_f32_16x16x32_bf16(kf, aq[t], sc[ct], 0, 0, 0);
            }
        }
        __builtin_amdgcn_s_setprio(0);
        bool diag = CAUSAL && (tt == ntiles - 1);
#pragma unroll
        for (int ct = 0; ct < 4; ct++) {
#pragma unroll
            for (int r = 0; r < 4; r++) {
                float v = sc[ct][r] * scale;
                if (diag && (16 * ct + 4 * quad + r > 16 * w + col)) v = -1e30f;
                sc[ct][r] = v;
            }
        }

        float mx0 = fmaxf(fmaxf(sc[0][0], sc[0][1]), fmaxf(sc[0][2], sc[0][3]));
        float mx1 = fmaxf(fmaxf(sc[1][0], sc[1][1]), fmaxf(sc[1][2], sc[1][3]));
        float mx2 = fmaxf(fmaxf(sc[2][0], sc[2][1]), fmaxf(sc[2][2], sc[2][3]));
        float mx3 = fmaxf(fmaxf(sc[3][0], sc[3][1]), fmaxf(sc[3][2], sc[3][3]));
        float rmax = fmaxf(fmaxf(mx0, mx1), fmaxf(mx2, mx3));
        rmax = fmaxf(rmax, __shfl_xor(rmax, 16));
        rmax = fmaxf(rmax, __shfl_xor(rmax, 32));
        float mn = fmaxf(m_, rmax);
        float al = __expf(m_ - mn);
#pragma unroll
        for (int ct = 0; ct < 4; ct++)
#pragma unroll
            for (int r = 0; r < 4; r++) sc[ct][r] = __expf(sc[ct][r] - mn);
        float s0 = (sc[0][0] + sc[0][1]) + (sc[0][2] + sc[0][3]);
        float s1 = (sc[1][0] + sc[1][1]) + (sc[1][2] + sc[1][3]);
        float s2 = (sc[2][0] + sc[2][1]) + (sc[2][2] + sc[2][3]);
        float s3 = (sc[3][0] + sc[3][1]) + (sc[3][2] + sc[3][3]);
        float rs = (s0 + s1) + (s2 + s3);
        rs += __shfl_xor(rs, 16);
        rs += __shfl_xor(rs, 32);
        l_ = l_ * al + rs;
        m_ = mn;

        unsigned int pu[4][2];
#pragma unroll
        for (int ct = 0; ct < 4; ct++) {
            pu[ct][0] = (unsigned int)f2bu(sc[ct][0]) | ((unsigned int)f2bu(sc[ct][1]) << 16);
            pu[ct][1] = (unsigned int)f2bu(sc[ct][2]) | ((unsigned int)f2bu(sc[ct][3]) << 16);
        }

#pragma unroll
        for (int nt = 0; nt < 8; nt++)
#pragma unroll
            for (int r = 0; r < 4; r++) o[nt][r] *= al;

#pragma unroll
        for (int ks = 0; ks < 2; ks++) {
            unsigned int a0 = __shfl(pu[2 * ks][0], sA);
            unsigned int a1 = __shfl(pu[2 * ks][1], sA);
            unsigned int c0 = __shfl(pu[2 * ks + 1][0], sA);
            unsigned int c1 = __shfl(pu[2 * ks + 1][1], sA);
            unsigned int b0 = __shfl(pu[2 * ks][0], sB);
            unsigned int b1 = __shfl(pu[2 * ks][1], sB);
            unsigned int g0 = __shfl(pu[2 * ks + 1][0], sB);
            unsigned int g1 = __shfl(pu[2 * ks + 1][1], sB);
            union {
                unsigned int u[4];
                bf16x8 v;
            } pb;
            pb.u[0] = hi ? c0 : a0;
            pb.u[1] = hi ? c1 : a1;
            pb.u[2] = hi ? g0 : b0;
            pb.u[3] = hi ? g1 : b1;
            __builtin_amdgcn_s_setprio(1);
#pragma unroll
            for (int nt = 0; nt < 8; nt++) {
                bf16x8 vf = *reinterpret_cast<const bf16x8*>(
                    Vb + ks * 8192 + swz64(16 * nt + col, quad * 16));
                o[nt] = __builtin_amdgcn_mfma_f32_16x16x32_bf16(vf, pb.v, o[nt], 0, 0, 0);
            }
            __builtin_amdgcn_s_setprio(0);
        }

        __syncthreads();
        cur ^= 1;
    }

    u16* outp = Out + (CAUSAL ? (size_t)eZ * ((size_t)S * HID) : (size_t)0);
    float inv = 1.f / l_;
    size_t rowoff = (size_t)(q0 + 16 * w + col) * HID + (size_t)h * HD + 4 * quad;
#pragma unroll
    for (int nt = 0; nt < 8; nt++) {
        ushort4 st;
        st.x = f2bu(o[nt][0] * inv);
        st.y = f2bu(o[nt][1] * inv);
        st.z = f2bu(o[nt][2] * inv);
        st.w = f2bu(o[nt][3] * inv);
        *reinterpret_cast<ushort4*>(&outp[rowoff + 16 * nt]) = st;
    }
}

// ============ Mixed attention, key-split (flash-decoding, 2 splits) ============
// blockIdx.z = split = expert whose 2048 keys this block processes. Single-buffer
// 32KB LDS -> 4 blocks/CU resident (16 waves) on the 1024-block grid. Writes
// UNNORMALIZED partial O (bf16, referenced to local max m) + per-row (m, l);
// attn_combine merges the two splits.
__global__ __launch_bounds__(256, 4) void attn_mixed_split(
    const u16* __restrict__ qa, const u16* __restrict__ qb, int sq,
    const u16* __restrict__ ka, const u16* __restrict__ kb, int sk,
    const u16* __restrict__ vta, const u16* __restrict__ vtb,
    u16* __restrict__ Opart, float2* __restrict__ ml) {
    __shared__ char Ks[16384];
    __shared__ char VTs[16384];

    int tid = threadIdx.x;
    int lane = tid & 63, w = tid >> 6;
    int col = lane & 15, quad = lane >> 4;
    int q0 = blockIdx.x * 64;  // 0..4032 over 2S queries
    int h = blockIdx.y;
    int z = blockIdx.z;  // split/expert
    const float scale = 0.08838834764831845f;

    const u16* qp = ((q0 < S) ? qa : qb) + (size_t)(q0 & (S - 1)) * sq;
    bf16x8 aq[4];
#pragma unroll
    for (int t = 0; t < 4; t++)
        aq[t] = *reinterpret_cast<const bf16x8*>(
            qp + (size_t)(16 * w + col) * sq + h * HD + 32 * t + quad * 8);

    const u16* kp = z ? kb : ka;
    const u16* vp = z ? vtb : vta;

    f32x4 o[8] = {};
    float m_ = -1e30f, l_ = 0.f;

    int sA = col + 16 * (2 * (quad & 1));
    int sB = sA + 16;
    bool hi = (quad >> 1) != 0;

    for (int tt = 0; tt < (S >> 6); tt++) {
        int j0r = tt * 64;
        __syncthreads();  // prev compute done reading LDS
        {
            char* kd = &Ks[(tid >> 6) * 1024];
            char* vd = &VTs[(tid >> 6) * 1024];
#pragma unroll
            for (int i = 0; i < 4; i++) {
                int l = 256 * i + tid;
                int key = (l >> 2) & 63;
                int c = (l >> 8) * 4 + ((l & 3) ^ ((key >> 1) & 3));
                gload16(kp + (size_t)(j0r + key) * sk + h * HD + c * 8, (u16*)(kd + i * 4096));
            }
#pragma unroll
            for (int i = 0; i < 4; i++) {
                int l = 256 * i + tid;
                int d = (l >> 2) & 127;
                int c = (l >> 9) * 4 + ((l & 3) ^ ((d >> 1) & 3));
                gload16(vp + (size_t)(h * HD + d) * S + j0r + c * 8, (u16*)(vd + i * 4096));
            }
        }
        __syncthreads();  // vmcnt drained -> tile in LDS

        f32x4 sc[4] = {};
        __builtin_amdgcn_s_setprio(1);
#pragma unroll
        for (int t = 0; t < 4; t++) {
#pragma unroll
            for (int ct = 0; ct < 4; ct++) {
                bf16x8 kf = *reinterpret_cast<const bf16x8*>(
                    Ks + t * 4096 + swz64(16 * ct + col, quad * 16));
                sc[ct] = __builtin_amdgcn_mfma_f32_16x16x32_bf16(kf, aq[t], sc[ct], 0, 0, 0);
            }
        }
        __builtin_amdgcn_s_setprio(0);
#pragma unroll
        for (int ct = 0; ct < 4; ct++)
#pragma unroll
            for (int r = 0; r < 4; r++) sc[ct][r] *= scale;

        float mx0 = fmaxf(fmaxf(sc[0][0], sc[0][1]), fmaxf(sc[0][2], sc[0][3]));
        float mx1 = fmaxf(fmaxf(sc[1][0], sc[1][1]), fmaxf(sc[1][2], sc[1][3]));
        float mx2 = fmaxf(fmaxf(sc[2][0], sc[2][1]), fmaxf(sc[2][2], sc[2][3]));
        float mx3 = fmaxf(fmaxf(sc[3][0], sc[3][1]), fmaxf(sc[3][2], sc[3][3]));
        float rmax = fmaxf(fmaxf(mx0, mx1), fmaxf(mx2, mx3));
        rmax = fmaxf(rmax, __shfl_xor(rmax, 16));
        rmax = fmaxf(rmax, __shfl_xor(rmax, 32));
        float mn = fmaxf(m_, rmax);
        float al = __expf(m_ - mn);
#pragma unroll
        for (int ct = 0; ct < 4; ct++)
#pragma unroll
            for (int r = 0; r < 4; r++) sc[ct][r] = __expf(sc[ct][r] - mn);
        float s0 = (sc[0][0] + sc[0][1]) + (sc[0][2] + sc[0][3]);
        float s1 = (sc[1][0] + sc[1][1]) + (sc[1][2] + sc[1][3]);
        float s2 = (sc[2][0] + sc[2][1]) + (sc[2][2] + sc[2][3]);
        float s3 = (sc[3][0] + sc[3][1]) + (sc[3][2] + sc[3][3]);
        float rs = (s0 + s1) + (s2 + s3);
        rs += __shfl_xor(rs, 16);
        rs += __shfl_xor(rs, 32);
        l_ = l_ * al + rs;
        m_ = mn;

        unsigned int pu[4][2];
#pragma unroll
        for (int ct = 0; ct < 4; ct++) {
            pu[ct][0] = (unsigned int)f2bu(sc[ct][0]) | ((unsigned int)f2bu(sc[ct][1]) << 16);
            pu[ct][1] = (unsigned int)f2bu(sc[ct][2]) | ((unsigned int)f2bu(sc[ct][3]) << 16);
        }

#pragma unroll
        for (int nt = 0; nt < 8; nt++)
#pragma unroll
            for (int r = 0; r < 4; r++) o[nt][r] *= al;

#pragma unroll
        for (int ks = 0; ks < 2; ks++) {
            unsigned int a0 = __shfl(pu[2 * ks][0], sA);
            unsigned int a1 = __shfl(pu[2 * ks][1], sA);
            unsigned int c0 = __shfl(pu[2 * ks + 1][0], sA);
            unsigned int c1 = __shfl(pu[2 * ks + 1][1], sA);
            unsigned int b0 = __shfl(pu[2 * ks][0], sB);
            unsigned int b1 = __shfl(pu[2 * ks][1], sB);
            unsigned int g0 = __shfl(pu[2 * ks + 1][0], sB);
            unsigned int g1 = __shfl(pu[2 * ks + 1][1], sB);
            union {
                unsigned int u[4];
                bf16x8 v;
            } pb;
            pb.u[0] = hi ? c0 : a0;
            pb.u[1] = hi ? c1 : a1;
            pb.u[2] = hi ? g0 : b0;
            pb.u[3] = hi ? g1 : b1;
            __builtin_amdgcn_s_setprio(1);
#pragma unroll
            for (int nt = 0; nt < 8; nt++) {
                bf16x8 vf = *reinterpret_cast<const bf16x8*>(
                    VTs + ks * 8192 + swz64(16 * nt + col, quad * 16));
                o[nt] = __builtin_amdgcn_mfma_f32_16x16x32_bf16(vf, pb.v, o[nt], 0, 0, 0);
            }
            __builtin_amdgcn_s_setprio(0);
        }
    }

    // partial epilogue: UNNORMALIZED O (bf16) + (m,l) per q-row
    const size_t SPL = (size_t)2 * S * HID;  // per-split element count
    size_t rowoff = (size_t)z * SPL + (size_t)(q0 + 16 * w + col) * HID + (size_t)h * HD + 4 * quad;
#pragma unroll
    for (int nt = 0; nt < 8; nt++) {
        ushort4 st;
        st.x = f2bu(o[nt][0]);
        st.y = f2bu(o[nt][1]);
        st.z = f2bu(o[nt][2]);
        st.w = f2bu(o[nt][3]);
        *reinterpret_cast<ushort4*>(&Opart[rowoff + 16 * nt]) = st;
    }
    if (quad == 0)
        ml[((size_t)z * 2 * S + q0 + 16 * w + col) * NH + h] = make_float2(m_, l_);
}

// ---------------- combine the 2 key-splits: out = (w0*O0 + w1*O1)/(w0*l0 + w1*l1) ----------------
__global__ __launch_bounds__(256) void attn_combine(const u16* __restrict__ Opart,
                                                    const float2* __restrict__ ml,
                                                    u16* __restrict__ out) {
    size_t idx = ((size_t)blockIdx.x * 256 + threadIdx.x) * 8;  // over 2S*HID elements
    int q = (int)(idx >> 10);
    int c0 = (int)(idx & 1023);
    int h = c0 >> 7;
    float2 ml0 = ml[(size_t)q * NH + h];
    float2 ml1 = ml[((size_t)2 * S + q) * NH + h];
    float ms = fmaxf(ml0.x, ml1.x);
    float w0 = __expf(ml0.x - ms), w1 = __expf(ml1.x - ms);
    float rden = 1.f / (w0 * ml0.y + w1 * ml1.y);
    const size_t SPL = (size_t)2 * S * HID;
    uint4 a = *reinterpret_cast<const uint4*>(&Opart[idx]);
    uint4 b = *reinterpret_cast<const uint4*>(&Opart[SPL + idx]);
    const u16* ap = reinterpret_cast<const u16*>(&a);
    const u16* bp = reinterpret_cast<const u16*>(&b);
    u16 res[8];
#pragma unroll
    for (int j = 0; j < 8; j++)
        res[j] = f2bu((w0 * bu2f(ap[j]) + w1 * bu2f(bp[j])) * rden);
    *reinterpret_cast<uint4*>(&out[idx]) = *reinterpret_cast<const uint4*>(res);
}

// ---------------- f32 -> output dtype (per flag) ----------------
__global__ __launch_bounds__(256) void store_out_kernel(const float* __restrict__ a,
                                                        const float* __restrict__ b,
                                                        void* __restrict__ out,
                                                        const int* __restrict__ flag) {
    bool isbf = (*flag != 0);
    size_t i = (size_t)blockIdx.x * 256 + threadIdx.x;
    const size_t MM = (size_t)S * HID;
    float v = (i < MM) ? a[i] : b[i - MM];
    if (isbf)
        ((bf16*)out)[i] = __float2bfloat16(v);
    else
        ((float*)out)[i] = v;
}

extern "C" void kernel_launch(void* const* d_in, const int* in_sizes, int n_in,
                              void* d_out, int out_size, void* d_ws, size_t ws_size,
                              hipStream_t stream) {
    const void* x[2] = {d_in[0], d_in[1]};
    const void* w_ln[2] = {d_in[5], d_in[14]};
    const void* w_q[2] = {d_in[6], d_in[15]};
    const void* w_k[2] = {d_in[7], d_in[16]};
    const void* w_v[2] = {d_in[8], d_in[17]};
    const void* w_o[2] = {d_in[9], d_in[18]};
    const void* w_pln[2] = {d_in[10], d_in[19]};
    const void* w_g[2] = {d_in[11], d_in[20]};
    const void* w_u[2] = {d_in[12], d_in[21]};
    const void* w_d[2] = {d_in[13], d_in[22]};

    char* base = (char*)d_ws;
    int* flag = (int*)base;
    u16* p = (u16*)(base + 256);
    const size_t E_QKV = (size_t)S * 3072;
    const size_t E_SH = (size_t)S * HID;
    const size_t E_VT = (size_t)NH * HD * S;  // == E_SH

    u16* qkv[2] = {p, p + E_QKV};            p += 2 * E_QKV;
    u16* qr = p;                             p += 2 * E_SH;  // [expert]
    u16* kr = p;                             p += 2 * E_SH;  // adjacent to qr
    u16* h_bf = p;                           p += 2 * E_SH;
    u16* attnbuf = p;                        p += 2 * E_SH;
    u16* vtg = p;                            p += 2 * E_VT;
    // Overlays (round-7 PROVEN plan — round 8's fused-MLP overlays collided and
    // were reverted): gated (S*INTER = 8.39M u16) fits qr+kr (4*E_SH = 8.39M)
    // exactly; Opart (2 x 2S*HID = 8.39M) same region after the down GEMMs;
    // mixed (2S*HID) overlays h_bf after the MLP loop.
    u16* gated = qr;
    u16* Opart = qr;
    u16* mixed = h_bf;
    u16* wqkvT = p;                          p += 2 * (size_t)3072 * 1024;
    u16* woT[2] = {p, p + (size_t)1024 * 1024};  p += 2 * (size_t)1024 * 1024;
    u16* wgT = p;                            p += (size_t)INTER * 1024;
    u16* wuT = p;                            p += (size_t)INTER * 1024;
    u16* wdT = p;                            p += (size_t)1024 * INTER;
    float* fbase = (float*)(((size_t)p + 255) & ~(size_t)255);
    float* outX[2] = {fbase, fbase + E_SH};
    float2* mlbuf = (float2*)(fbase + 2 * E_SH);  // 2 splits x 2S x NH

    probe_kernel<<<1, 256, 0, stream>>>((const unsigned short*)d_in[0], flag);

    // ---- upfront transposes: qkv + wo weights for both experts, one z=8 dispatch ----
    {
        TransN tn = {};
        for (int e = 0; e < 2; e++) {
            u16* wt = wqkvT + (size_t)e * 3072 * 1024;
            tn.W[4 * e + 0] = w_q[e];  tn.T[4 * e + 0] = wt;
            tn.W[4 * e + 1] = w_k[e];  tn.T[4 * e + 1] = wt + (size_t)1024 * 1024;
            tn.W[4 * e + 2] = w_v[e];  tn.T[4 * e + 2] = wt + (size_t)2048 * 1024;
            tn.W[4 * e + 3] = w_o[e];  tn.T[4 * e + 3] = woT[e];
        }
        transpose_wN<<<dim3(32, 32, 8), 256, 0, stream>>>(tn, flag, 1024, 1024);
    }

    // ---- fused attention path (both experts per dispatch) ----
    {
        RmsDual rd = {{x[0], x[1]}, {w_ln[0], w_ln[1]}, {h_bf, h_bf + E_SH}};
        rmsnorm_kernel<<<dim3(S, 2), 256, 0, stream>>>(rd, flag, 1);
    }
    {
        GemmDual g = {{h_bf, h_bf + E_SH},
                      {wqkvT, wqkvT + (size_t)3072 * 1024},
                      {nullptr, nullptr},
                      {qkv[0], qkv[1]},
                      {nullptr, nullptr}};
        gemm_mfma<128, 128, 2, 2, 0><<<dim3(3072 / 128, S / 128, 2), 256, 0, stream>>>(
            g, flag, S, 3072, 1024);
    }
    rope_kernel<<<dim3(S * NH, 1, 2), 64, 0, stream>>>(qkv[0], qkv[1], qr, kr);
    transpose_v<<<dim3(S / 32, 1024 / 32, 2), 256, 0, stream>>>(qkv[0] + 2048, qkv[1] + 2048, 3072, vtg);
    attn_mfma_kernel<true><<<dim3(S / 64, NH, 2), 256, 0, stream>>>(
        qr, qr + E_SH, HID, kr, kr + E_SH, HID, vtg, vtg + E_VT, attnbuf, S);
    {
        GemmDual g = {{attnbuf, attnbuf + E_SH},
                      {woT[0], woT[1]},
                      {outX[0], outX[1]},
                      {nullptr, nullptr},
                      {x[0], x[1]}};
        gemm_mfma<64, 64, 2, 2, 1><<<dim3(1024 / 64, S / 64, 2), 256, 0, stream>>>(
            g, flag, S, 1024, 1024);
    }
    {
        RmsDual rd = {{outX[0], outX[1]}, {w_pln[0], w_pln[1]}, {h_bf, h_bf + E_SH}};
        rmsnorm_kernel<<<dim3(S, 2), 256, 0, stream>>>(rd, flag, 0);
    }

    // ---- MLP per expert (round-7 proven structure; gated overlays dead qr/kr) ----
    for (int e = 0; e < 2; e++) {
        {
            TransN tg = {};
            tg.W[0] = w_g[e];  tg.T[0] = wgT;
            tg.W[1] = w_u[e];  tg.T[1] = wuT;
            transpose_wN<<<dim3(INTER / 32, 1024 / 32, 2), 256, 0, stream>>>(tg, flag, 1024, INTER);
        }
        gemm_gated_mfma<128, 64, 2, 2><<<dim3(INTER / 64, S / 128), 256, 0, stream>>>(
            h_bf + e * E_SH, wgT, wuT, gated, S, INTER, 1024);
        {
            TransN td = {};
            td.W[0] = w_d[e];  td.T[0] = wdT;
            transpose_wN<<<dim3(1024 / 32, INTER / 32, 1), 256, 0, stream>>>(td, flag, INTER, 1024);
        }
        GemmDual g = {{gated, gated}, {wdT, wdT}, {outX[e], outX[e]}, {nullptr, nullptr}, {nullptr, nullptr}};
        gemm_mfma<64, 64, 2, 2, 2><<<dim3(1024 / 64, S / 64, 1), 256, 0, stream>>>(
            g, flag, S, 1024, INTER);
    }

    // ---- mixed attention (key-split over the 2 experts) + combine + output projections ----
    attn_mixed_split<<<dim3(2 * S / 64, NH, 2), 256, 0, stream>>>(
        qkv[0], qkv[1], 3072, qkv[0] + 1024, qkv[1] + 1024, 3072,
        vtg, vtg + E_VT, Opart, mlbuf);
    attn_combine<<<(2 * E_SH) / (256 * 8), 256, 0, stream>>>(Opart, mlbuf, mixed);
    {
        GemmDual g = {{mixed, mixed + E_SH},
                      {woT[0], woT[1]},
                      {outX[0], outX[1]},
                      {nullptr, nullptr},
                      {nullptr, nullptr}};
        gemm_mfma<64, 64, 2, 2, 2><<<dim3(1024 / 64, S / 64, 2), 256, 0, stream>>>(
            g, flag, S, 1024, 1024);
    }

    store_out_kernel<<<(2 * E_SH) / 256, 256, 0, stream>>>(outX[0], outX[1], d_out, flag);
}

// Round 10
// 707.490 us; speedup vs baseline: 2.0021x; 1.0533x over previous
//
#include <hip/hip_runtime.h>
#include <hip/hip_bf16.h>
#include <math.h>

#define S 2048
#define HID 1024
#define NH 8
#define HD 128
#define INTER 4096
#define EPSV 1e-6f
#define THETA 10000.0f

typedef __hip_bfloat16 bf16;
typedef unsigned short u16;
typedef __attribute__((ext_vector_type(8))) short bf16x8;  // 8 bf16 = 4 VGPRs
typedef __attribute__((ext_vector_type(4))) float f32x4;

__device__ inline float bu2f(u16 u) {
    unsigned int x = ((unsigned int)u) << 16;
    return __uint_as_float(x);
}
__device__ inline u16 f2bu(float f) {
    bf16 h = __float2bfloat16(f);
    return *reinterpret_cast<u16*>(&h);
}
// Dual-dtype input load (raw harness inputs): isbf ? bf16 : f32
__device__ inline float ldin(const void* p, size_t i, bool isbf) {
    return isbf ? bu2f(((const u16*)p)[i]) : ((const float*)p)[i];
}
__device__ inline float gelu_tanh(float x) {
    float x3 = x * x * x;
    return 0.5f * x * (1.f + tanhf(0.7978845608028654f * (x + 0.044715f * x3)));
}
// Direct global->LDS 16B/lane async copy. LDS dest must be wave-uniform;
// lane i's 16B lands at ldsbase + i*16. Global source IS per-lane.
__device__ inline void gload16(const u16* g, u16* l) {
    __builtin_amdgcn_global_load_lds(
        (const __attribute__((address_space(1))) void*)g,
        (__attribute__((address_space(3))) void*)l, 16, 0, 0);
}

// ---------------- dtype probe (round-1 notes) ----------------
__global__ __launch_bounds__(256) void probe_kernel(const unsigned short* __restrict__ x,
                                                    int* __restrict__ flag) {
    __shared__ int red[256];
    int tid = threadIdx.x;
    int cnt = 0;
    for (int i = tid; i < 2048; i += 256) {
        unsigned short u = x[2 * i];
        int e = (u >> 7) & 0xFF;
        cnt += (e >= 110 && e <= 135) ? 1 : 0;
    }
    red[tid] = cnt;
    __syncthreads();
    for (int off = 128; off > 0; off >>= 1) {
        if (tid < off) red[tid] += red[tid + off];
        __syncthreads();
    }
    if (tid == 0) *flag = (red[0] > 1024) ? 1 : 0;
}

// ---------------- weight transpose+convert, z-batched: W (KxN) -> WT (NxK, bf16) ----------------
struct TransN {
    const void* W[8];
    u16* T[8];
};
__global__ __launch_bounds__(256) void transpose_wN(TransN tn, const int* __restrict__ flag,
                                                    int K, int N) {
    bool isbf = (*flag != 0);
    const void* W = tn.W[blockIdx.z];
    u16* WT = tn.T[blockIdx.z];
    __shared__ float t[32][33];
    int n0 = blockIdx.x * 32, k0 = blockIdx.y * 32;
    int c = threadIdx.x & 31, r = threadIdx.x >> 5;
#pragma unroll
    for (int p = 0; p < 4; p++)
        t[r + 8 * p][c] = ldin(W, (size_t)(k0 + r + 8 * p) * N + n0 + c, isbf);
    __syncthreads();
#pragma unroll
    for (int p = 0; p < 4; p++) {
        int row = r + 8 * p;
        WT[(size_t)(n0 + row) * K + k0 + c] = f2bu(t[c][row]);
    }
}

// ---------------- V transpose (dual-expert via z): V[key][dh] -> VT[dh][key] ----------------
__global__ __launch_bounds__(256) void transpose_v(const u16* __restrict__ V0,
                                                   const u16* __restrict__ V1, int sv,
                                                   u16* __restrict__ VT) {
    const u16* V = blockIdx.z ? V1 : V0;
    VT += (size_t)blockIdx.z * ((size_t)NH * HD * S);
    __shared__ u16 t[32][33];
    int k0 = blockIdx.x * 32;  // key tile
    int d0 = blockIdx.y * 32;  // dh tile
    int c = threadIdx.x & 31, r = threadIdx.x >> 5;
#pragma unroll
    for (int p = 0; p < 4; p++)
        t[r + 8 * p][c] = V[(size_t)(k0 + r + 8 * p) * sv + d0 + c];
    __syncthreads();
#pragma unroll
    for (int p = 0; p < 4; p++)
        VT[(size_t)(d0 + r + 8 * p) * S + k0 + c] = t[c][r + 8 * p];
}

// ---------------- RMSNorm -> bf16 (dual-expert via blockIdx.y) ----------------
struct RmsDual {
    const void* x[2];
    const void* w[2];
    u16* y[2];
};
__global__ __launch_bounds__(256) void rmsnorm_kernel(RmsDual rd,
                                                      const int* __restrict__ flag,
                                                      int dual) {
    int e = blockIdx.y;
    const void* x = rd.x[e];
    const void* w = rd.w[e];
    u16* y = rd.y[e];
    bool isbf = (*flag != 0);
    bool xbf = dual && isbf;
    int row = blockIdx.x;
    size_t base = (size_t)row * HID;
    __shared__ float red[256];
    float xv[4];
    float s = 0.f;
#pragma unroll
    for (int i = 0; i < 4; i++) {
        float v = ldin(x, base + threadIdx.x + 256 * i, xbf);
        xv[i] = v;
        s += v * v;
    }
    red[threadIdx.x] = s;
    __syncthreads();
    for (int off = 128; off > 0; off >>= 1) {
        if (threadIdx.x < off) red[threadIdx.x] += red[threadIdx.x + off];
        __syncthreads();
    }
    float scale = rsqrtf(red[0] / (float)HID + EPSV);
#pragma unroll
    for (int i = 0; i < 4; i++) {
        int c = threadIdx.x + 256 * i;
        y[base + c] = f2bu(xv[i] * scale * (1.f + ldin(w, c, isbf)));
    }
}

// ================= MFMA GEMM (v4: 2-panel K staging, effective BK=64) =================
// Two BK=32 panels staged per barrier-pair -> half the barriers, 2x MFMA per phase.
// Per-panel layout/swizzle identical to the verified v3 (chunk ^= (row>>1)&3 applied
// on the global SOURCE address and again on the frag-read address).
struct GemmDual {
    const u16* A[2];
    const u16* BT[2];
    float* Cf[2];
    u16* Cb[2];
    const void* res[2];
};
template <int BM, int BN, int WRN, int WCN, int EPI>
__global__ __launch_bounds__(256) void gemm_mfma(GemmDual g, const int* __restrict__ flag,
                                                 int M, int N, int K) {
    int eZ = blockIdx.z;
    const u16* __restrict__ A = g.A[eZ];
    const u16* __restrict__ BT = g.BT[eZ];
    float* __restrict__ Cf = g.Cf[eZ];
    u16* __restrict__ Cb = g.Cb[eZ];
    const void* __restrict__ res = g.res[eZ];
    constexpr int WM = BM / WRN, WN = BN / WCN, TI = WM / 16, TJ = WN / 16;
    __shared__ u16 As[2][BM * 32];
    __shared__ u16 Bs[2][BN * 32];
    int tid = threadIdx.x, lane = tid & 63, wv = tid >> 6;
    int wr = wv / WCN, wc = wv % WCN;
    int m = lane & 15, quad = lane >> 4;
    int m0 = blockIdx.y * BM, n0 = blockIdx.x * BN;
    f32x4 acc[TI][TJ] = {};
    for (int k0 = 0; k0 < K; k0 += 64) {
        __syncthreads();  // prev compute done reading LDS
#pragma unroll
        for (int pan = 0; pan < 2; pan++) {
            int kp = k0 + 32 * pan;
#pragma unroll
            for (int c2 = 0; c2 < BM / 64; c2++) {
                int row0 = (wv * (BM / 64) + c2) * 16;
                int row = row0 + (lane >> 2);
                int ch = lane & 3;
                gload16(&A[(size_t)(m0 + row) * K + kp + ((ch ^ ((row >> 1) & 3)) << 3)],
                        &As[pan][row0 * 32]);
            }
#pragma unroll
            for (int c2 = 0; c2 < BN / 64; c2++) {
                int row0 = (wv * (BN / 64) + c2) * 16;
                int row = row0 + (lane >> 2);
                int ch = lane & 3;
                gload16(&BT[(size_t)(n0 + row) * K + kp + ((ch ^ ((row >> 1) & 3)) << 3)],
                        &Bs[pan][row0 * 32]);
            }
        }
        __syncthreads();  // vmcnt drained by barrier -> both panels in LDS
#pragma unroll
        for (int pan = 0; pan < 2; pan++) {
            bf16x8 af[TI], bf_[TJ];
#pragma unroll
            for (int i = 0; i < TI; i++) {
                int rr = wr * WM + i * 16 + m;
                af[i] = *reinterpret_cast<const bf16x8*>(
                    &As[pan][rr * 32 + ((quad ^ ((rr >> 1) & 3)) << 3)]);
            }
#pragma unroll
            for (int j = 0; j < TJ; j++) {
                int rr = wc * WN + j * 16 + m;
                bf_[j] = *reinterpret_cast<const bf16x8*>(
                    &Bs[pan][rr * 32 + ((quad ^ ((rr >> 1) & 3)) << 3)]);
            }
#pragma unroll
            for (int i = 0; i < TI; i++)
#pragma unroll
                for (int j = 0; j < TJ; j++)
                    acc[i][j] = __builtin_amdgcn_mfma_f32_16x16x32_bf16(af[i], bf_[j], acc[i][j], 0, 0, 0);
        }
    }
    bool isbf = (EPI == 1) ? (*flag != 0) : false;
#pragma unroll
    for (int i = 0; i < TI; i++) {
#pragma unroll
        for (int j = 0; j < TJ; j++) {
#pragma unroll
            for (int r = 0; r < 4; r++) {
                int row = m0 + wr * WM + i * 16 + quad * 4 + r;
                int col = n0 + wc * WN + j * 16 + m;
                size_t idx = (size_t)row * N + col;
                float v = acc[i][j][r];
                if (EPI == 0) Cb[idx] = f2bu(v);
                else if (EPI == 1) Cf[idx] = v + ldin(res, idx, isbf);
                else Cf[idx] = Cf[idx] + v;
            }
        }
    }
}

// ------------- Fused gated MLP MFMA (dual-expert via z, 2-panel): C = gelu(A@Wg)*(A@Wu) -------------
struct GatedDual {
    const u16* A[2];
    const u16* Bg[2];
    const u16* Bu[2];
    u16* C[2];
};
template <int BM, int BN, int WRN, int WCN>
__global__ __launch_bounds__(256) void gemm_gated_mfma(GatedDual gd, int M, int N, int K) {
    int eZ = blockIdx.z;
    const u16* __restrict__ A = gd.A[eZ];
    const u16* __restrict__ BgT = gd.Bg[eZ];
    const u16* __restrict__ BuT = gd.Bu[eZ];
    u16* __restrict__ C = gd.C[eZ];
    constexpr int WM = BM / WRN, WN = BN / WCN, TI = WM / 16, TJ = WN / 16;
    __shared__ u16 As[2][BM * 32];
    __shared__ u16 Bgs[2][BN * 32];
    __shared__ u16 Bus[2][BN * 32];
    int tid = threadIdx.x, lane = tid & 63, wv = tid >> 6;
    int wr = wv / WCN, wc = wv % WCN;
    int m = lane & 15, quad = lane >> 4;
    int m0 = blockIdx.y * BM, n0 = blockIdx.x * BN;
    f32x4 accg[TI][TJ] = {};
    f32x4 accu[TI][TJ] = {};
    for (int k0 = 0; k0 < K; k0 += 64) {
        __syncthreads();
#pragma unroll
        for (int pan = 0; pan < 2; pan++) {
            int kp = k0 + 32 * pan;
#pragma unroll
            for (int c2 = 0; c2 < BM / 64; c2++) {
                int row0 = (wv * (BM / 64) + c2) * 16;
                int row = row0 + (lane >> 2);
                int ch = lane & 3;
                gload16(&A[(size_t)(m0 + row) * K + kp + ((ch ^ ((row >> 1) & 3)) << 3)],
                        &As[pan][row0 * 32]);
            }
#pragma unroll
            for (int c2 = 0; c2 < BN / 64; c2++) {
                int row0 = (wv * (BN / 64) + c2) * 16;
                int row = row0 + (lane >> 2);
                int ch = lane & 3;
                gload16(&BgT[(size_t)(n0 + row) * K + kp + ((ch ^ ((row >> 1) & 3)) << 3)],
                        &Bgs[pan][row0 * 32]);
                gload16(&BuT[(size_t)(n0 + row) * K + kp + ((ch ^ ((row >> 1) & 3)) << 3)],
                        &Bus[pan][row0 * 32]);
            }
        }
        __syncthreads();
#pragma unroll
        for (int pan = 0; pan < 2; pan++) {
            bf16x8 af[TI], bg[TJ], bu[TJ];
#pragma unroll
            for (int i = 0; i < TI; i++) {
                int rr = wr * WM + i * 16 + m;
                af[i] = *reinterpret_cast<const bf16x8*>(
                    &As[pan][rr * 32 + ((quad ^ ((rr >> 1) & 3)) << 3)]);
            }
#pragma unroll
            for (int j = 0; j < TJ; j++) {
                int rr = wc * WN + j * 16 + m;
                int off = rr * 32 + ((quad ^ ((rr >> 1) & 3)) << 3);
                bg[j] = *reinterpret_cast<const bf16x8*>(&Bgs[pan][off]);
                bu[j] = *reinterpret_cast<const bf16x8*>(&Bus[pan][off]);
            }
#pragma unroll
            for (int i = 0; i < TI; i++)
#pragma unroll
                for (int j = 0; j < TJ; j++) {
                    accg[i][j] = __builtin_amdgcn_mfma_f32_16x16x32_bf16(af[i], bg[j], accg[i][j], 0, 0, 0);
                    accu[i][j] = __builtin_amdgcn_mfma_f32_16x16x32_bf16(af[i], bu[j], accu[i][j], 0, 0, 0);
                }
        }
    }
#pragma unroll
    for (int i = 0; i < TI; i++)
#pragma unroll
        for (int j = 0; j < TJ; j++)
#pragma unroll
            for (int r = 0; r < 4; r++) {
                int row = m0 + wr * WM + i * 16 + quad * 4 + r;
                int col = n0 + wc * WN + j * 16 + m;
                C[(size_t)row * N + col] = f2bu(gelu_tanh(accg[i][j][r]) * accu[i][j][r]);
            }
}

// ---------------- RoPE (dual-expert via z): qkv (stride 3072) -> qr/kr (stride 1024) ----------------
__global__ __launch_bounds__(64) void rope_kernel(const u16* __restrict__ qkv0,
                                                  const u16* __restrict__ qkv1,
                                                  u16* __restrict__ qr,
                                                  u16* __restrict__ kr) {
    const u16* qkv = blockIdx.z ? qkv1 : qkv0;
    size_t zo = (size_t)blockIdx.z * ((size_t)S * HID);
    int b = blockIdx.x;
    int t = b >> 3, h = b & 7;
    int i = threadIdx.x;  // 0..63
    size_t ib = (size_t)t * 3072 + h * HD;
    size_t ob = zo + (size_t)t * HID + h * HD;
    // powf(THETA, -x) == exp(-x * ln(THETA)); ln(10000) = 9.210340372
    float inv = __expf(-9.210340372f * (float)(2 * i) / (float)HD);
    float f = (float)t * inv;
    float c = cosf(f), s = sinf(f);
    float q1 = bu2f(qkv[ib + i]), q2 = bu2f(qkv[ib + i + 64]);
    qr[ob + i] = f2bu(q1 * c - q2 * s);
    qr[ob + i + 64] = f2bu(q2 * c + q1 * s);
    float k1 = bu2f(qkv[ib + 1024 + i]), k2 = bu2f(qkv[ib + 1024 + i + 64]);
    kr[ob + i] = f2bu(k1 * c - k2 * s);
    kr[ob + i + 64] = f2bu(k2 * c + k1 * s);
}

__device__ inline int swz64(int row, int b) {
    return row * 64 + (b ^ (((row >> 1) & 3) << 4));
}

// ============ MFMA flash attention, CAUSAL (v4: gload16 double-buffered) ============
// Grid-limited at 2 blocks/CU (512 blocks) so 64KB double-buffer LDS costs nothing.
template <bool CAUSAL>
__global__ __launch_bounds__(256, 2) void attn_mfma_kernel(
    const u16* __restrict__ qa, const u16* __restrict__ qb, int sq,
    const u16* __restrict__ ka, const u16* __restrict__ kb, int sk,
    const u16* __restrict__ vta, const u16* __restrict__ vtb,
    u16* __restrict__ Out, int nkeys) {
    __shared__ char Ks[2][16384];   // [buf][t=d/32][key][32 d] swizzled 64B rows
    __shared__ char VTs[2][16384];  // [buf][ks=key/32][d][32 keys] swizzled

    int tid = threadIdx.x;
    int lane = tid & 63, w = tid >> 6;
    int col = lane & 15, quad = lane >> 4;
    int eZ = CAUSAL ? (int)blockIdx.z : 0;
    int bx = (CAUSAL && eZ) ? ((int)gridDim.x - 1 - (int)blockIdx.x) : (int)blockIdx.x;
    int q0 = bx * 64;
    int h = blockIdx.y;
    const float scale = 0.08838834764831845f;  // 1/sqrt(128)

    int q0r = CAUSAL ? q0 : (q0 & (S - 1));
    const u16* qsel = CAUSAL ? (eZ ? qb : qa) : ((q0 < S) ? qa : qb);
    const u16* qp = qsel + (size_t)q0r * sq;
    bf16x8 aq[4];
#pragma unroll
    for (int t = 0; t < 4; t++)
        aq[t] = *reinterpret_cast<const bf16x8*>(
            qp + (size_t)(16 * w + col) * sq + h * HD + 32 * t + quad * 8);

    const u16* kplo = (CAUSAL && eZ) ? kb : ka;
    const u16* vplo = (CAUSAL && eZ) ? vtb : vta;

    f32x4 o[8] = {};           // O^T: o[nt][r] = O[q][d = 16nt + 4quad + r]
    float m_ = -1e30f, l_ = 0.f;

    int sA = col + 16 * (2 * (quad & 1));
    int sB = sA + 16;
    bool hi = (quad >> 1) != 0;

    int ntiles = CAUSAL ? (q0 >> 6) + 1 : (nkeys >> 6);

    auto stage = [&](int buf, int tt) {
        int j0r = (tt * 64) & (S - 1);
        bool eb = (!CAUSAL) && (tt >= (S >> 6));
        const u16* kp = eb ? kb : kplo;
        const u16* vp = eb ? vtb : vplo;
        char* kd = &Ks[buf][(tid >> 6) * 1024];
        char* vd = &VTs[buf][(tid >> 6) * 1024];
#pragma unroll
        for (int i = 0; i < 4; i++) {
            int l = 256 * i + tid;
            int key = (l >> 2) & 63;
            int c = (l >> 8) * 4 + ((l & 3) ^ ((key >> 1) & 3));
            gload16(kp + (size_t)(j0r + key) * sk + h * HD + c * 8, (u16*)(kd + i * 4096));
        }
#pragma unroll
        for (int i = 0; i < 4; i++) {
            int l = 256 * i + tid;
            int d = (l >> 2) & 127;
            int c = (l >> 9) * 4 + ((l & 3) ^ ((d >> 1) & 3));
            gload16(vp + (size_t)(h * HD + d) * S + j0r + c * 8, (u16*)(vd + i * 4096));
        }
    };

    stage(0, 0);
    __syncthreads();
    int cur = 0;

    for (int tt = 0; tt < ntiles; tt++) {
        if (tt + 1 < ntiles) stage(cur ^ 1, tt + 1);
        const char* Kb = Ks[cur];
        const char* Vb = VTs[cur];

        f32x4 sc[4] = {};
        __builtin_amdgcn_s_setprio(1);
#pragma unroll
        for (int t = 0; t < 4; t++) {
#pragma unroll
            for (int ct = 0; ct < 4; ct++) {
                bf16x8 kf = *reinterpret_cast<const bf16x8*>(
                    Kb + t * 4096 + swz64(16 * ct + col, quad * 16));
                sc[ct] = __builtin_amdgcn_mfma_f32_16x16x32_bf16(kf, aq[t], sc[ct], 0, 0, 0);
            }
        }
        __builtin_amdgcn_s_setprio(0);
        bool diag = CAUSAL && (tt == ntiles - 1);
#pragma unroll
        for (int ct = 0; ct < 4; ct++) {
#pragma unroll
            for (int r = 0; r < 4; r++) {
                float v = sc[ct][r] * scale;
                if (diag && (16 * ct + 4 * quad + r > 16 * w + col)) v = -1e30f;
                sc[ct][r] = v;
            }
        }

        float mx0 = fmaxf(fmaxf(sc[0][0], sc[0][1]), fmaxf(sc[0][2], sc[0][3]));
        float mx1 = fmaxf(fmaxf(sc[1][0], sc[1][1]), fmaxf(sc[1][2], sc[1][3]));
        float mx2 = fmaxf(fmaxf(sc[2][0], sc[2][1]), fmaxf(sc[2][2], sc[2][3]));
        float mx3 = fmaxf(fmaxf(sc[3][0], sc[3][1]), fmaxf(sc[3][2], sc[3][3]));
        float rmax = fmaxf(fmaxf(mx0, mx1), fmaxf(mx2, mx3));
        rmax = fmaxf(rmax, __shfl_xor(rmax, 16));
        rmax = fmaxf(rmax, __shfl_xor(rmax, 32));
        float mn = fmaxf(m_, rmax);
        float al = __expf(m_ - mn);
#pragma unroll
        for (int ct = 0; ct < 4; ct++)
#pragma unroll
            for (int r = 0; r < 4; r++) sc[ct][r] = __expf(sc[ct][r] - mn);
        float s0 = (sc[0][0] + sc[0][1]) + (sc[0][2] + sc[0][3]);
        float s1 = (sc[1][0] + sc[1][1]) + (sc[1][2] + sc[1][3]);
        float s2 = (sc[2][0] + sc[2][1]) + (sc[2][2] + sc[2][3]);
        float s3 = (sc[3][0] + sc[3][1]) + (sc[3][2] + sc[3][3]);
        float rs = (s0 + s1) + (s2 + s3);
        rs += __shfl_xor(rs, 16);
        rs += __shfl_xor(rs, 32);
        l_ = l_ * al + rs;
        m_ = mn;

        unsigned int pu[4][2];
#pragma unroll
        for (int ct = 0; ct < 4; ct++) {
            pu[ct][0] = (unsigned int)f2bu(sc[ct][0]) | ((unsigned int)f2bu(sc[ct][1]) << 16);
            pu[ct][1] = (unsigned int)f2bu(sc[ct][2]) | ((unsigned int)f2bu(sc[ct][3]) << 16);
        }

#pragma unroll
        for (int nt = 0; nt < 8; nt++)
#pragma unroll
            for (int r = 0; r < 4; r++) o[nt][r] *= al;

#pragma unroll
        for (int ks = 0; ks < 2; ks++) {
            unsigned int a0 = __shfl(pu[2 * ks][0], sA);
            unsigned int a1 = __shfl(pu[2 * ks][1], sA);
            unsigned int c0 = __shfl(pu[2 * ks + 1][0], sA);
            unsigned int c1 = __shfl(pu[2 * ks + 1][1], sA);
            unsigned int b0 = __shfl(pu[2 * ks][0], sB);
            unsigned int b1 = __shfl(pu[2 * ks][1], sB);
            unsigned int g0 = __shfl(pu[2 * ks + 1][0], sB);
            unsigned int g1 = __shfl(pu[2 * ks + 1][1], sB);
            union {
                unsigned int u[4];
                bf16x8 v;
            } pb;
            pb.u[0] = hi ? c0 : a0;
            pb.u[1] = hi ? c1 : a1;
            pb.u[2] = hi ? g0 : b0;
            pb.u[3] = hi ? g1 : b1;
            __builtin_amdgcn_s_setprio(1);
#pragma unroll
            for (int nt = 0; nt < 8; nt++) {
                bf16x8 vf = *reinterpret_cast<const bf16x8*>(
                    Vb + ks * 8192 + swz64(16 * nt + col, quad * 16));
                o[nt] = __builtin_amdgcn_mfma_f32_16x16x32_bf16(vf, pb.v, o[nt], 0, 0, 0);
            }
            __builtin_amdgcn_s_setprio(0);
        }

        __syncthreads();
        cur ^= 1;
    }

    u16* outp = Out + (CAUSAL ? (size_t)eZ * ((size_t)S * HID) : (size_t)0);
    float inv = 1.f / l_;
    size_t rowoff = (size_t)(q0 + 16 * w + col) * HID + (size_t)h * HD + 4 * quad;
#pragma unroll
    for (int nt = 0; nt < 8; nt++) {
        ushort4 st;
        st.x = f2bu(o[nt][0] * inv);
        st.y = f2bu(o[nt][1] * inv);
        st.z = f2bu(o[nt][2] * inv);
        st.w = f2bu(o[nt][3] * inv);
        *reinterpret_cast<ushort4*>(&outp[rowoff + 16 * nt]) = st;
    }
}

// ============ Mixed attention, key-split (flash-decoding, 2 splits) ============
// blockIdx.z = split = expert whose 2048 keys this block processes. Single-buffer
// 32KB LDS -> 4 blocks/CU resident (16 waves) on the 1024-block grid. Writes
// UNNORMALIZED partial O (bf16, referenced to local max m) + per-row (m, l);
// attn_combine merges the two splits.
__global__ __launch_bounds__(256, 4) void attn_mixed_split(
    const u16* __restrict__ qa, const u16* __restrict__ qb, int sq,
    const u16* __restrict__ ka, const u16* __restrict__ kb, int sk,
    const u16* __restrict__ vta, const u16* __restrict__ vtb,
    u16* __restrict__ Opart, float2* __restrict__ ml) {
    __shared__ char Ks[16384];
    __shared__ char VTs[16384];

    int tid = threadIdx.x;
    int lane = tid & 63, w = tid >> 6;
    int col = lane & 15, quad = lane >> 4;
    int q0 = blockIdx.x * 64;  // 0..4032 over 2S queries
    int h = blockIdx.y;
    int z = blockIdx.z;  // split/expert
    const float scale = 0.08838834764831845f;

    const u16* qp = ((q0 < S) ? qa : qb) + (size_t)(q0 & (S - 1)) * sq;
    bf16x8 aq[4];
#pragma unroll
    for (int t = 0; t < 4; t++)
        aq[t] = *reinterpret_cast<const bf16x8*>(
            qp + (size_t)(16 * w + col) * sq + h * HD + 32 * t + quad * 8);

    const u16* kp = z ? kb : ka;
    const u16* vp = z ? vtb : vta;

    f32x4 o[8] = {};
    float m_ = -1e30f, l_ = 0.f;

    int sA = col + 16 * (2 * (quad & 1));
    int sB = sA + 16;
    bool hi = (quad >> 1) != 0;

    for (int tt = 0; tt < (S >> 6); tt++) {
        int j0r = tt * 64;
        __syncthreads();  // prev compute done reading LDS
        {
            char* kd = &Ks[(tid >> 6) * 1024];
            char* vd = &VTs[(tid >> 6) * 1024];
#pragma unroll
            for (int i = 0; i < 4; i++) {
                int l = 256 * i + tid;
                int key = (l >> 2) & 63;
                int c = (l >> 8) * 4 + ((l & 3) ^ ((key >> 1) & 3));
                gload16(kp + (size_t)(j0r + key) * sk + h * HD + c * 8, (u16*)(kd + i * 4096));
            }
#pragma unroll
            for (int i = 0; i < 4; i++) {
                int l = 256 * i + tid;
                int d = (l >> 2) & 127;
                int c = (l >> 9) * 4 + ((l & 3) ^ ((d >> 1) & 3));
                gload16(vp + (size_t)(h * HD + d) * S + j0r + c * 8, (u16*)(vd + i * 4096));
            }
        }
        __syncthreads();  // vmcnt drained -> tile in LDS

        f32x4 sc[4] = {};
        __builtin_amdgcn_s_setprio(1);
#pragma unroll
        for (int t = 0; t < 4; t++) {
#pragma unroll
            for (int ct = 0; ct < 4; ct++) {
                bf16x8 kf = *reinterpret_cast<const bf16x8*>(
                    Ks + t * 4096 + swz64(16 * ct + col, quad * 16));
                sc[ct] = __builtin_amdgcn_mfma_f32_16x16x32_bf16(kf, aq[t], sc[ct], 0, 0, 0);
            }
        }
        __builtin_amdgcn_s_setprio(0);
#pragma unroll
        for (int ct = 0; ct < 4; ct++)
#pragma unroll
            for (int r = 0; r < 4; r++) sc[ct][r] *= scale;

        float mx0 = fmaxf(fmaxf(sc[0][0], sc[0][1]), fmaxf(sc[0][2], sc[0][3]));
        float mx1 = fmaxf(fmaxf(sc[1][0], sc[1][1]), fmaxf(sc[1][2], sc[1][3]));
        float mx2 = fmaxf(fmaxf(sc[2][0], sc[2][1]), fmaxf(sc[2][2], sc[2][3]));
        float mx3 = fmaxf(fmaxf(sc[3][0], sc[3][1]), fmaxf(sc[3][2], sc[3][3]));
        float rmax = fmaxf(fmaxf(mx0, mx1), fmaxf(mx2, mx3));
        rmax = fmaxf(rmax, __shfl_xor(rmax, 16));
        rmax = fmaxf(rmax, __shfl_xor(rmax, 32));
        float mn = fmaxf(m_, rmax);
        float al = __expf(m_ - mn);
#pragma unroll
        for (int ct = 0; ct < 4; ct++)
#pragma unroll
            for (int r = 0; r < 4; r++) sc[ct][r] = __expf(sc[ct][r] - mn);
        float s0 = (sc[0][0] + sc[0][1]) + (sc[0][2] + sc[0][3]);
        float s1 = (sc[1][0] + sc[1][1]) + (sc[1][2] + sc[1][3]);
        float s2 = (sc[2][0] + sc[2][1]) + (sc[2][2] + sc[2][3]);
        float s3 = (sc[3][0] + sc[3][1]) + (sc[3][2] + sc[3][3]);
        float rs = (s0 + s1) + (s2 + s3);
        rs += __shfl_xor(rs, 16);
        rs += __shfl_xor(rs, 32);
        l_ = l_ * al + rs;
        m_ = mn;

        unsigned int pu[4][2];
#pragma unroll
        for (int ct = 0; ct < 4; ct++) {
            pu[ct][0] = (unsigned int)f2bu(sc[ct][0]) | ((unsigned int)f2bu(sc[ct][1]) << 16);
            pu[ct][1] = (unsigned int)f2bu(sc[ct][2]) | ((unsigned int)f2bu(sc[ct][3]) << 16);
        }

#pragma unroll
        for (int nt = 0; nt < 8; nt++)
#pragma unroll
            for (int r = 0; r < 4; r++) o[nt][r] *= al;

#pragma unroll
        for (int ks = 0; ks < 2; ks++) {
            unsigned int a0 = __shfl(pu[2 * ks][0], sA);
            unsigned int a1 = __shfl(pu[2 * ks][1], sA);
            unsigned int c0 = __shfl(pu[2 * ks + 1][0], sA);
            unsigned int c1 = __shfl(pu[2 * ks + 1][1], sA);
            unsigned int b0 = __shfl(pu[2 * ks][0], sB);
            unsigned int b1 = __shfl(pu[2 * ks][1], sB);
            unsigned int g0 = __shfl(pu[2 * ks + 1][0], sB);
            unsigned int g1 = __shfl(pu[2 * ks + 1][1], sB);
            union {
                unsigned int u[4];
                bf16x8 v;
            } pb;
            pb.u[0] = hi ? c0 : a0;
            pb.u[1] = hi ? c1 : a1;
            pb.u[2] = hi ? g0 : b0;
            pb.u[3] = hi ? g1 : b1;
            __builtin_amdgcn_s_setprio(1);
#pragma unroll
            for (int nt = 0; nt < 8; nt++) {
                bf16x8 vf = *reinterpret_cast<const bf16x8*>(
                    VTs + ks * 8192 + swz64(16 * nt + col, quad * 16));
                o[nt] = __builtin_amdgcn_mfma_f32_16x16x32_bf16(vf, pb.v, o[nt], 0, 0, 0);
            }
            __builtin_amdgcn_s_setprio(0);
        }
    }

    // partial epilogue: UNNORMALIZED O (bf16) + (m,l) per q-row
    const size_t SPL = (size_t)2 * S * HID;  // per-split element count
    size_t rowoff = (size_t)z * SPL + (size_t)(q0 + 16 * w + col) * HID + (size_t)h * HD + 4 * quad;
#pragma unroll
    for (int nt = 0; nt < 8; nt++) {
        ushort4 st;
        st.x = f2bu(o[nt][0]);
        st.y = f2bu(o[nt][1]);
        st.z = f2bu(o[nt][2]);
        st.w = f2bu(o[nt][3]);
        *reinterpret_cast<ushort4*>(&Opart[rowoff + 16 * nt]) = st;
    }
    if (quad == 0)
        ml[((size_t)z * 2 * S + q0 + 16 * w + col) * NH + h] = make_float2(m_, l_);
}

// ---------------- combine the 2 key-splits: out = (w0*O0 + w1*O1)/(w0*l0 + w1*l1) ----------------
__global__ __launch_bounds__(256) void attn_combine(const u16* __restrict__ Opart,
                                                    const float2* __restrict__ ml,
                                                    u16* __restrict__ out) {
    size_t idx = ((size_t)blockIdx.x * 256 + threadIdx.x) * 8;  // over 2S*HID elements
    int q = (int)(idx >> 10);
    int c0 = (int)(idx & 1023);
    int h = c0 >> 7;
    float2 ml0 = ml[(size_t)q * NH + h];
    float2 ml1 = ml[((size_t)2 * S + q) * NH + h];
    float ms = fmaxf(ml0.x, ml1.x);
    float w0 = __expf(ml0.x - ms), w1 = __expf(ml1.x - ms);
    float rden = 1.f / (w0 * ml0.y + w1 * ml1.y);
    const size_t SPL = (size_t)2 * S * HID;
    uint4 a = *reinterpret_cast<const uint4*>(&Opart[idx]);
    uint4 b = *reinterpret_cast<const uint4*>(&Opart[SPL + idx]);
    const u16* ap = reinterpret_cast<const u16*>(&a);
    const u16* bp = reinterpret_cast<const u16*>(&b);
    u16 res[8];
#pragma unroll
    for (int j = 0; j < 8; j++)
        res[j] = f2bu((w0 * bu2f(ap[j]) + w1 * bu2f(bp[j])) * rden);
    *reinterpret_cast<uint4*>(&out[idx]) = *reinterpret_cast<const uint4*>(res);
}

// ---------------- f32 -> output dtype (per flag) ----------------
__global__ __launch_bounds__(256) void store_out_kernel(const float* __restrict__ a,
                                                        const float* __restrict__ b,
                                                        void* __restrict__ out,
                                                        const int* __restrict__ flag) {
    bool isbf = (*flag != 0);
    size_t i = (size_t)blockIdx.x * 256 + threadIdx.x;
    const size_t MM = (size_t)S * HID;
    float v = (i < MM) ? a[i] : b[i - MM];
    if (isbf)
        ((bf16*)out)[i] = __float2bfloat16(v);
    else
        ((float*)out)[i] = v;
}

extern "C" void kernel_launch(void* const* d_in, const int* in_sizes, int n_in,
                              void* d_out, int out_size, void* d_ws, size_t ws_size,
                              hipStream_t stream) {
    const void* x[2] = {d_in[0], d_in[1]};
    const void* w_ln[2] = {d_in[5], d_in[14]};
    const void* w_q[2] = {d_in[6], d_in[15]};
    const void* w_k[2] = {d_in[7], d_in[16]};
    const void* w_v[2] = {d_in[8], d_in[17]};
    const void* w_o[2] = {d_in[9], d_in[18]};
    const void* w_pln[2] = {d_in[10], d_in[19]};
    const void* w_g[2] = {d_in[11], d_in[20]};
    const void* w_u[2] = {d_in[12], d_in[21]};
    const void* w_d[2] = {d_in[13], d_in[22]};

    char* base = (char*)d_ws;
    int* flag = (int*)base;
    u16* p = (u16*)(base + 256);
    const size_t E_QKV = (size_t)S * 3072;
    const size_t E_SH = (size_t)S * HID;
    const size_t E_VT = (size_t)NH * HD * S;  // == E_SH
    const size_t E_GT = (size_t)S * INTER;    // 8.39M u16

    u16* qkv[2] = {p, p + E_QKV};            p += 2 * E_QKV;
    u16* qr = p;                             p += 2 * E_SH;  // [expert]
    u16* kr = p;                             p += 2 * E_SH;  // adjacent to qr
    u16* h_bf = p;                           p += 2 * E_SH;
    u16* attnbuf = p;                        p += 2 * E_SH;
    u16* vtg = p;                            p += 2 * E_VT;
    u16* wqkvT = p;                          p += 2 * (size_t)3072 * 1024;
    u16* woT[2] = {p, p + (size_t)1024 * 1024};  p += 2 * (size_t)1024 * 1024;
    u16* wgT = p;                            p += (size_t)INTER * 1024;
    u16* wuT = p;                            p += (size_t)INTER * 1024;
    u16* wdT = p;                            p += (size_t)1024 * INTER;
    u16* gated1 = p;                         p += E_GT;  // fresh: expert-1 gated
    float* fbase = (float*)(((size_t)p + 255) & ~(size_t)255);
    float* outX[2] = {fbase, fbase + E_SH};
    float2* mlbuf = (float2*)(fbase + 2 * E_SH);  // 2 splits x 2S x NH
    // Overlays (each checked against liveness; round-8 lesson):
    //   gated0 (E_GT = 8.39M) = qr+kr (4*E_SH = 8.39M exactly; dead after causal attn)
    //   wgT2 (4.19M) = wqkvT (6.29M; dead after qkv GEMM)
    //   wuT2 (4.19M) = attnbuf (4.19M; dead after wo-causal GEMM; transpose is after it)
    //   wdT2 (4.19M) = wgT (dead after gated GEMM; wd transpose scheduled after gated)
    //   Opart (8.39M) = qr+kr (gated0 dead after down GEMM)
    //   mixed (4.19M) = h_bf (dead after gated GEMM reads it)
    u16* gated0 = qr;
    u16* wgT2 = wqkvT;
    u16* wuT2 = attnbuf;
    u16* wdT2 = wgT;
    u16* Opart = qr;
    u16* mixed = h_bf;

    probe_kernel<<<1, 256, 0, stream>>>((const unsigned short*)d_in[0], flag);

    // ---- upfront transposes: qkv + wo weights for both experts, one z=8 dispatch ----
    {
        TransN tn = {};
        for (int e = 0; e < 2; e++) {
            u16* wt = wqkvT + (size_t)e * 3072 * 1024;
            tn.W[4 * e + 0] = w_q[e];  tn.T[4 * e + 0] = wt;
            tn.W[4 * e + 1] = w_k[e];  tn.T[4 * e + 1] = wt + (size_t)1024 * 1024;
            tn.W[4 * e + 2] = w_v[e];  tn.T[4 * e + 2] = wt + (size_t)2048 * 1024;
            tn.W[4 * e + 3] = w_o[e];  tn.T[4 * e + 3] = woT[e];
        }
        transpose_wN<<<dim3(32, 32, 8), 256, 0, stream>>>(tn, flag, 1024, 1024);
    }

    // ---- fused attention path (both experts per dispatch) ----
    {
        RmsDual rd = {{x[0], x[1]}, {w_ln[0], w_ln[1]}, {h_bf, h_bf + E_SH}};
        rmsnorm_kernel<<<dim3(S, 2), 256, 0, stream>>>(rd, flag, 1);
    }
    {
        GemmDual g = {{h_bf, h_bf + E_SH},
                      {wqkvT, wqkvT + (size_t)3072 * 1024},
                      {nullptr, nullptr},
                      {qkv[0], qkv[1]},
                      {nullptr, nullptr}};
        gemm_mfma<128, 128, 2, 2, 0><<<dim3(3072 / 128, S / 128, 2), 256, 0, stream>>>(
            g, flag, S, 3072, 1024);
    }
    rope_kernel<<<dim3(S * NH, 1, 2), 64, 0, stream>>>(qkv[0], qkv[1], qr, kr);
    transpose_v<<<dim3(S / 32, 1024 / 32, 2), 256, 0, stream>>>(qkv[0] + 2048, qkv[1] + 2048, 3072, vtg);
    attn_mfma_kernel<true><<<dim3(S / 64, NH, 2), 256, 0, stream>>>(
        qr, qr + E_SH, HID, kr, kr + E_SH, HID, vtg, vtg + E_VT, attnbuf, S);
    {
        GemmDual g = {{attnbuf, attnbuf + E_SH},
                      {woT[0], woT[1]},
                      {outX[0], outX[1]},
                      {nullptr, nullptr},
                      {x[0], x[1]}};
        gemm_mfma<64, 64, 2, 2, 1><<<dim3(1024 / 64, S / 64, 2), 256, 0, stream>>>(
            g, flag, S, 1024, 1024);
    }
    {
        RmsDual rd = {{outX[0], outX[1]}, {w_pln[0], w_pln[1]}, {h_bf, h_bf + E_SH}};
        rmsnorm_kernel<<<dim3(S, 2), 256, 0, stream>>>(rd, flag, 0);
    }

    // ---- MLP, both experts fused via z (overlays: wgT2=wqkvT, wuT2=attnbuf, wdT2=wgT) ----
    {
        TransN tg = {};
        tg.W[0] = w_g[0];  tg.T[0] = wgT;
        tg.W[1] = w_u[0];  tg.T[1] = wuT;
        tg.W[2] = w_g[1];  tg.T[2] = wgT2;
        tg.W[3] = w_u[1];  tg.T[3] = wuT2;
        transpose_wN<<<dim3(INTER / 32, 1024 / 32, 4), 256, 0, stream>>>(tg, flag, 1024, INTER);
    }
    {
        GatedDual gg = {{h_bf, h_bf + E_SH},
                        {wgT, wgT2},
                        {wuT, wuT2},
                        {gated0, gated1}};
        gemm_gated_mfma<128, 64, 2, 2><<<dim3(INTER / 64, S / 128, 2), 256, 0, stream>>>(
            gg, S, INTER, 1024);
    }
    {
        TransN td = {};
        td.W[0] = w_d[0];  td.T[0] = wdT;
        td.W[1] = w_d[1];  td.T[1] = wdT2;  // wgT region, dead after gated GEMM
        transpose_wN<<<dim3(1024 / 32, INTER / 32, 2), 256, 0, stream>>>(td, flag, INTER, 1024);
    }
    {
        GemmDual g = {{gated0, gated1},
                      {wdT, wdT2},
                      {outX[0], outX[1]},
                      {nullptr, nullptr},
                      {nullptr, nullptr}};
        gemm_mfma<64, 64, 2, 2, 2><<<dim3(1024 / 64, S / 64, 2), 256, 0, stream>>>(
            g, flag, S, 1024, INTER);
    }

    // ---- mixed attention (key-split over the 2 experts) + combine + output projections ----
    attn_mixed_split<<<dim3(2 * S / 64, NH, 2), 256, 0, stream>>>(
        qkv[0], qkv[1], 3072, qkv[0] + 1024, qkv[1] + 1024, 3072,
        vtg, vtg + E_VT, Opart, mlbuf);
    attn_combine<<<(2 * E_SH) / (256 * 8), 256, 0, stream>>>(Opart, mlbuf, mixed);
    {
        GemmDual g = {{mixed, mixed + E_SH},
                      {woT[0], woT[1]},
                      {outX[0], outX[1]},
                      {nullptr, nullptr},
                      {nullptr, nullptr}};
        gemm_mfma<64, 64, 2, 2, 2><<<dim3(1024 / 64, S / 64, 2), 256, 0, stream>>>(
            g, flag, S, 1024, 1024);
    }

    store_out_kernel<<<(2 * E_SH) / 256, 256, 0, stream>>>(outX[0], outX[1], d_out, flag);
}